// Round 1
// baseline (438.206 us; speedup 1.0000x reference)
//
#include <hip/hip_runtime.h>
#include <hip/hip_bf16.h>

// Problem constants
#define BATCH 2
#define NPTS  2048
#define CDIM  256
#define NHEAD 8
#define DHEAD 64
#define INNER 512            // NHEAD*DHEAD
#define TRIPLE 1536          // 3*INNER
#define KNN   32
#define SCALE 0.125f         // 64^-0.5

// ---------------------------------------------------------------------------
// Kernel 1: row squared norms  x2[b*N+n] = sum_c x[b,n,c]^2
// ---------------------------------------------------------------------------
__global__ __launch_bounds__(64) void rowsq_kernel(const float* __restrict__ x,
                                                   float* __restrict__ x2) {
    int row = blockIdx.x;                       // 0 .. B*N-1
    const float4* p = (const float4*)(x + (size_t)row * CDIM);
    float4 v = p[threadIdx.x];                  // 64 threads * 4 = 256
    float s = v.x*v.x + v.y*v.y + v.z*v.z + v.w*v.w;
    for (int o = 32; o; o >>= 1) s += __shfl_down(s, o);
    if (threadIdx.x == 0) x2[row] = s;
}

// ---------------------------------------------------------------------------
// Kernel 2: Gram/score matrix  S[b][i][j] = x2[b][j] - 2*dot(x_i, x_j),
// diag = +inf.  (x2[i] dropped: constant per row, doesn't change top-k.)
// Tiled 64x64, BK=16, 256 threads, 4x4 per thread.
// ---------------------------------------------------------------------------
__global__ __launch_bounds__(256) void gram_kernel(const float* __restrict__ x,
                                                   const float* __restrict__ x2,
                                                   float* __restrict__ S) {
    int b = blockIdx.z;
    const float* A = x + (size_t)b * NPTS * CDIM;
    float* Sb = S + (size_t)b * NPTS * NPTS;
    const float* x2b = x2 + (size_t)b * NPTS;

    __shared__ float As[16][65];
    __shared__ float Bs[16][65];

    int bi = blockIdx.y * 64;
    int bj = blockIdx.x * 64;
    int tx = threadIdx.x & 15;
    int ty = threadIdx.x >> 4;

    float acc[4][4] = {};

    for (int k0 = 0; k0 < CDIM; k0 += 16) {
        // load A-tile rows bi..bi+63, k0..k0+15 (transposed into As[k][i])
        {
            int r  = threadIdx.x >> 2;
            int kk = (threadIdx.x & 3) * 4;
            float4 v = *(const float4*)(A + (size_t)(bi + r) * CDIM + k0 + kk);
            As[kk+0][r] = v.x; As[kk+1][r] = v.y; As[kk+2][r] = v.z; As[kk+3][r] = v.w;
        }
        // load B-tile rows bj..bj+63 (same matrix, S = A A^T)
        {
            int r  = threadIdx.x >> 2;
            int kk = (threadIdx.x & 3) * 4;
            float4 v = *(const float4*)(A + (size_t)(bj + r) * CDIM + k0 + kk);
            Bs[kk+0][r] = v.x; Bs[kk+1][r] = v.y; Bs[kk+2][r] = v.z; Bs[kk+3][r] = v.w;
        }
        __syncthreads();
        #pragma unroll
        for (int k = 0; k < 16; ++k) {
            float a[4], bv[4];
            #pragma unroll
            for (int u = 0; u < 4; ++u) a[u]  = As[k][ty*4 + u];
            #pragma unroll
            for (int u = 0; u < 4; ++u) bv[u] = Bs[k][tx*4 + u];
            #pragma unroll
            for (int u = 0; u < 4; ++u)
                #pragma unroll
                for (int w = 0; w < 4; ++w) acc[u][w] += a[u] * bv[w];
        }
        __syncthreads();
    }

    #pragma unroll
    for (int u = 0; u < 4; ++u) {
        int row = bi + ty*4 + u;
        #pragma unroll
        for (int w = 0; w < 4; ++w) {
            int col = bj + tx*4 + w;
            float val = x2b[col] - 2.0f * acc[u][w];
            if (row == col) val = __builtin_inff();
            Sb[(size_t)row * NPTS + col] = val;
        }
    }
}

// ---------------------------------------------------------------------------
// Kernel 3: per-row top-KNN smallest -> neighbor indices
// One block (256 thr) per (b,n). Row staged in LDS, 32 x argmin.
// ---------------------------------------------------------------------------
__global__ __launch_bounds__(256) void knn_select_kernel(const float* __restrict__ S,
                                                         int* __restrict__ idx) {
    int n = blockIdx.x, b = blockIdx.y;
    const float* row = S + ((size_t)b * NPTS + n) * NPTS;
    int* out = idx + ((size_t)b * NPTS + n) * KNN;

    __shared__ float vals[NPTS];
    __shared__ float rv[4];
    __shared__ int   ri[4];

    for (int i = threadIdx.x; i < NPTS; i += 256) vals[i] = row[i];
    __syncthreads();

    for (int it = 0; it < KNN; ++it) {
        float best = __builtin_inff();
        int   bi   = 0x7fffffff;
        for (int i = threadIdx.x; i < NPTS; i += 256) {
            float v = vals[i];
            if (v < best || (v == best && i < bi)) { best = v; bi = i; }
        }
        for (int o = 32; o; o >>= 1) {
            float ov = __shfl_down(best, o);
            int   oi = __shfl_down(bi, o);
            if (ov < best || (ov == best && oi < bi)) { best = ov; bi = oi; }
        }
        int wave = threadIdx.x >> 6;
        if ((threadIdx.x & 63) == 0) { rv[wave] = best; ri[wave] = bi; }
        __syncthreads();
        if (threadIdx.x == 0) {
            float bv = rv[0]; int bx = ri[0];
            for (int w = 1; w < 4; ++w)
                if (rv[w] < bv || (rv[w] == bv && ri[w] < bx)) { bv = rv[w]; bx = ri[w]; }
            out[it] = bx;
            vals[bx] = __builtin_inff();
        }
        __syncthreads();
    }
}

// ---------------------------------------------------------------------------
// Kernel 4: generic tiled fp32 GEMM  C[M,N] = A[M,K] @ B[K,N] (+bias)
// 64x64 tile, BK=16, 256 threads, 4x4 per thread.
// ---------------------------------------------------------------------------
__global__ __launch_bounds__(256) void gemm64_kernel(const float* __restrict__ A,
                                                     const float* __restrict__ Bm,
                                                     const float* __restrict__ bias,
                                                     float* __restrict__ C,
                                                     int M, int Nn, int K) {
    __shared__ float As[16][65];
    __shared__ float Bs[16][65];

    int bi = blockIdx.y * 64;
    int bj = blockIdx.x * 64;
    int tx = threadIdx.x & 15;
    int ty = threadIdx.x >> 4;

    float acc[4][4] = {};

    for (int k0 = 0; k0 < K; k0 += 16) {
        {
            int r  = threadIdx.x >> 2;
            int kk = (threadIdx.x & 3) * 4;
            float4 v = *(const float4*)(A + (size_t)(bi + r) * K + k0 + kk);
            As[kk+0][r] = v.x; As[kk+1][r] = v.y; As[kk+2][r] = v.z; As[kk+3][r] = v.w;
        }
        {
            int kk = threadIdx.x >> 4;          // 0..15
            int c  = (threadIdx.x & 15) * 4;    // 0..60
            float4 v = *(const float4*)(Bm + (size_t)(k0 + kk) * Nn + bj + c);
            Bs[kk][c+0] = v.x; Bs[kk][c+1] = v.y; Bs[kk][c+2] = v.z; Bs[kk][c+3] = v.w;
        }
        __syncthreads();
        #pragma unroll
        for (int k = 0; k < 16; ++k) {
            float a[4], bv[4];
            #pragma unroll
            for (int u = 0; u < 4; ++u) a[u]  = As[k][ty*4 + u];
            #pragma unroll
            for (int u = 0; u < 4; ++u) bv[u] = Bs[k][tx*4 + u];
            #pragma unroll
            for (int u = 0; u < 4; ++u)
                #pragma unroll
                for (int w = 0; w < 4; ++w) acc[u][w] += a[u] * bv[w];
        }
        __syncthreads();
    }

    #pragma unroll
    for (int u = 0; u < 4; ++u) {
        int row = bi + ty*4 + u;
        #pragma unroll
        for (int w = 0; w < 4; ++w) {
            int col = bj + tx*4 + w;
            float val = acc[u][w];
            if (bias) val += bias[col];
            C[(size_t)row * Nn + col] = val;
        }
    }
}

// ---------------------------------------------------------------------------
// Kernel 5: sparse graph attention. One block (256 thr) per (b,n).
// Threads: h = tid>>5 (8 heads), j = tid&31 (32 neighbors / 32 dim-pairs).
// ---------------------------------------------------------------------------
__global__ __launch_bounds__(256) void attn_kernel(const float* __restrict__ qkv,
                                                   const int* __restrict__ idx,
                                                   float* __restrict__ aout) {
    int n = blockIdx.x, b = blockIdx.y;
    size_t rowoff = ((size_t)b * NPTS + n);
    const float* qrowbase = qkv + rowoff * TRIPLE;                  // q cols 0..511
    const float* kbase = qkv + (size_t)b * NPTS * TRIPLE + INNER;   // + m*TRIPLE
    const float* vbase = qkv + (size_t)b * NPTS * TRIPLE + 2*INNER;

    __shared__ int   nb[KNN];
    __shared__ float p[NHEAD][KNN];

    if (threadIdx.x < KNN)
        nb[threadIdx.x] = idx[rowoff * KNN + threadIdx.x];
    __syncthreads();

    int h = threadIdx.x >> 5;
    int j = threadIdx.x & 31;

    // --- dots + softmax (each thread: one neighbor of one head) ---
    {
        int m = nb[j];
        const float* krow = kbase + (size_t)m * TRIPLE + h * DHEAD;
        const float* qrow = qrowbase + h * DHEAD;
        float dot = 0.f;
        #pragma unroll
        for (int d = 0; d < DHEAD; ++d) dot += qrow[d] * krow[d];
        dot *= SCALE;
        float mx = dot;
        for (int o = 16; o; o >>= 1) mx = fmaxf(mx, __shfl_xor(mx, o));
        float e = expf(dot - mx);
        float s = e;
        for (int o = 16; o; o >>= 1) s += __shfl_xor(s, o);
        p[h][j] = e / s;
    }
    __syncthreads();

    // --- weighted sum of v (each thread: 2 dims of one head) ---
    {
        float o0 = 0.f, o1 = 0.f;
        #pragma unroll 8
        for (int jj = 0; jj < KNN; ++jj) {
            int mm = nb[jj];
            const float* vrow = vbase + (size_t)mm * TRIPLE + h * DHEAD;
            float pw = p[h][jj];
            o0 += pw * vrow[j];
            o1 += pw * vrow[j + 32];
        }
        float* orow = aout + rowoff * INNER + h * DHEAD;
        orow[j]      = o0;
        orow[j + 32] = o1;
    }
}

// ---------------------------------------------------------------------------
extern "C" void kernel_launch(void* const* d_in, const int* in_sizes, int n_in,
                              void* d_out, int out_size, void* d_ws, size_t ws_size,
                              hipStream_t stream) {
    const float* x    = (const float*)d_in[0];   // [2,2048,256]
    const float* Wqkv = (const float*)d_in[1];   // [256,1536]
    const float* Wout = (const float*)d_in[2];   // [512,256]
    const float* bout = (const float*)d_in[3];   // [256]
    float* out = (float*)d_out;                  // [2,2048,256]

    // workspace layout (floats)
    float* S    = (float*)d_ws;                          // B*N*N      = 8388608
    float* x2   = S + (size_t)BATCH * NPTS * NPTS;       // B*N        = 4096
    int*   idx  = (int*)(x2 + (size_t)BATCH * NPTS);     // B*N*KNN    = 131072
    float* qkv  = (float*)(idx + (size_t)BATCH * NPTS * KNN); // B*N*1536
    float* aout = qkv + (size_t)BATCH * NPTS * TRIPLE;   // B*N*512

    // 1. row squared norms
    rowsq_kernel<<<BATCH * NPTS, 64, 0, stream>>>(x, x2);

    // 2. Gram/scores
    {
        dim3 grid(NPTS / 64, NPTS / 64, BATCH);
        gram_kernel<<<grid, 256, 0, stream>>>(x, x2, S);
    }

    // 3. top-32 neighbor selection
    {
        dim3 grid(NPTS, BATCH);
        knn_select_kernel<<<grid, 256, 0, stream>>>(S, idx);
    }

    // 4. qkv projection: [B*N,256] @ [256,1536]
    {
        dim3 grid(TRIPLE / 64, (BATCH * NPTS) / 64);
        gemm64_kernel<<<grid, 256, 0, stream>>>(x, Wqkv, nullptr, qkv,
                                                BATCH * NPTS, TRIPLE, CDIM);
    }

    // 5. sparse attention
    {
        dim3 grid(NPTS, BATCH);
        attn_kernel<<<grid, 256, 0, stream>>>(qkv, idx, aout);
    }

    // 6. output projection: [B*N,512] @ [512,256] + bias
    {
        dim3 grid(CDIM / 64, (BATCH * NPTS) / 64);
        gemm64_kernel<<<grid, 256, 0, stream>>>(aout, Wout, bout, out,
                                                BATCH * NPTS, CDIM, INNER);
    }
}

// Round 2
// 323.149 us; speedup vs baseline: 1.3561x; 1.3561x over previous
//
#include <hip/hip_runtime.h>
#include <hip/hip_bf16.h>

// Problem constants
#define BATCH 2
#define NPTS  2048
#define CDIM  256
#define NHEAD 8
#define DHEAD 64
#define INNER 512            // NHEAD*DHEAD
#define TRIPLE 1536          // 3*INNER
#define KNN   32
#define SCALE 0.125f         // 64^-0.5

// ---------------------------------------------------------------------------
// Kernel 1: row squared norms  x2[b*N+n] = sum_c x[b,n,c]^2
// ---------------------------------------------------------------------------
__global__ __launch_bounds__(64) void rowsq_kernel(const float* __restrict__ x,
                                                   float* __restrict__ x2) {
    int row = blockIdx.x;                       // 0 .. B*N-1
    const float4* p = (const float4*)(x + (size_t)row * CDIM);
    float4 v = p[threadIdx.x];                  // 64 threads * 4 = 256
    float s = v.x*v.x + v.y*v.y + v.z*v.z + v.w*v.w;
    for (int o = 32; o; o >>= 1) s += __shfl_down(s, o);
    if (threadIdx.x == 0) x2[row] = s;
}

// ---------------------------------------------------------------------------
// Kernel 2: Gram/score matrix  S[b][i][j] = x2[b][j] - 2*dot(x_i, x_j),
// diag = +inf.  (x2[i] dropped: constant per row, doesn't change top-k.)
// Tiled 64x64, BK=16, 256 threads, 4x4 per thread.
// ---------------------------------------------------------------------------
__global__ __launch_bounds__(256) void gram_kernel(const float* __restrict__ x,
                                                   const float* __restrict__ x2,
                                                   float* __restrict__ S) {
    int b = blockIdx.z;
    const float* A = x + (size_t)b * NPTS * CDIM;
    float* Sb = S + (size_t)b * NPTS * NPTS;
    const float* x2b = x2 + (size_t)b * NPTS;

    __shared__ float As[16][65];
    __shared__ float Bs[16][65];

    int bi = blockIdx.y * 64;
    int bj = blockIdx.x * 64;
    int tx = threadIdx.x & 15;
    int ty = threadIdx.x >> 4;

    float acc[4][4] = {};

    for (int k0 = 0; k0 < CDIM; k0 += 16) {
        // load A-tile rows bi..bi+63, k0..k0+15 (transposed into As[k][i])
        {
            int r  = threadIdx.x >> 2;
            int kk = (threadIdx.x & 3) * 4;
            float4 v = *(const float4*)(A + (size_t)(bi + r) * CDIM + k0 + kk);
            As[kk+0][r] = v.x; As[kk+1][r] = v.y; As[kk+2][r] = v.z; As[kk+3][r] = v.w;
        }
        // load B-tile rows bj..bj+63 (same matrix, S = A A^T)
        {
            int r  = threadIdx.x >> 2;
            int kk = (threadIdx.x & 3) * 4;
            float4 v = *(const float4*)(A + (size_t)(bj + r) * CDIM + k0 + kk);
            Bs[kk+0][r] = v.x; Bs[kk+1][r] = v.y; Bs[kk+2][r] = v.z; Bs[kk+3][r] = v.w;
        }
        __syncthreads();
        #pragma unroll
        for (int k = 0; k < 16; ++k) {
            float a[4], bv[4];
            #pragma unroll
            for (int u = 0; u < 4; ++u) a[u]  = As[k][ty*4 + u];
            #pragma unroll
            for (int u = 0; u < 4; ++u) bv[u] = Bs[k][tx*4 + u];
            #pragma unroll
            for (int u = 0; u < 4; ++u)
                #pragma unroll
                for (int w = 0; w < 4; ++w) acc[u][w] += a[u] * bv[w];
        }
        __syncthreads();
    }

    #pragma unroll
    for (int u = 0; u < 4; ++u) {
        int row = bi + ty*4 + u;
        #pragma unroll
        for (int w = 0; w < 4; ++w) {
            int col = bj + tx*4 + w;
            float val = x2b[col] - 2.0f * acc[u][w];
            if (row == col) val = __builtin_inff();
            Sb[(size_t)row * NPTS + col] = val;
        }
    }
}

// ---------------------------------------------------------------------------
// Kernel 3 (NEW): per-row exact top-KNN smallest via 4x8-bit radix select.
// One block (256 thr) per (b,n).
//  - map fp32 -> order-preserving uint
//  - 4 histogram passes pin down the exact 32nd-smallest key (pivot) and the
//    residual rank r among pivot-equal keys
//  - deterministic emit: block prefix-scan positions; ties at pivot taken by
//    lowest index (matches jax.lax.top_k tie-breaking)
// ---------------------------------------------------------------------------
__device__ __forceinline__ unsigned block_excl_scan_256(unsigned c,
                                                        unsigned* wsum,
                                                        unsigned* total_out) {
    // inclusive scan within each 64-lane wave
    unsigned v = c;
    #pragma unroll
    for (int o = 1; o < 64; o <<= 1) {
        unsigned t = __shfl_up(v, o);
        if ((threadIdx.x & 63) >= o) v += t;
    }
    if ((threadIdx.x & 63) == 63) wsum[threadIdx.x >> 6] = v;
    __syncthreads();
    unsigned woff = 0;
    int mywave = threadIdx.x >> 6;
    #pragma unroll
    for (int w = 0; w < 4; ++w) {
        unsigned s = wsum[w];
        if (w < mywave) woff += s;
    }
    if (total_out) *total_out = wsum[0] + wsum[1] + wsum[2] + wsum[3];
    __syncthreads();            // allow wsum reuse by caller
    return v + woff - c;        // exclusive prefix
}

__global__ __launch_bounds__(256) void knn_radix_kernel(const float* __restrict__ S,
                                                        int* __restrict__ idx) {
    int n = blockIdx.x, b = blockIdx.y;
    const float* row = S + ((size_t)b * NPTS + n) * NPTS;
    int* out = idx + ((size_t)b * NPTS + n) * KNN;

    __shared__ unsigned keys[NPTS];      // 8 KB
    __shared__ unsigned hist[256];       // 1 KB
    __shared__ unsigned wsum[4];
    __shared__ unsigned sh_below, sh_sel;
    __shared__ int eqlist[64];

    // load + order-preserving map (ascending)
    for (int i = threadIdx.x; i < NPTS; i += 256) {
        unsigned u = __float_as_uint(row[i]);
        u = (u & 0x80000000u) ? ~u : (u | 0x80000000u);
        keys[i] = u;
    }
    __syncthreads();

    unsigned prefix = 0, pmask = 0;
    int rank = KNN;                      // 1-based rank still needed among candidates
    #pragma unroll
    for (int pass = 0; pass < 4; ++pass) {
        int shift = 24 - pass * 8;
        hist[threadIdx.x] = 0;
        __syncthreads();
        for (int i = threadIdx.x; i < NPTS; i += 256) {
            unsigned u = keys[i];
            if ((u & pmask) == prefix)
                atomicAdd(&hist[(u >> shift) & 0xffu], 1u);
        }
        __syncthreads();
        unsigned c = hist[threadIdx.x];
        unsigned excl = block_excl_scan_256(c, wsum, nullptr);
        if (excl < (unsigned)rank && excl + c >= (unsigned)rank) {
            sh_below = excl;
            sh_sel   = (unsigned)threadIdx.x;
        }
        __syncthreads();
        rank   -= (int)sh_below;
        prefix |= sh_sel << shift;
        pmask  |= 0xffu << shift;
        __syncthreads();                 // before hist reuse next pass
    }
    unsigned pivot = prefix;             // exact 32nd-smallest key

    // per-thread counts over its strided elements
    unsigned lt = 0, eq = 0;
    for (int i = threadIdx.x; i < NPTS; i += 256) {
        unsigned u = keys[i];
        lt += (u < pivot) ? 1u : 0u;
        eq += (u == pivot) ? 1u : 0u;
    }
    unsigned total = 0;
    unsigned excl = block_excl_scan_256(lt | (eq << 16), wsum, &total);
    unsigned lt_base = excl & 0xffffu;
    unsigned eq_base = excl >> 16;
    unsigned eq_total = total >> 16;

    for (int i = threadIdx.x; i < NPTS; i += 256) {
        unsigned u = keys[i];
        if (u < pivot) {
            out[lt_base++] = i;
        } else if (u == pivot) {
            if (eq_base < 64) eqlist[eq_base] = i;
            eq_base++;
        }
    }
    __syncthreads();

    if (threadIdx.x == 0) {
        int base = KNN - rank;           // = count of keys strictly below pivot
        int m = (int)(eq_total < 64u ? eq_total : 64u);
        for (int t = 0; t < rank; ++t) { // take `rank` lowest-index ties
            int best = 0x7fffffff, bj = -1;
            for (int j = 0; j < m; ++j) {
                int v = eqlist[j];
                if (v >= 0 && v < best) { best = v; bj = j; }
            }
            out[base + t] = best;
            if (bj >= 0) eqlist[bj] = -1;
        }
    }
}

// ---------------------------------------------------------------------------
// Kernel 4: generic tiled fp32 GEMM  C[M,N] = A[M,K] @ B[K,N] (+bias)
// 64x64 tile, BK=16, 256 threads, 4x4 per thread.
// ---------------------------------------------------------------------------
__global__ __launch_bounds__(256) void gemm64_kernel(const float* __restrict__ A,
                                                     const float* __restrict__ Bm,
                                                     const float* __restrict__ bias,
                                                     float* __restrict__ C,
                                                     int M, int Nn, int K) {
    __shared__ float As[16][65];
    __shared__ float Bs[16][65];

    int bi = blockIdx.y * 64;
    int bj = blockIdx.x * 64;
    int tx = threadIdx.x & 15;
    int ty = threadIdx.x >> 4;

    float acc[4][4] = {};

    for (int k0 = 0; k0 < K; k0 += 16) {
        {
            int r  = threadIdx.x >> 2;
            int kk = (threadIdx.x & 3) * 4;
            float4 v = *(const float4*)(A + (size_t)(bi + r) * K + k0 + kk);
            As[kk+0][r] = v.x; As[kk+1][r] = v.y; As[kk+2][r] = v.z; As[kk+3][r] = v.w;
        }
        {
            int kk = threadIdx.x >> 4;          // 0..15
            int c  = (threadIdx.x & 15) * 4;    // 0..60
            float4 v = *(const float4*)(Bm + (size_t)(k0 + kk) * Nn + bj + c);
            Bs[kk][c+0] = v.x; Bs[kk][c+1] = v.y; Bs[kk][c+2] = v.z; Bs[kk][c+3] = v.w;
        }
        __syncthreads();
        #pragma unroll
        for (int k = 0; k < 16; ++k) {
            float a[4], bv[4];
            #pragma unroll
            for (int u = 0; u < 4; ++u) a[u]  = As[k][ty*4 + u];
            #pragma unroll
            for (int u = 0; u < 4; ++u) bv[u] = Bs[k][tx*4 + u];
            #pragma unroll
            for (int u = 0; u < 4; ++u)
                #pragma unroll
                for (int w = 0; w < 4; ++w) acc[u][w] += a[u] * bv[w];
        }
        __syncthreads();
    }

    #pragma unroll
    for (int u = 0; u < 4; ++u) {
        int row = bi + ty*4 + u;
        #pragma unroll
        for (int w = 0; w < 4; ++w) {
            int col = bj + tx*4 + w;
            float val = acc[u][w];
            if (bias) val += bias[col];
            C[(size_t)row * Nn + col] = val;
        }
    }
}

// ---------------------------------------------------------------------------
// Kernel 5: sparse graph attention. One block (256 thr) per (b,n).
// Threads: h = tid>>5 (8 heads), j = tid&31 (32 neighbors / 32 dim-pairs).
// ---------------------------------------------------------------------------
__global__ __launch_bounds__(256) void attn_kernel(const float* __restrict__ qkv,
                                                   const int* __restrict__ idx,
                                                   float* __restrict__ aout) {
    int n = blockIdx.x, b = blockIdx.y;
    size_t rowoff = ((size_t)b * NPTS + n);
    const float* qrowbase = qkv + rowoff * TRIPLE;                  // q cols 0..511
    const float* kbase = qkv + (size_t)b * NPTS * TRIPLE + INNER;   // + m*TRIPLE
    const float* vbase = qkv + (size_t)b * NPTS * TRIPLE + 2*INNER;

    __shared__ int   nb[KNN];
    __shared__ float p[NHEAD][KNN];

    if (threadIdx.x < KNN)
        nb[threadIdx.x] = idx[rowoff * KNN + threadIdx.x];
    __syncthreads();

    int h = threadIdx.x >> 5;
    int j = threadIdx.x & 31;

    // --- dots + softmax (each thread: one neighbor of one head) ---
    {
        int m = nb[j];
        const float* krow = kbase + (size_t)m * TRIPLE + h * DHEAD;
        const float* qrow = qrowbase + h * DHEAD;
        float dot = 0.f;
        #pragma unroll
        for (int d = 0; d < DHEAD; ++d) dot += qrow[d] * krow[d];
        dot *= SCALE;
        float mx = dot;
        for (int o = 16; o; o >>= 1) mx = fmaxf(mx, __shfl_xor(mx, o));
        float e = expf(dot - mx);
        float s = e;
        for (int o = 16; o; o >>= 1) s += __shfl_xor(s, o);
        p[h][j] = e / s;
    }
    __syncthreads();

    // --- weighted sum of v (each thread: 2 dims of one head) ---
    {
        float o0 = 0.f, o1 = 0.f;
        #pragma unroll 8
        for (int jj = 0; jj < KNN; ++jj) {
            int mm = nb[jj];
            const float* vrow = vbase + (size_t)mm * TRIPLE + h * DHEAD;
            float pw = p[h][jj];
            o0 += pw * vrow[j];
            o1 += pw * vrow[j + 32];
        }
        float* orow = aout + rowoff * INNER + h * DHEAD;
        orow[j]      = o0;
        orow[j + 32] = o1;
    }
}

// ---------------------------------------------------------------------------
extern "C" void kernel_launch(void* const* d_in, const int* in_sizes, int n_in,
                              void* d_out, int out_size, void* d_ws, size_t ws_size,
                              hipStream_t stream) {
    const float* x    = (const float*)d_in[0];   // [2,2048,256]
    const float* Wqkv = (const float*)d_in[1];   // [256,1536]
    const float* Wout = (const float*)d_in[2];   // [512,256]
    const float* bout = (const float*)d_in[3];   // [256]
    float* out = (float*)d_out;                  // [2,2048,256]

    // workspace layout (floats)
    float* S    = (float*)d_ws;                          // B*N*N      = 8388608
    float* x2   = S + (size_t)BATCH * NPTS * NPTS;       // B*N        = 4096
    int*   idx  = (int*)(x2 + (size_t)BATCH * NPTS);     // B*N*KNN    = 131072
    float* qkv  = (float*)(idx + (size_t)BATCH * NPTS * KNN); // B*N*1536
    float* aout = qkv + (size_t)BATCH * NPTS * TRIPLE;   // B*N*512

    // 1. row squared norms
    rowsq_kernel<<<BATCH * NPTS, 64, 0, stream>>>(x, x2);

    // 2. Gram/scores
    {
        dim3 grid(NPTS / 64, NPTS / 64, BATCH);
        gram_kernel<<<grid, 256, 0, stream>>>(x, x2, S);
    }

    // 3. top-32 neighbor selection (radix select)
    {
        dim3 grid(NPTS, BATCH);
        knn_radix_kernel<<<grid, 256, 0, stream>>>(S, idx);
    }

    // 4. qkv projection: [B*N,256] @ [256,1536]
    {
        dim3 grid(TRIPLE / 64, (BATCH * NPTS) / 64);
        gemm64_kernel<<<grid, 256, 0, stream>>>(x, Wqkv, nullptr, qkv,
                                                BATCH * NPTS, TRIPLE, CDIM);
    }

    // 5. sparse attention
    {
        dim3 grid(NPTS, BATCH);
        attn_kernel<<<grid, 256, 0, stream>>>(qkv, idx, aout);
    }

    // 6. output projection: [B*N,512] @ [512,256] + bias
    {
        dim3 grid(CDIM / 64, (BATCH * NPTS) / 64);
        gemm64_kernel<<<grid, 256, 0, stream>>>(aout, Wout, bout, out,
                                                BATCH * NPTS, CDIM, INNER);
    }
}

// Round 4
// 253.495 us; speedup vs baseline: 1.7287x; 1.2748x over previous
//
#include <hip/hip_runtime.h>
#include <hip/hip_bf16.h>

// Problem constants
#define BATCH 2
#define NPTS  2048
#define CDIM  256
#define NHEAD 8
#define DHEAD 64
#define INNER 512            // NHEAD*DHEAD
#define TRIPLE 1536          // 3*INNER
#define KNN   32
#define SCALE 0.125f         // 64^-0.5

typedef __attribute__((ext_vector_type(8))) short short8;      // 8 bf16 (4 VGPR)
typedef __attribute__((ext_vector_type(4))) float floatx4;     // MFMA acc
typedef __attribute__((ext_vector_type(4))) unsigned short ushort4v;
typedef unsigned short ushort;

// bf16 split: x = hi + lo (both RNE bf16), residual ~2^-18 relative.
// Returns hi in bits [15:0], lo in bits [31:16].
__device__ __forceinline__ unsigned bfsplit(float x) {
    unsigned u = __float_as_uint(x);
    unsigned r = u + 0x7fffu + ((u >> 16) & 1u);
    unsigned hs = r >> 16;
    float hf = __uint_as_float(hs << 16);
    float lo = x - hf;
    unsigned u2 = __float_as_uint(lo);
    unsigned r2 = u2 + 0x7fffu + ((u2 >> 16) & 1u);
    return (hs & 0xffffu) | (r2 & 0xffff0000u);
}

// ---------------------------------------------------------------------------
// Kernel 1: row squared norms
// ---------------------------------------------------------------------------
__global__ __launch_bounds__(64) void rowsq_kernel(const float* __restrict__ x,
                                                   float* __restrict__ x2) {
    int row = blockIdx.x;
    const float4* p = (const float4*)(x + (size_t)row * CDIM);
    float4 v = p[threadIdx.x];
    float s = v.x*v.x + v.y*v.y + v.z*v.z + v.w*v.w;
    for (int o = 32; o; o >>= 1) s += __shfl_down(s, o);
    if (threadIdx.x == 0) x2[row] = s;
}

// ---------------------------------------------------------------------------
// Kernel 2: elementwise fp32 -> bf16 hi/lo split
// ---------------------------------------------------------------------------
__global__ __launch_bounds__(256) void split_kernel(const float* __restrict__ src,
                                                    ushort* __restrict__ hi,
                                                    ushort* __restrict__ lo,
                                                    int n) {
    int i = (blockIdx.x * 256 + threadIdx.x) * 4;
    if (i >= n) return;
    float4 v = *(const float4*)(src + i);
    unsigned p0 = bfsplit(v.x), p1 = bfsplit(v.y),
             p2 = bfsplit(v.z), p3 = bfsplit(v.w);
    ushort4v h, l;
    h.x = (ushort)p0; l.x = (ushort)(p0 >> 16);
    h.y = (ushort)p1; l.y = (ushort)(p1 >> 16);
    h.z = (ushort)p2; l.z = (ushort)(p2 >> 16);
    h.w = (ushort)p3; l.w = (ushort)(p3 >> 16);
    *(ushort4v*)(hi + i) = h;
    *(ushort4v*)(lo + i) = l;
}

// ---------------------------------------------------------------------------
// Kernel 3: W [K][N] fp32 -> hi/lo bf16 transposed [N][K]
// 64x64 LDS tile transpose. K, N multiples of 64.
// ---------------------------------------------------------------------------
__global__ __launch_bounds__(256) void wtrans_split_kernel(const float* __restrict__ W,
                                                           ushort* __restrict__ hiT,
                                                           ushort* __restrict__ loT,
                                                           int K, int N) {
    __shared__ float tile[64][65];
    int k0 = blockIdx.y * 64, n0 = blockIdx.x * 64;
    #pragma unroll
    for (int i = 0; i < 4; ++i) {
        int f = threadIdx.x + i * 256;      // 0..1023
        int r = f >> 4, c4 = (f & 15) * 4;
        float4 v = *(const float4*)(W + (size_t)(k0 + r) * N + n0 + c4);
        tile[r][c4+0] = v.x; tile[r][c4+1] = v.y;
        tile[r][c4+2] = v.z; tile[r][c4+3] = v.w;
    }
    __syncthreads();
    #pragma unroll
    for (int i = 0; i < 4; ++i) {
        int f = threadIdx.x + i * 256;
        int rn = f >> 4, ck = (f & 15) * 4;
        unsigned p0 = bfsplit(tile[ck+0][rn]);
        unsigned p1 = bfsplit(tile[ck+1][rn]);
        unsigned p2 = bfsplit(tile[ck+2][rn]);
        unsigned p3 = bfsplit(tile[ck+3][rn]);
        ushort4v h, l;
        h.x = (ushort)p0; l.x = (ushort)(p0 >> 16);
        h.y = (ushort)p1; l.y = (ushort)(p1 >> 16);
        h.z = (ushort)p2; l.z = (ushort)(p2 >> 16);
        h.w = (ushort)p3; l.w = (ushort)(p3 >> 16);
        *(ushort4v*)(hiT + (size_t)(n0 + rn) * K + k0 + ck) = h;
        *(ushort4v*)(loT + (size_t)(n0 + rn) * K + k0 + ck) = l;
    }
}

// ---------------------------------------------------------------------------
// Kernel 4: Gram/scores, fp32, 128x128 tile, 8x8 per thread, BK=16.
// S[b][i][j] = x2[b][j] - 2*dot(x_i,x_j), diag=+inf.
// ---------------------------------------------------------------------------
#define GP 132
__global__ __launch_bounds__(256) void gram128_kernel(const float* __restrict__ x,
                                                      const float* __restrict__ x2,
                                                      float* __restrict__ S) {
    int b = blockIdx.z;
    const float* A = x + (size_t)b * NPTS * CDIM;
    float* Sb = S + (size_t)b * NPTS * NPTS;
    const float* x2b = x2 + (size_t)b * NPTS;

    __shared__ float As[16][GP];
    __shared__ float Bs[16][GP];

    int bi = blockIdx.y * 128;
    int bj = blockIdx.x * 128;
    int tx = threadIdx.x & 15;
    int ty = threadIdx.x >> 4;
    int row0 = ty * 8, col0 = tx * 8;

    float acc[8][8] = {};

    for (int k0 = 0; k0 < CDIM; k0 += 16) {
        #pragma unroll
        for (int i = 0; i < 2; ++i) {
            int f = threadIdx.x + i * 256;      // 0..511
            int r = f & 127, cq = f >> 7;       // cq 0..3
            float4 v = *(const float4*)(A + (size_t)(bi + r) * CDIM + k0 + cq*4);
            As[cq*4+0][r] = v.x; As[cq*4+1][r] = v.y;
            As[cq*4+2][r] = v.z; As[cq*4+3][r] = v.w;
            float4 w = *(const float4*)(A + (size_t)(bj + r) * CDIM + k0 + cq*4);
            Bs[cq*4+0][r] = w.x; Bs[cq*4+1][r] = w.y;
            Bs[cq*4+2][r] = w.z; Bs[cq*4+3][r] = w.w;
        }
        __syncthreads();
        #pragma unroll
        for (int k = 0; k < 16; ++k) {
            float a[8], bv[8];
            *(float4*)&a[0]  = *(const float4*)&As[k][row0];
            *(float4*)&a[4]  = *(const float4*)&As[k][row0+4];
            *(float4*)&bv[0] = *(const float4*)&Bs[k][col0];
            *(float4*)&bv[4] = *(const float4*)&Bs[k][col0+4];
            #pragma unroll
            for (int u = 0; u < 8; ++u)
                #pragma unroll
                for (int w = 0; w < 8; ++w) acc[u][w] += a[u] * bv[w];
        }
        __syncthreads();
    }

    #pragma unroll
    for (int u = 0; u < 8; ++u) {
        int row = bi + row0 + u;
        #pragma unroll
        for (int w4 = 0; w4 < 8; w4 += 4) {
            float4 o;
            float* op = (float*)&o;
            #pragma unroll
            for (int j = 0; j < 4; ++j) {
                int col = bj + col0 + w4 + j;
                float val = x2b[col] - 2.0f * acc[u][w4+j];
                if (row == col) val = __builtin_inff();
                op[j] = val;
            }
            *(float4*)(Sb + (size_t)row * NPTS + bj + col0 + w4) = o;
        }
    }
}

// ---------------------------------------------------------------------------
// Kernel 5: per-row exact top-KNN via 4x8-bit radix select.
// ---------------------------------------------------------------------------
__device__ __forceinline__ unsigned block_excl_scan_256(unsigned c,
                                                        unsigned* wsum,
                                                        unsigned* total_out) {
    unsigned v = c;
    #pragma unroll
    for (int o = 1; o < 64; o <<= 1) {
        unsigned t = __shfl_up(v, o);
        if ((threadIdx.x & 63) >= o) v += t;
    }
    if ((threadIdx.x & 63) == 63) wsum[threadIdx.x >> 6] = v;
    __syncthreads();
    unsigned woff = 0;
    int mywave = threadIdx.x >> 6;
    #pragma unroll
    for (int w = 0; w < 4; ++w) {
        unsigned s = wsum[w];
        if (w < mywave) woff += s;
    }
    if (total_out) *total_out = wsum[0] + wsum[1] + wsum[2] + wsum[3];
    __syncthreads();
    return v + woff - c;
}

__global__ __launch_bounds__(256) void knn_radix_kernel(const float* __restrict__ S,
                                                        int* __restrict__ idx) {
    int n = blockIdx.x, b = blockIdx.y;
    const float* row = S + ((size_t)b * NPTS + n) * NPTS;
    int* out = idx + ((size_t)b * NPTS + n) * KNN;

    __shared__ unsigned keys[NPTS];
    __shared__ unsigned hist[256];
    __shared__ unsigned wsum[4];
    __shared__ unsigned sh_below, sh_sel;
    __shared__ int eqlist[64];

    for (int i = threadIdx.x; i < NPTS; i += 256) {
        unsigned u = __float_as_uint(row[i]);
        u = (u & 0x80000000u) ? ~u : (u | 0x80000000u);
        keys[i] = u;
    }
    __syncthreads();

    unsigned prefix = 0, pmask = 0;
    int rank = KNN;
    #pragma unroll
    for (int pass = 0; pass < 4; ++pass) {
        int shift = 24 - pass * 8;
        hist[threadIdx.x] = 0;
        __syncthreads();
        for (int i = threadIdx.x; i < NPTS; i += 256) {
            unsigned u = keys[i];
            if ((u & pmask) == prefix)
                atomicAdd(&hist[(u >> shift) & 0xffu], 1u);
        }
        __syncthreads();
        unsigned c = hist[threadIdx.x];
        unsigned excl = block_excl_scan_256(c, wsum, nullptr);
        if (excl < (unsigned)rank && excl + c >= (unsigned)rank) {
            sh_below = excl;
            sh_sel   = (unsigned)threadIdx.x;
        }
        __syncthreads();
        rank   -= (int)sh_below;
        prefix |= sh_sel << shift;
        pmask  |= 0xffu << shift;
        __syncthreads();
    }
    unsigned pivot = prefix;

    unsigned lt = 0, eq = 0;
    for (int i = threadIdx.x; i < NPTS; i += 256) {
        unsigned u = keys[i];
        lt += (u < pivot) ? 1u : 0u;
        eq += (u == pivot) ? 1u : 0u;
    }
    unsigned total = 0;
    unsigned excl = block_excl_scan_256(lt | (eq << 16), wsum, &total);
    unsigned lt_base = excl & 0xffffu;
    unsigned eq_base = excl >> 16;
    unsigned eq_total = total >> 16;

    for (int i = threadIdx.x; i < NPTS; i += 256) {
        unsigned u = keys[i];
        if (u < pivot) {
            out[lt_base++] = i;
        } else if (u == pivot) {
            if (eq_base < 64) eqlist[eq_base] = i;
            eq_base++;
        }
    }
    __syncthreads();

    if (threadIdx.x == 0) {
        int base = KNN - rank;
        int m = (int)(eq_total < 64u ? eq_total : 64u);
        for (int t = 0; t < rank; ++t) {
            int best = 0x7fffffff, bj = -1;
            for (int j = 0; j < m; ++j) {
                int v = eqlist[j];
                if (v >= 0 && v < best) { best = v; bj = j; }
            }
            out[base + t] = best;
            if (bj >= 0) eqlist[bj] = -1;
        }
    }
}

// ---------------------------------------------------------------------------
// Kernel 6: split-bf16 MFMA GEMM.
// C[M][N] fp32 = A @ B (+bias), A given as Ahi/Alo [M][K] bf16,
// B given as BhiT/BloT [N][K] bf16 (pre-transposed).
// 3 products per fragment pair: hh + hl + lh into one fp32 accumulator.
// 128x128 tile, BK=32, 4 waves (2x2), 4x4 16x16 frags per wave.
// ---------------------------------------------------------------------------
__global__ __launch_bounds__(256) void mfma_split_gemm(const ushort* __restrict__ Ahi,
                                                       const ushort* __restrict__ Alo,
                                                       const ushort* __restrict__ BhiT,
                                                       const ushort* __restrict__ BloT,
                                                       const float* __restrict__ bias,
                                                       float* __restrict__ C,
                                                       int M, int N, int K) {
    // padded stride 40 ushort (80B): b128-aligned, spreads banks
    __shared__ ushort ldsAh[128*40];
    __shared__ ushort ldsAl[128*40];
    __shared__ ushort ldsBh[128*40];
    __shared__ ushort ldsBl[128*40];

    int bi = blockIdx.y * 128, bj = blockIdx.x * 128;
    int lane = threadIdx.x & 63, wave = threadIdx.x >> 6;
    int wr = wave >> 1, wc = wave & 1;
    int fr = lane & 15, kg = lane >> 4;

    floatx4 acc[4][4] = {};

    int srow = threadIdx.x >> 1;          // 0..127
    int sseg = (threadIdx.x & 1) * 16;    // 0 / 16 (bf16 elems)

    const ushort* s0 = Ahi  + (size_t)(bi + srow) * K + sseg;
    const ushort* s1 = Alo  + (size_t)(bi + srow) * K + sseg;
    const ushort* s2 = BhiT + (size_t)(bj + srow) * K + sseg;
    const ushort* s3 = BloT + (size_t)(bj + srow) * K + sseg;
    ushort* d0 = &ldsAh[srow*40 + sseg];
    ushort* d1 = &ldsAl[srow*40 + sseg];
    ushort* d2 = &ldsBh[srow*40 + sseg];
    ushort* d3 = &ldsBl[srow*40 + sseg];

    for (int k0 = 0; k0 < K; k0 += 32) {
        uint4 va0 = *(const uint4*)(s0 + k0);
        uint4 va1 = *(const uint4*)(s0 + k0 + 8);
        uint4 vb0 = *(const uint4*)(s1 + k0);
        uint4 vb1 = *(const uint4*)(s1 + k0 + 8);
        uint4 vc0 = *(const uint4*)(s2 + k0);
        uint4 vc1 = *(const uint4*)(s2 + k0 + 8);
        uint4 vd0 = *(const uint4*)(s3 + k0);
        uint4 vd1 = *(const uint4*)(s3 + k0 + 8);
        *(uint4*)(d0)     = va0;  *(uint4*)(d0 + 8) = va1;
        *(uint4*)(d1)     = vb0;  *(uint4*)(d1 + 8) = vb1;
        *(uint4*)(d2)     = vc0;  *(uint4*)(d2 + 8) = vc1;
        *(uint4*)(d3)     = vd0;  *(uint4*)(d3 + 8) = vd1;
        __syncthreads();

        short8 a_h[4], a_l[4], b_h[4], b_l[4];
        #pragma unroll
        for (int m = 0; m < 4; ++m) {
            int row = wr*64 + m*16 + fr;
            a_h[m] = *(const short8*)&ldsAh[row*40 + kg*8];
            a_l[m] = *(const short8*)&ldsAl[row*40 + kg*8];
        }
        #pragma unroll
        for (int n = 0; n < 4; ++n) {
            int col = wc*64 + n*16 + fr;
            b_h[n] = *(const short8*)&ldsBh[col*40 + kg*8];
            b_l[n] = *(const short8*)&ldsBl[col*40 + kg*8];
        }
        #pragma unroll
        for (int m = 0; m < 4; ++m)
            #pragma unroll
            for (int n = 0; n < 4; ++n) {
                acc[m][n] = __builtin_amdgcn_mfma_f32_16x16x32_bf16(a_h[m], b_h[n], acc[m][n], 0, 0, 0);
                acc[m][n] = __builtin_amdgcn_mfma_f32_16x16x32_bf16(a_h[m], b_l[n], acc[m][n], 0, 0, 0);
                acc[m][n] = __builtin_amdgcn_mfma_f32_16x16x32_bf16(a_l[m], b_h[n], acc[m][n], 0, 0, 0);
            }
        __syncthreads();
    }

    #pragma unroll
    for (int m = 0; m < 4; ++m)
        #pragma unroll
        for (int n = 0; n < 4; ++n) {
            int col = bj + wc*64 + n*16 + fr;
            float bv = bias ? bias[col] : 0.0f;
            #pragma unroll
            for (int r = 0; r < 4; ++r) {
                int row = bi + wr*64 + m*16 + kg*4 + r;
                C[(size_t)row * N + col] = acc[m][n][r] + bv;
            }
        }
}

// ---------------------------------------------------------------------------
// Kernel 7: sparse graph attention; writes output pre-split (hi/lo bf16).
// ---------------------------------------------------------------------------
__global__ __launch_bounds__(256) void attn_kernel(const float* __restrict__ qkv,
                                                   const int* __restrict__ idx,
                                                   ushort* __restrict__ ahi,
                                                   ushort* __restrict__ alo) {
    int n = blockIdx.x, b = blockIdx.y;
    size_t rowoff = ((size_t)b * NPTS + n);
    const float* qrowbase = qkv + rowoff * TRIPLE;
    const float* kbase = qkv + (size_t)b * NPTS * TRIPLE + INNER;
    const float* vbase = qkv + (size_t)b * NPTS * TRIPLE + 2*INNER;

    __shared__ int   nb[KNN];
    __shared__ float p[NHEAD][KNN];

    if (threadIdx.x < KNN)
        nb[threadIdx.x] = idx[rowoff * KNN + threadIdx.x];
    __syncthreads();

    int hd = threadIdx.x >> 5;
    int j  = threadIdx.x & 31;

    {
        int m = nb[j];
        const float* krow = kbase + (size_t)m * TRIPLE + hd * DHEAD;
        const float* qrow = qrowbase + hd * DHEAD;
        float dot = 0.f;
        #pragma unroll
        for (int d = 0; d < DHEAD; ++d) dot += qrow[d] * krow[d];
        dot *= SCALE;
        float mx = dot;
        for (int o = 16; o; o >>= 1) mx = fmaxf(mx, __shfl_xor(mx, o));
        float e = expf(dot - mx);
        float s = e;
        for (int o = 16; o; o >>= 1) s += __shfl_xor(s, o);
        p[hd][j] = e / s;
    }
    __syncthreads();

    {
        float o0 = 0.f, o1 = 0.f;
        #pragma unroll 8
        for (int jj = 0; jj < KNN; ++jj) {
            int mm = nb[jj];
            const float* vrow = vbase + (size_t)mm * TRIPLE + hd * DHEAD;
            float pw = p[hd][jj];
            o0 += pw * vrow[j];
            o1 += pw * vrow[j + 32];
        }
        size_t base = rowoff * INNER + hd * DHEAD;
        unsigned q0 = bfsplit(o0);
        unsigned q1 = bfsplit(o1);
        ahi[base + j]      = (ushort)q0;  alo[base + j]      = (ushort)(q0 >> 16);
        ahi[base + j + 32] = (ushort)q1;  alo[base + j + 32] = (ushort)(q1 >> 16);
    }
}

// ---------------------------------------------------------------------------
extern "C" void kernel_launch(void* const* d_in, const int* in_sizes, int n_in,
                              void* d_out, int out_size, void* d_ws, size_t ws_size,
                              hipStream_t stream) {
    const float* x    = (const float*)d_in[0];   // [2,2048,256]
    const float* Wqkv = (const float*)d_in[1];   // [256,1536]
    const float* Wout = (const float*)d_in[2];   // [512,256]
    const float* bout = (const float*)d_in[3];   // [256]
    float* out = (float*)d_out;                  // [2,2048,256]

    // workspace layout
    float* S    = (float*)d_ws;                           // 8,388,608 f32
    float* x2   = S + (size_t)BATCH * NPTS * NPTS;        // 4096 f32
    int*   idx  = (int*)(x2 + (size_t)BATCH * NPTS);      // 131072 int
    float* qkv  = (float*)(idx + (size_t)BATCH * NPTS * KNN);   // 6,291,456 f32
    ushort* xhi = (ushort*)(qkv + (size_t)BATCH * NPTS * TRIPLE);
    ushort* xlo   = xhi   + (size_t)BATCH * NPTS * CDIM;  // 1,048,576 each
    ushort* ahi   = xlo   + (size_t)BATCH * NPTS * CDIM;  // 2,097,152 each
    ushort* alo   = ahi   + (size_t)BATCH * NPTS * INNER;
    ushort* wqhiT = alo   + (size_t)BATCH * NPTS * INNER; // [1536][256]
    ushort* wqloT = wqhiT + (size_t)TRIPLE * CDIM;
    ushort* wohiT = wqloT + (size_t)TRIPLE * CDIM;        // [256][512]
    ushort* woloT = wohiT + (size_t)CDIM * INNER;

    // 1. row squared norms
    rowsq_kernel<<<BATCH * NPTS, 64, 0, stream>>>(x, x2);

    // 2. split x -> bf16 hi/lo
    {
        int n = BATCH * NPTS * CDIM;
        split_kernel<<<n / 1024, 256, 0, stream>>>(x, xhi, xlo, n);
    }

    // 3. transpose+split weights
    {
        dim3 g1(TRIPLE / 64, CDIM / 64);
        wtrans_split_kernel<<<g1, 256, 0, stream>>>(Wqkv, wqhiT, wqloT, CDIM, TRIPLE);
        dim3 g2(CDIM / 64, INNER / 64);
        wtrans_split_kernel<<<g2, 256, 0, stream>>>(Wout, wohiT, woloT, INNER, CDIM);
    }

    // 4. Gram/scores (fp32 — selection-critical)
    {
        dim3 grid(NPTS / 128, NPTS / 128, BATCH);
        gram128_kernel<<<grid, 256, 0, stream>>>(x, x2, S);
    }

    // 5. top-32 neighbor selection
    {
        dim3 grid(NPTS, BATCH);
        knn_radix_kernel<<<grid, 256, 0, stream>>>(S, idx);
    }

    // 6. qkv projection: [4096,256] @ [256,1536] via split-bf16 MFMA
    {
        dim3 grid(TRIPLE / 128, (BATCH * NPTS) / 128);
        mfma_split_gemm<<<grid, 256, 0, stream>>>(xhi, xlo, wqhiT, wqloT,
                                                  nullptr, qkv,
                                                  BATCH * NPTS, TRIPLE, CDIM);
    }

    // 7. sparse attention -> pre-split hi/lo
    {
        dim3 grid(NPTS, BATCH);
        attn_kernel<<<grid, 256, 0, stream>>>(qkv, idx, ahi, alo);
    }

    // 8. output projection: [4096,512] @ [512,256] + bias
    {
        dim3 grid(CDIM / 128, (BATCH * NPTS) / 128);
        mfma_split_gemm<<<grid, 256, 0, stream>>>(ahi, alo, wohiT, woloT,
                                                  bout, out,
                                                  BATCH * NPTS, CDIM, INNER);
    }
}

// Round 5
// 204.727 us; speedup vs baseline: 2.1404x; 1.2382x over previous
//
#include <hip/hip_runtime.h>
#include <hip/hip_bf16.h>

// Problem constants
#define BATCH 2
#define NPTS  2048
#define CDIM  256
#define NHEAD 8
#define DHEAD 64
#define INNER 512            // NHEAD*DHEAD
#define TRIPLE 1536          // 3*INNER
#define KNN   32
#define SCALE 0.125f         // 64^-0.5

typedef __attribute__((ext_vector_type(8))) short short8;      // 8 bf16 (4 VGPR)
typedef __attribute__((ext_vector_type(4))) float floatx4;     // MFMA acc
typedef __attribute__((ext_vector_type(4))) unsigned short ushort4v;
typedef unsigned short ushort;

// bf16 split: x = hi + lo (both RNE bf16), residual ~2^-18 relative.
// Returns hi in bits [15:0], lo in bits [31:16].
__device__ __forceinline__ unsigned bfsplit(float x) {
    unsigned u = __float_as_uint(x);
    unsigned r = u + 0x7fffu + ((u >> 16) & 1u);
    unsigned hs = r >> 16;
    float hf = __uint_as_float(hs << 16);
    float lo = x - hf;
    unsigned u2 = __float_as_uint(lo);
    unsigned r2 = u2 + 0x7fffu + ((u2 >> 16) & 1u);
    return (hs & 0xffffu) | (r2 & 0xffff0000u);
}

// 3-component split: x = h + l + q, residual ~2^-27 relative.
__device__ __forceinline__ void bfsplit3(float x, ushort* hh, ushort* ll, ushort* qq) {
    unsigned u = __float_as_uint(x);
    unsigned r = u + 0x7fffu + ((u >> 16) & 1u);
    unsigned hs = r >> 16;
    float hf = __uint_as_float(hs << 16);
    float d1 = x - hf;
    unsigned u2 = __float_as_uint(d1);
    unsigned r2 = u2 + 0x7fffu + ((u2 >> 16) & 1u);
    unsigned ls = r2 >> 16;
    float lf = __uint_as_float(ls << 16);
    float d2 = d1 - lf;
    unsigned u3 = __float_as_uint(d2);
    unsigned r3 = u3 + 0x7fffu + ((u3 >> 16) & 1u);
    *hh = (ushort)hs;
    *ll = (ushort)ls;
    *qq = (ushort)(r3 >> 16);
}

// ---------------------------------------------------------------------------
// Kernel 1: row squared norms
// ---------------------------------------------------------------------------
__global__ __launch_bounds__(64) void rowsq_kernel(const float* __restrict__ x,
                                                   float* __restrict__ x2) {
    int row = blockIdx.x;
    const float4* p = (const float4*)(x + (size_t)row * CDIM);
    float4 v = p[threadIdx.x];
    float s = v.x*v.x + v.y*v.y + v.z*v.z + v.w*v.w;
    for (int o = 32; o; o >>= 1) s += __shfl_down(s, o);
    if (threadIdx.x == 0) x2[row] = s;
}

// ---------------------------------------------------------------------------
// Kernel 2: elementwise fp32 -> bf16 3-way split (h, l, q)
// ---------------------------------------------------------------------------
__global__ __launch_bounds__(256) void split3_kernel(const float* __restrict__ src,
                                                     ushort* __restrict__ hi,
                                                     ushort* __restrict__ lo,
                                                     ushort* __restrict__ qd,
                                                     int n) {
    int i = (blockIdx.x * 256 + threadIdx.x) * 4;
    if (i >= n) return;
    float4 v = *(const float4*)(src + i);
    ushort h[4], l[4], q[4];
    bfsplit3(v.x, &h[0], &l[0], &q[0]);
    bfsplit3(v.y, &h[1], &l[1], &q[1]);
    bfsplit3(v.z, &h[2], &l[2], &q[2]);
    bfsplit3(v.w, &h[3], &l[3], &q[3]);
    *(ushort4v*)(hi + i) = *(ushort4v*)h;
    *(ushort4v*)(lo + i) = *(ushort4v*)l;
    *(ushort4v*)(qd + i) = *(ushort4v*)q;
}

// ---------------------------------------------------------------------------
// Kernel 3: W [K][N] fp32 -> hi/lo bf16 transposed [N][K]
// ---------------------------------------------------------------------------
__global__ __launch_bounds__(256) void wtrans_split_kernel(const float* __restrict__ W,
                                                           ushort* __restrict__ hiT,
                                                           ushort* __restrict__ loT,
                                                           int K, int N) {
    __shared__ float tile[64][65];
    int k0 = blockIdx.y * 64, n0 = blockIdx.x * 64;
    #pragma unroll
    for (int i = 0; i < 4; ++i) {
        int f = threadIdx.x + i * 256;      // 0..1023
        int r = f >> 4, c4 = (f & 15) * 4;
        float4 v = *(const float4*)(W + (size_t)(k0 + r) * N + n0 + c4);
        tile[r][c4+0] = v.x; tile[r][c4+1] = v.y;
        tile[r][c4+2] = v.z; tile[r][c4+3] = v.w;
    }
    __syncthreads();
    #pragma unroll
    for (int i = 0; i < 4; ++i) {
        int f = threadIdx.x + i * 256;
        int rn = f >> 4, ck = (f & 15) * 4;
        unsigned p0 = bfsplit(tile[ck+0][rn]);
        unsigned p1 = bfsplit(tile[ck+1][rn]);
        unsigned p2 = bfsplit(tile[ck+2][rn]);
        unsigned p3 = bfsplit(tile[ck+3][rn]);
        ushort4v h, l;
        h.x = (ushort)p0; l.x = (ushort)(p0 >> 16);
        h.y = (ushort)p1; l.y = (ushort)(p1 >> 16);
        h.z = (ushort)p2; l.z = (ushort)(p2 >> 16);
        h.w = (ushort)p3; l.w = (ushort)(p3 >> 16);
        *(ushort4v*)(hiT + (size_t)(n0 + rn) * K + k0 + ck) = h;
        *(ushort4v*)(loT + (size_t)(n0 + rn) * K + k0 + ck) = l;
    }
}

// ---------------------------------------------------------------------------
// Kernel 4: Gram/scores via 3-split bf16 MFMA (6 products = fp32 precision).
// S[b][i][j] = x2[b][j] - 2*dot(x_i,x_j), diag=+inf.
// 128x128 tile, BK=32, 4 waves (2x2), 4x4 16x16x32 frags per wave.
// ---------------------------------------------------------------------------
#define LSTR 40   // LDS row stride in ushort (80 B)
__global__ __launch_bounds__(256) void gram_mfma_kernel(const ushort* __restrict__ xh,
                                                        const ushort* __restrict__ xl,
                                                        const ushort* __restrict__ xq,
                                                        const float* __restrict__ x2,
                                                        float* __restrict__ S) {
    int b = blockIdx.z;
    size_t xoff = (size_t)b * NPTS * CDIM;
    const ushort* Ah = xh + xoff;
    const ushort* Al = xl + xoff;
    const ushort* Aq = xq + xoff;
    float* Sb = S + (size_t)b * NPTS * NPTS;
    const float* x2b = x2 + (size_t)b * NPTS;

    __shared__ ushort A_[3][128*LSTR];
    __shared__ ushort B_[3][128*LSTR];

    int bi = blockIdx.y * 128, bj = blockIdx.x * 128;
    int lane = threadIdx.x & 63, wave = threadIdx.x >> 6;
    int wr = wave >> 1, wc = wave & 1;
    int fr = lane & 15, kg = lane >> 4;

    floatx4 acc[4][4] = {};

    int srow = threadIdx.x >> 1;          // 0..127
    int sseg = (threadIdx.x & 1) * 16;    // 0 / 16 (bf16 elems)

    const ushort* sAh = Ah + (size_t)(bi + srow) * CDIM + sseg;
    const ushort* sAl = Al + (size_t)(bi + srow) * CDIM + sseg;
    const ushort* sAq = Aq + (size_t)(bi + srow) * CDIM + sseg;
    const ushort* sBh = Ah + (size_t)(bj + srow) * CDIM + sseg;
    const ushort* sBl = Al + (size_t)(bj + srow) * CDIM + sseg;
    const ushort* sBq = Aq + (size_t)(bj + srow) * CDIM + sseg;
    int dof = srow * LSTR + sseg;

    for (int k0 = 0; k0 < CDIM; k0 += 32) {
        uint4 a0 = *(const uint4*)(sAh + k0); uint4 a1 = *(const uint4*)(sAh + k0 + 8);
        uint4 b0 = *(const uint4*)(sAl + k0); uint4 b1 = *(const uint4*)(sAl + k0 + 8);
        uint4 c0 = *(const uint4*)(sAq + k0); uint4 c1 = *(const uint4*)(sAq + k0 + 8);
        uint4 d0 = *(const uint4*)(sBh + k0); uint4 d1 = *(const uint4*)(sBh + k0 + 8);
        uint4 e0 = *(const uint4*)(sBl + k0); uint4 e1 = *(const uint4*)(sBl + k0 + 8);
        uint4 f0 = *(const uint4*)(sBq + k0); uint4 f1 = *(const uint4*)(sBq + k0 + 8);
        *(uint4*)&A_[0][dof] = a0; *(uint4*)&A_[0][dof+8] = a1;
        *(uint4*)&A_[1][dof] = b0; *(uint4*)&A_[1][dof+8] = b1;
        *(uint4*)&A_[2][dof] = c0; *(uint4*)&A_[2][dof+8] = c1;
        *(uint4*)&B_[0][dof] = d0; *(uint4*)&B_[0][dof+8] = d1;
        *(uint4*)&B_[1][dof] = e0; *(uint4*)&B_[1][dof+8] = e1;
        *(uint4*)&B_[2][dof] = f0; *(uint4*)&B_[2][dof+8] = f1;
        __syncthreads();

        short8 a_h[4], a_l[4], a_q[4], b_h[4], b_l[4], b_q[4];
        #pragma unroll
        for (int m = 0; m < 4; ++m) {
            int off = (wr*64 + m*16 + fr) * LSTR + kg*8;
            a_h[m] = *(const short8*)&A_[0][off];
            a_l[m] = *(const short8*)&A_[1][off];
            a_q[m] = *(const short8*)&A_[2][off];
        }
        #pragma unroll
        for (int n = 0; n < 4; ++n) {
            int off = (wc*64 + n*16 + fr) * LSTR + kg*8;
            b_h[n] = *(const short8*)&B_[0][off];
            b_l[n] = *(const short8*)&B_[1][off];
            b_q[n] = *(const short8*)&B_[2][off];
        }
        #pragma unroll
        for (int m = 0; m < 4; ++m)
            #pragma unroll
            for (int n = 0; n < 4; ++n) {
                acc[m][n] = __builtin_amdgcn_mfma_f32_16x16x32_bf16(a_h[m], b_h[n], acc[m][n], 0, 0, 0);
                acc[m][n] = __builtin_amdgcn_mfma_f32_16x16x32_bf16(a_h[m], b_l[n], acc[m][n], 0, 0, 0);
                acc[m][n] = __builtin_amdgcn_mfma_f32_16x16x32_bf16(a_l[m], b_h[n], acc[m][n], 0, 0, 0);
                acc[m][n] = __builtin_amdgcn_mfma_f32_16x16x32_bf16(a_l[m], b_l[n], acc[m][n], 0, 0, 0);
                acc[m][n] = __builtin_amdgcn_mfma_f32_16x16x32_bf16(a_h[m], b_q[n], acc[m][n], 0, 0, 0);
                acc[m][n] = __builtin_amdgcn_mfma_f32_16x16x32_bf16(a_q[m], b_h[n], acc[m][n], 0, 0, 0);
            }
        __syncthreads();
    }

    #pragma unroll
    for (int m = 0; m < 4; ++m)
        #pragma unroll
        for (int n = 0; n < 4; ++n) {
            int col = bj + wc*64 + n*16 + fr;
            float xc = x2b[col];
            #pragma unroll
            for (int r = 0; r < 4; ++r) {
                int row = bi + wr*64 + m*16 + kg*4 + r;
                float val = xc - 2.0f * acc[m][n][r];
                if (row == col) val = __builtin_inff();
                Sb[(size_t)row * NPTS + col] = val;
            }
        }
}

// ---------------------------------------------------------------------------
// Kernel 5: per-row exact top-KNN via 4x8-bit radix select.
// ---------------------------------------------------------------------------
__device__ __forceinline__ unsigned block_excl_scan_256(unsigned c,
                                                        unsigned* wsum,
                                                        unsigned* total_out) {
    unsigned v = c;
    #pragma unroll
    for (int o = 1; o < 64; o <<= 1) {
        unsigned t = __shfl_up(v, o);
        if ((threadIdx.x & 63) >= o) v += t;
    }
    if ((threadIdx.x & 63) == 63) wsum[threadIdx.x >> 6] = v;
    __syncthreads();
    unsigned woff = 0;
    int mywave = threadIdx.x >> 6;
    #pragma unroll
    for (int w = 0; w < 4; ++w) {
        unsigned s = wsum[w];
        if (w < mywave) woff += s;
    }
    if (total_out) *total_out = wsum[0] + wsum[1] + wsum[2] + wsum[3];
    __syncthreads();
    return v + woff - c;
}

__global__ __launch_bounds__(256) void knn_radix_kernel(const float* __restrict__ S,
                                                        int* __restrict__ idx) {
    int n = blockIdx.x, b = blockIdx.y;
    const float* row = S + ((size_t)b * NPTS + n) * NPTS;
    int* out = idx + ((size_t)b * NPTS + n) * KNN;

    __shared__ unsigned keys[NPTS];
    __shared__ unsigned hist[256];
    __shared__ unsigned wsum[4];
    __shared__ unsigned sh_below, sh_sel;
    __shared__ int eqlist[64];

    for (int i = threadIdx.x; i < NPTS; i += 256) {
        unsigned u = __float_as_uint(row[i]);
        u = (u & 0x80000000u) ? ~u : (u | 0x80000000u);
        keys[i] = u;
    }
    __syncthreads();

    unsigned prefix = 0, pmask = 0;
    int rank = KNN;
    #pragma unroll
    for (int pass = 0; pass < 4; ++pass) {
        int shift = 24 - pass * 8;
        hist[threadIdx.x] = 0;
        __syncthreads();
        for (int i = threadIdx.x; i < NPTS; i += 256) {
            unsigned u = keys[i];
            if ((u & pmask) == prefix)
                atomicAdd(&hist[(u >> shift) & 0xffu], 1u);
        }
        __syncthreads();
        unsigned c = hist[threadIdx.x];
        unsigned excl = block_excl_scan_256(c, wsum, nullptr);
        if (excl < (unsigned)rank && excl + c >= (unsigned)rank) {
            sh_below = excl;
            sh_sel   = (unsigned)threadIdx.x;
        }
        __syncthreads();
        rank   -= (int)sh_below;
        prefix |= sh_sel << shift;
        pmask  |= 0xffu << shift;
        __syncthreads();
    }
    unsigned pivot = prefix;

    unsigned lt = 0, eq = 0;
    for (int i = threadIdx.x; i < NPTS; i += 256) {
        unsigned u = keys[i];
        lt += (u < pivot) ? 1u : 0u;
        eq += (u == pivot) ? 1u : 0u;
    }
    unsigned total = 0;
    unsigned excl = block_excl_scan_256(lt | (eq << 16), wsum, &total);
    unsigned lt_base = excl & 0xffffu;
    unsigned eq_base = excl >> 16;
    unsigned eq_total = total >> 16;

    for (int i = threadIdx.x; i < NPTS; i += 256) {
        unsigned u = keys[i];
        if (u < pivot) {
            out[lt_base++] = i;
        } else if (u == pivot) {
            if (eq_base < 64) eqlist[eq_base] = i;
            eq_base++;
        }
    }
    __syncthreads();

    if (threadIdx.x == 0) {
        int base = KNN - rank;
        int m = (int)(eq_total < 64u ? eq_total : 64u);
        for (int t = 0; t < rank; ++t) {
            int best = 0x7fffffff, bj = -1;
            for (int j = 0; j < m; ++j) {
                int v = eqlist[j];
                if (v >= 0 && v < best) { best = v; bj = j; }
            }
            out[base + t] = best;
            if (bj >= 0) eqlist[bj] = -1;
        }
    }
}

// ---------------------------------------------------------------------------
// Kernel 6: split-bf16 MFMA GEMM (hi/lo, 3 products).
// ---------------------------------------------------------------------------
__global__ __launch_bounds__(256) void mfma_split_gemm(const ushort* __restrict__ Ahi,
                                                       const ushort* __restrict__ Alo,
                                                       const ushort* __restrict__ BhiT,
                                                       const ushort* __restrict__ BloT,
                                                       const float* __restrict__ bias,
                                                       float* __restrict__ C,
                                                       int M, int N, int K) {
    __shared__ ushort ldsAh[128*LSTR];
    __shared__ ushort ldsAl[128*LSTR];
    __shared__ ushort ldsBh[128*LSTR];
    __shared__ ushort ldsBl[128*LSTR];

    int bi = blockIdx.y * 128, bj = blockIdx.x * 128;
    int lane = threadIdx.x & 63, wave = threadIdx.x >> 6;
    int wr = wave >> 1, wc = wave & 1;
    int fr = lane & 15, kg = lane >> 4;

    floatx4 acc[4][4] = {};

    int srow = threadIdx.x >> 1;
    int sseg = (threadIdx.x & 1) * 16;

    const ushort* s0 = Ahi  + (size_t)(bi + srow) * K + sseg;
    const ushort* s1 = Alo  + (size_t)(bi + srow) * K + sseg;
    const ushort* s2 = BhiT + (size_t)(bj + srow) * K + sseg;
    const ushort* s3 = BloT + (size_t)(bj + srow) * K + sseg;
    ushort* d0 = &ldsAh[srow*LSTR + sseg];
    ushort* d1 = &ldsAl[srow*LSTR + sseg];
    ushort* d2 = &ldsBh[srow*LSTR + sseg];
    ushort* d3 = &ldsBl[srow*LSTR + sseg];

    for (int k0 = 0; k0 < K; k0 += 32) {
        uint4 va0 = *(const uint4*)(s0 + k0);
        uint4 va1 = *(const uint4*)(s0 + k0 + 8);
        uint4 vb0 = *(const uint4*)(s1 + k0);
        uint4 vb1 = *(const uint4*)(s1 + k0 + 8);
        uint4 vc0 = *(const uint4*)(s2 + k0);
        uint4 vc1 = *(const uint4*)(s2 + k0 + 8);
        uint4 vd0 = *(const uint4*)(s3 + k0);
        uint4 vd1 = *(const uint4*)(s3 + k0 + 8);
        *(uint4*)(d0)     = va0;  *(uint4*)(d0 + 8) = va1;
        *(uint4*)(d1)     = vb0;  *(uint4*)(d1 + 8) = vb1;
        *(uint4*)(d2)     = vc0;  *(uint4*)(d2 + 8) = vc1;
        *(uint4*)(d3)     = vd0;  *(uint4*)(d3 + 8) = vd1;
        __syncthreads();

        short8 a_h[4], a_l[4], b_h[4], b_l[4];
        #pragma unroll
        for (int m = 0; m < 4; ++m) {
            int off = (wr*64 + m*16 + fr) * LSTR + kg*8;
            a_h[m] = *(const short8*)&ldsAh[off];
            a_l[m] = *(const short8*)&ldsAl[off];
        }
        #pragma unroll
        for (int n = 0; n < 4; ++n) {
            int off = (wc*64 + n*16 + fr) * LSTR + kg*8;
            b_h[n] = *(const short8*)&ldsBh[off];
            b_l[n] = *(const short8*)&ldsBl[off];
        }
        #pragma unroll
        for (int m = 0; m < 4; ++m)
            #pragma unroll
            for (int n = 0; n < 4; ++n) {
                acc[m][n] = __builtin_amdgcn_mfma_f32_16x16x32_bf16(a_h[m], b_h[n], acc[m][n], 0, 0, 0);
                acc[m][n] = __builtin_amdgcn_mfma_f32_16x16x32_bf16(a_h[m], b_l[n], acc[m][n], 0, 0, 0);
                acc[m][n] = __builtin_amdgcn_mfma_f32_16x16x32_bf16(a_l[m], b_h[n], acc[m][n], 0, 0, 0);
            }
        __syncthreads();
    }

    #pragma unroll
    for (int m = 0; m < 4; ++m)
        #pragma unroll
        for (int n = 0; n < 4; ++n) {
            int col = bj + wc*64 + n*16 + fr;
            float bv = bias ? bias[col] : 0.0f;
            #pragma unroll
            for (int r = 0; r < 4; ++r) {
                int row = bi + wr*64 + m*16 + kg*4 + r;
                C[(size_t)row * N + col] = acc[m][n][r] + bv;
            }
        }
}

// ---------------------------------------------------------------------------
// Kernel 7: sparse graph attention; writes output pre-split (hi/lo bf16).
// ---------------------------------------------------------------------------
__global__ __launch_bounds__(256) void attn_kernel(const float* __restrict__ qkv,
                                                   const int* __restrict__ idx,
                                                   ushort* __restrict__ ahi,
                                                   ushort* __restrict__ alo) {
    int n = blockIdx.x, b = blockIdx.y;
    size_t rowoff = ((size_t)b * NPTS + n);
    const float* qrowbase = qkv + rowoff * TRIPLE;
    const float* kbase = qkv + (size_t)b * NPTS * TRIPLE + INNER;
    const float* vbase = qkv + (size_t)b * NPTS * TRIPLE + 2*INNER;

    __shared__ int   nb[KNN];
    __shared__ float p[NHEAD][KNN];

    if (threadIdx.x < KNN)
        nb[threadIdx.x] = idx[rowoff * KNN + threadIdx.x];
    __syncthreads();

    int hd = threadIdx.x >> 5;
    int j  = threadIdx.x & 31;

    {
        int m = nb[j];
        const float* krow = kbase + (size_t)m * TRIPLE + hd * DHEAD;
        const float* qrow = qrowbase + hd * DHEAD;
        float dot = 0.f;
        #pragma unroll
        for (int d = 0; d < DHEAD; ++d) dot += qrow[d] * krow[d];
        dot *= SCALE;
        float mx = dot;
        for (int o = 16; o; o >>= 1) mx = fmaxf(mx, __shfl_xor(mx, o));
        float e = expf(dot - mx);
        float s = e;
        for (int o = 16; o; o >>= 1) s += __shfl_xor(s, o);
        p[hd][j] = e / s;
    }
    __syncthreads();

    {
        float o0 = 0.f, o1 = 0.f;
        #pragma unroll 8
        for (int jj = 0; jj < KNN; ++jj) {
            int mm = nb[jj];
            const float* vrow = vbase + (size_t)mm * TRIPLE + hd * DHEAD;
            float pw = p[hd][jj];
            o0 += pw * vrow[j];
            o1 += pw * vrow[j + 32];
        }
        size_t base = rowoff * INNER + hd * DHEAD;
        unsigned q0 = bfsplit(o0);
        unsigned q1 = bfsplit(o1);
        ahi[base + j]      = (ushort)q0;  alo[base + j]      = (ushort)(q0 >> 16);
        ahi[base + j + 32] = (ushort)q1;  alo[base + j + 32] = (ushort)(q1 >> 16);
    }
}

// ---------------------------------------------------------------------------
extern "C" void kernel_launch(void* const* d_in, const int* in_sizes, int n_in,
                              void* d_out, int out_size, void* d_ws, size_t ws_size,
                              hipStream_t stream) {
    const float* x    = (const float*)d_in[0];   // [2,2048,256]
    const float* Wqkv = (const float*)d_in[1];   // [256,1536]
    const float* Wout = (const float*)d_in[2];   // [512,256]
    const float* bout = (const float*)d_in[3];   // [256]
    float* out = (float*)d_out;                  // [2,2048,256]

    // workspace layout
    float* S    = (float*)d_ws;                           // 8,388,608 f32
    float* x2   = S + (size_t)BATCH * NPTS * NPTS;        // 4096 f32
    int*   idx  = (int*)(x2 + (size_t)BATCH * NPTS);      // 131072 int
    float* qkv  = (float*)(idx + (size_t)BATCH * NPTS * KNN);   // 6,291,456 f32
    ushort* xhi = (ushort*)(qkv + (size_t)BATCH * NPTS * TRIPLE);
    ushort* xlo   = xhi   + (size_t)BATCH * NPTS * CDIM;  // 1,048,576 each
    ushort* xqd   = xlo   + (size_t)BATCH * NPTS * CDIM;
    ushort* ahi   = xqd   + (size_t)BATCH * NPTS * CDIM;  // 2,097,152 each
    ushort* alo   = ahi   + (size_t)BATCH * NPTS * INNER;
    ushort* wqhiT = alo   + (size_t)BATCH * NPTS * INNER; // [1536][256]
    ushort* wqloT = wqhiT + (size_t)TRIPLE * CDIM;
    ushort* wohiT = wqloT + (size_t)TRIPLE * CDIM;        // [256][512]
    ushort* woloT = wohiT + (size_t)CDIM * INNER;

    // 1. row squared norms
    rowsq_kernel<<<BATCH * NPTS, 64, 0, stream>>>(x, x2);

    // 2. split x -> bf16 h/l/q
    {
        int n = BATCH * NPTS * CDIM;
        split3_kernel<<<n / 1024, 256, 0, stream>>>(x, xhi, xlo, xqd, n);
    }

    // 3. transpose+split weights
    {
        dim3 g1(TRIPLE / 64, CDIM / 64);
        wtrans_split_kernel<<<g1, 256, 0, stream>>>(Wqkv, wqhiT, wqloT, CDIM, TRIPLE);
        dim3 g2(CDIM / 64, INNER / 64);
        wtrans_split_kernel<<<g2, 256, 0, stream>>>(Wout, wohiT, woloT, INNER, CDIM);
    }

    // 4. Gram/scores via 3-split MFMA (fp32-precision, selection-safe)
    {
        dim3 grid(NPTS / 128, NPTS / 128, BATCH);
        gram_mfma_kernel<<<grid, 256, 0, stream>>>(xhi, xlo, xqd, x2, S);
    }

    // 5. top-32 neighbor selection
    {
        dim3 grid(NPTS, BATCH);
        knn_radix_kernel<<<grid, 256, 0, stream>>>(S, idx);
    }

    // 6. qkv projection: [4096,256] @ [256,1536] via split-bf16 MFMA
    {
        dim3 grid(TRIPLE / 128, (BATCH * NPTS) / 128);
        mfma_split_gemm<<<grid, 256, 0, stream>>>(xhi, xlo, wqhiT, wqloT,
                                                  nullptr, qkv,
                                                  BATCH * NPTS, TRIPLE, CDIM);
    }

    // 7. sparse attention -> pre-split hi/lo
    {
        dim3 grid(NPTS, BATCH);
        attn_kernel<<<grid, 256, 0, stream>>>(qkv, idx, ahi, alo);
    }

    // 8. output projection: [4096,512] @ [512,256] + bias
    {
        dim3 grid(CDIM / 128, (BATCH * NPTS) / 128);
        mfma_split_gemm<<<grid, 256, 0, stream>>>(ahi, alo, wohiT, woloT,
                                                  bout, out,
                                                  BATCH * NPTS, CDIM, INNER);
    }
}

// Round 6
// 173.886 us; speedup vs baseline: 2.5201x; 1.1774x over previous
//
#include <hip/hip_runtime.h>
#include <hip/hip_bf16.h>

// Problem constants
#define BATCH 2
#define NPTS  2048
#define CDIM  256
#define NHEAD 8
#define DHEAD 64
#define INNER 512            // NHEAD*DHEAD
#define TRIPLE 1536          // 3*INNER
#define KNN   32
#define SCALE 0.125f         // 64^-0.5

typedef __attribute__((ext_vector_type(8))) short short8;      // 8 bf16 (4 VGPR)
typedef __attribute__((ext_vector_type(4))) float floatx4;     // MFMA acc
typedef __attribute__((ext_vector_type(4))) unsigned short ushort4v;
typedef unsigned short ushort;

// bf16 split: x = hi + lo (both RNE bf16), residual ~2^-18 relative.
// Returns hi in bits [15:0], lo in bits [31:16].
__device__ __forceinline__ unsigned bfsplit(float x) {
    unsigned u = __float_as_uint(x);
    unsigned r = u + 0x7fffu + ((u >> 16) & 1u);
    unsigned hs = r >> 16;
    float hf = __uint_as_float(hs << 16);
    float lo = x - hf;
    unsigned u2 = __float_as_uint(lo);
    unsigned r2 = u2 + 0x7fffu + ((u2 >> 16) & 1u);
    return (hs & 0xffffu) | (r2 & 0xffff0000u);
}

// 3-component split: x = h + l + q, residual ~2^-27 relative.
__device__ __forceinline__ void bfsplit3(float x, ushort* hh, ushort* ll, ushort* qq) {
    unsigned u = __float_as_uint(x);
    unsigned r = u + 0x7fffu + ((u >> 16) & 1u);
    unsigned hs = r >> 16;
    float hf = __uint_as_float(hs << 16);
    float d1 = x - hf;
    unsigned u2 = __float_as_uint(d1);
    unsigned r2 = u2 + 0x7fffu + ((u2 >> 16) & 1u);
    unsigned ls = r2 >> 16;
    float lf = __uint_as_float(ls << 16);
    float d2 = d1 - lf;
    unsigned u3 = __float_as_uint(d2);
    unsigned r3 = u3 + 0x7fffu + ((u3 >> 16) & 1u);
    *hh = (ushort)hs;
    *ll = (ushort)ls;
    *qq = (ushort)(r3 >> 16);
}

// ---------------------------------------------------------------------------
// Kernel 1: row squared norms
// ---------------------------------------------------------------------------
__global__ __launch_bounds__(64) void rowsq_kernel(const float* __restrict__ x,
                                                   float* __restrict__ x2) {
    int row = blockIdx.x;
    const float4* p = (const float4*)(x + (size_t)row * CDIM);
    float4 v = p[threadIdx.x];
    float s = v.x*v.x + v.y*v.y + v.z*v.z + v.w*v.w;
    for (int o = 32; o; o >>= 1) s += __shfl_down(s, o);
    if (threadIdx.x == 0) x2[row] = s;
}

// ---------------------------------------------------------------------------
// Kernel 2: elementwise fp32 -> bf16 3-way split (h, l, q)
// ---------------------------------------------------------------------------
__global__ __launch_bounds__(256) void split3_kernel(const float* __restrict__ src,
                                                     ushort* __restrict__ hi,
                                                     ushort* __restrict__ lo,
                                                     ushort* __restrict__ qd,
                                                     int n) {
    int i = (blockIdx.x * 256 + threadIdx.x) * 4;
    if (i >= n) return;
    float4 v = *(const float4*)(src + i);
    ushort h[4], l[4], q[4];
    bfsplit3(v.x, &h[0], &l[0], &q[0]);
    bfsplit3(v.y, &h[1], &l[1], &q[1]);
    bfsplit3(v.z, &h[2], &l[2], &q[2]);
    bfsplit3(v.w, &h[3], &l[3], &q[3]);
    *(ushort4v*)(hi + i) = *(ushort4v*)h;
    *(ushort4v*)(lo + i) = *(ushort4v*)l;
    *(ushort4v*)(qd + i) = *(ushort4v*)q;
}

// ---------------------------------------------------------------------------
// Kernel 3: W [K][N] fp32 -> hi/lo bf16 transposed [N][K]
// ---------------------------------------------------------------------------
__global__ __launch_bounds__(256) void wtrans_split_kernel(const float* __restrict__ W,
                                                           ushort* __restrict__ hiT,
                                                           ushort* __restrict__ loT,
                                                           int K, int N) {
    __shared__ float tile[64][65];
    int k0 = blockIdx.y * 64, n0 = blockIdx.x * 64;
    #pragma unroll
    for (int i = 0; i < 4; ++i) {
        int f = threadIdx.x + i * 256;      // 0..1023
        int r = f >> 4, c4 = (f & 15) * 4;
        float4 v = *(const float4*)(W + (size_t)(k0 + r) * N + n0 + c4);
        tile[r][c4+0] = v.x; tile[r][c4+1] = v.y;
        tile[r][c4+2] = v.z; tile[r][c4+3] = v.w;
    }
    __syncthreads();
    #pragma unroll
    for (int i = 0; i < 4; ++i) {
        int f = threadIdx.x + i * 256;
        int rn = f >> 4, ck = (f & 15) * 4;
        unsigned p0 = bfsplit(tile[ck+0][rn]);
        unsigned p1 = bfsplit(tile[ck+1][rn]);
        unsigned p2 = bfsplit(tile[ck+2][rn]);
        unsigned p3 = bfsplit(tile[ck+3][rn]);
        ushort4v h, l;
        h.x = (ushort)p0; l.x = (ushort)(p0 >> 16);
        h.y = (ushort)p1; l.y = (ushort)(p1 >> 16);
        h.z = (ushort)p2; l.z = (ushort)(p2 >> 16);
        h.w = (ushort)p3; l.w = (ushort)(p3 >> 16);
        *(ushort4v*)(hiT + (size_t)(n0 + rn) * K + k0 + ck) = h;
        *(ushort4v*)(loT + (size_t)(n0 + rn) * K + k0 + ck) = l;
    }
}

// ---------------------------------------------------------------------------
// Kernel 4: Gram/scores via 3-split bf16 MFMA (6 products = fp32 precision).
// S[b][i][j] = x2[b][j] - 2*dot(x_i,x_j), diag=+inf.
// 128x128 tile, BK=32, 4 waves (2x2), 4x4 16x16x32 frags per wave.
// ---------------------------------------------------------------------------
#define LSTR 40   // LDS row stride in ushort (80 B)
__global__ __launch_bounds__(256) void gram_mfma_kernel(const ushort* __restrict__ xh,
                                                        const ushort* __restrict__ xl,
                                                        const ushort* __restrict__ xq,
                                                        const float* __restrict__ x2,
                                                        float* __restrict__ S) {
    int b = blockIdx.z;
    size_t xoff = (size_t)b * NPTS * CDIM;
    const ushort* Ah = xh + xoff;
    const ushort* Al = xl + xoff;
    const ushort* Aq = xq + xoff;
    float* Sb = S + (size_t)b * NPTS * NPTS;
    const float* x2b = x2 + (size_t)b * NPTS;

    __shared__ ushort A_[3][128*LSTR];
    __shared__ ushort B_[3][128*LSTR];

    int bi = blockIdx.y * 128, bj = blockIdx.x * 128;
    int lane = threadIdx.x & 63, wave = threadIdx.x >> 6;
    int wr = wave >> 1, wc = wave & 1;
    int fr = lane & 15, kg = lane >> 4;

    floatx4 acc[4][4] = {};

    int srow = threadIdx.x >> 1;          // 0..127
    int sseg = (threadIdx.x & 1) * 16;    // 0 / 16 (bf16 elems)

    const ushort* sAh = Ah + (size_t)(bi + srow) * CDIM + sseg;
    const ushort* sAl = Al + (size_t)(bi + srow) * CDIM + sseg;
    const ushort* sAq = Aq + (size_t)(bi + srow) * CDIM + sseg;
    const ushort* sBh = Ah + (size_t)(bj + srow) * CDIM + sseg;
    const ushort* sBl = Al + (size_t)(bj + srow) * CDIM + sseg;
    const ushort* sBq = Aq + (size_t)(bj + srow) * CDIM + sseg;
    int dof = srow * LSTR + sseg;

    for (int k0 = 0; k0 < CDIM; k0 += 32) {
        uint4 a0 = *(const uint4*)(sAh + k0); uint4 a1 = *(const uint4*)(sAh + k0 + 8);
        uint4 b0 = *(const uint4*)(sAl + k0); uint4 b1 = *(const uint4*)(sAl + k0 + 8);
        uint4 c0 = *(const uint4*)(sAq + k0); uint4 c1 = *(const uint4*)(sAq + k0 + 8);
        uint4 d0 = *(const uint4*)(sBh + k0); uint4 d1 = *(const uint4*)(sBh + k0 + 8);
        uint4 e0 = *(const uint4*)(sBl + k0); uint4 e1 = *(const uint4*)(sBl + k0 + 8);
        uint4 f0 = *(const uint4*)(sBq + k0); uint4 f1 = *(const uint4*)(sBq + k0 + 8);
        *(uint4*)&A_[0][dof] = a0; *(uint4*)&A_[0][dof+8] = a1;
        *(uint4*)&A_[1][dof] = b0; *(uint4*)&A_[1][dof+8] = b1;
        *(uint4*)&A_[2][dof] = c0; *(uint4*)&A_[2][dof+8] = c1;
        *(uint4*)&B_[0][dof] = d0; *(uint4*)&B_[0][dof+8] = d1;
        *(uint4*)&B_[1][dof] = e0; *(uint4*)&B_[1][dof+8] = e1;
        *(uint4*)&B_[2][dof] = f0; *(uint4*)&B_[2][dof+8] = f1;
        __syncthreads();

        short8 a_h[4], a_l[4], a_q[4], b_h[4], b_l[4], b_q[4];
        #pragma unroll
        for (int m = 0; m < 4; ++m) {
            int off = (wr*64 + m*16 + fr) * LSTR + kg*8;
            a_h[m] = *(const short8*)&A_[0][off];
            a_l[m] = *(const short8*)&A_[1][off];
            a_q[m] = *(const short8*)&A_[2][off];
        }
        #pragma unroll
        for (int n = 0; n < 4; ++n) {
            int off = (wc*64 + n*16 + fr) * LSTR + kg*8;
            b_h[n] = *(const short8*)&B_[0][off];
            b_l[n] = *(const short8*)&B_[1][off];
            b_q[n] = *(const short8*)&B_[2][off];
        }
        #pragma unroll
        for (int m = 0; m < 4; ++m)
            #pragma unroll
            for (int n = 0; n < 4; ++n) {
                acc[m][n] = __builtin_amdgcn_mfma_f32_16x16x32_bf16(a_h[m], b_h[n], acc[m][n], 0, 0, 0);
                acc[m][n] = __builtin_amdgcn_mfma_f32_16x16x32_bf16(a_h[m], b_l[n], acc[m][n], 0, 0, 0);
                acc[m][n] = __builtin_amdgcn_mfma_f32_16x16x32_bf16(a_l[m], b_h[n], acc[m][n], 0, 0, 0);
                acc[m][n] = __builtin_amdgcn_mfma_f32_16x16x32_bf16(a_l[m], b_l[n], acc[m][n], 0, 0, 0);
                acc[m][n] = __builtin_amdgcn_mfma_f32_16x16x32_bf16(a_h[m], b_q[n], acc[m][n], 0, 0, 0);
                acc[m][n] = __builtin_amdgcn_mfma_f32_16x16x32_bf16(a_q[m], b_h[n], acc[m][n], 0, 0, 0);
            }
        __syncthreads();
    }

    #pragma unroll
    for (int m = 0; m < 4; ++m)
        #pragma unroll
        for (int n = 0; n < 4; ++n) {
            int col = bj + wc*64 + n*16 + fr;
            float xc = x2b[col];
            #pragma unroll
            for (int r = 0; r < 4; ++r) {
                int row = bi + wr*64 + m*16 + kg*4 + r;
                float val = xc - 2.0f * acc[m][n][r];
                if (row == col) val = __builtin_inff();
                Sb[(size_t)row * NPTS + col] = val;
            }
        }
}

// ---------------------------------------------------------------------------
// Kernel 5: per-row exact top-KNN via 4x8-bit radix select.
// ---------------------------------------------------------------------------
__device__ __forceinline__ unsigned block_excl_scan_256(unsigned c,
                                                        unsigned* wsum,
                                                        unsigned* total_out) {
    unsigned v = c;
    #pragma unroll
    for (int o = 1; o < 64; o <<= 1) {
        unsigned t = __shfl_up(v, o);
        if ((threadIdx.x & 63) >= o) v += t;
    }
    if ((threadIdx.x & 63) == 63) wsum[threadIdx.x >> 6] = v;
    __syncthreads();
    unsigned woff = 0;
    int mywave = threadIdx.x >> 6;
    #pragma unroll
    for (int w = 0; w < 4; ++w) {
        unsigned s = wsum[w];
        if (w < mywave) woff += s;
    }
    if (total_out) *total_out = wsum[0] + wsum[1] + wsum[2] + wsum[3];
    __syncthreads();
    return v + woff - c;
}

__global__ __launch_bounds__(256) void knn_radix_kernel(const float* __restrict__ S,
                                                        int* __restrict__ idx) {
    int n = blockIdx.x, b = blockIdx.y;
    const float* row = S + ((size_t)b * NPTS + n) * NPTS;
    int* out = idx + ((size_t)b * NPTS + n) * KNN;

    __shared__ unsigned keys[NPTS];
    __shared__ unsigned hist[256];
    __shared__ unsigned wsum[4];
    __shared__ unsigned sh_below, sh_sel;
    __shared__ int eqlist[64];

    for (int i = threadIdx.x; i < NPTS; i += 256) {
        unsigned u = __float_as_uint(row[i]);
        u = (u & 0x80000000u) ? ~u : (u | 0x80000000u);
        keys[i] = u;
    }
    __syncthreads();

    unsigned prefix = 0, pmask = 0;
    int rank = KNN;
    #pragma unroll
    for (int pass = 0; pass < 4; ++pass) {
        int shift = 24 - pass * 8;
        hist[threadIdx.x] = 0;
        __syncthreads();
        for (int i = threadIdx.x; i < NPTS; i += 256) {
            unsigned u = keys[i];
            if ((u & pmask) == prefix)
                atomicAdd(&hist[(u >> shift) & 0xffu], 1u);
        }
        __syncthreads();
        unsigned c = hist[threadIdx.x];
        unsigned excl = block_excl_scan_256(c, wsum, nullptr);
        if (excl < (unsigned)rank && excl + c >= (unsigned)rank) {
            sh_below = excl;
            sh_sel   = (unsigned)threadIdx.x;
        }
        __syncthreads();
        rank   -= (int)sh_below;
        prefix |= sh_sel << shift;
        pmask  |= 0xffu << shift;
        __syncthreads();
    }
    unsigned pivot = prefix;

    unsigned lt = 0, eq = 0;
    for (int i = threadIdx.x; i < NPTS; i += 256) {
        unsigned u = keys[i];
        lt += (u < pivot) ? 1u : 0u;
        eq += (u == pivot) ? 1u : 0u;
    }
    unsigned total = 0;
    unsigned excl = block_excl_scan_256(lt | (eq << 16), wsum, &total);
    unsigned lt_base = excl & 0xffffu;
    unsigned eq_base = excl >> 16;
    unsigned eq_total = total >> 16;

    for (int i = threadIdx.x; i < NPTS; i += 256) {
        unsigned u = keys[i];
        if (u < pivot) {
            out[lt_base++] = i;
        } else if (u == pivot) {
            if (eq_base < 64) eqlist[eq_base] = i;
            eq_base++;
        }
    }
    __syncthreads();

    if (threadIdx.x == 0) {
        int base = KNN - rank;
        int m = (int)(eq_total < 64u ? eq_total : 64u);
        for (int t = 0; t < rank; ++t) {
            int best = 0x7fffffff, bj = -1;
            for (int j = 0; j < m; ++j) {
                int v = eqlist[j];
                if (v >= 0 && v < best) { best = v; bj = j; }
            }
            out[base + t] = best;
            if (bj >= 0) eqlist[bj] = -1;
        }
    }
}

// ---------------------------------------------------------------------------
// Kernel 6: split-bf16 MFMA GEMM (hi/lo, 3 products).
// ---------------------------------------------------------------------------
__global__ __launch_bounds__(256) void mfma_split_gemm(const ushort* __restrict__ Ahi,
                                                       const ushort* __restrict__ Alo,
                                                       const ushort* __restrict__ BhiT,
                                                       const ushort* __restrict__ BloT,
                                                       const float* __restrict__ bias,
                                                       float* __restrict__ C,
                                                       int M, int N, int K) {
    __shared__ ushort ldsAh[128*LSTR];
    __shared__ ushort ldsAl[128*LSTR];
    __shared__ ushort ldsBh[128*LSTR];
    __shared__ ushort ldsBl[128*LSTR];

    int bi = blockIdx.y * 128, bj = blockIdx.x * 128;
    int lane = threadIdx.x & 63, wave = threadIdx.x >> 6;
    int wr = wave >> 1, wc = wave & 1;
    int fr = lane & 15, kg = lane >> 4;

    floatx4 acc[4][4] = {};

    int srow = threadIdx.x >> 1;
    int sseg = (threadIdx.x & 1) * 16;

    const ushort* s0 = Ahi  + (size_t)(bi + srow) * K + sseg;
    const ushort* s1 = Alo  + (size_t)(bi + srow) * K + sseg;
    const ushort* s2 = BhiT + (size_t)(bj + srow) * K + sseg;
    const ushort* s3 = BloT + (size_t)(bj + srow) * K + sseg;
    ushort* d0 = &ldsAh[srow*LSTR + sseg];
    ushort* d1 = &ldsAl[srow*LSTR + sseg];
    ushort* d2 = &ldsBh[srow*LSTR + sseg];
    ushort* d3 = &ldsBl[srow*LSTR + sseg];

    for (int k0 = 0; k0 < K; k0 += 32) {
        uint4 va0 = *(const uint4*)(s0 + k0);
        uint4 va1 = *(const uint4*)(s0 + k0 + 8);
        uint4 vb0 = *(const uint4*)(s1 + k0);
        uint4 vb1 = *(const uint4*)(s1 + k0 + 8);
        uint4 vc0 = *(const uint4*)(s2 + k0);
        uint4 vc1 = *(const uint4*)(s2 + k0 + 8);
        uint4 vd0 = *(const uint4*)(s3 + k0);
        uint4 vd1 = *(const uint4*)(s3 + k0 + 8);
        *(uint4*)(d0)     = va0;  *(uint4*)(d0 + 8) = va1;
        *(uint4*)(d1)     = vb0;  *(uint4*)(d1 + 8) = vb1;
        *(uint4*)(d2)     = vc0;  *(uint4*)(d2 + 8) = vc1;
        *(uint4*)(d3)     = vd0;  *(uint4*)(d3 + 8) = vd1;
        __syncthreads();

        short8 a_h[4], a_l[4], b_h[4], b_l[4];
        #pragma unroll
        for (int m = 0; m < 4; ++m) {
            int off = (wr*64 + m*16 + fr) * LSTR + kg*8;
            a_h[m] = *(const short8*)&ldsAh[off];
            a_l[m] = *(const short8*)&ldsAl[off];
        }
        #pragma unroll
        for (int n = 0; n < 4; ++n) {
            int off = (wc*64 + n*16 + fr) * LSTR + kg*8;
            b_h[n] = *(const short8*)&ldsBh[off];
            b_l[n] = *(const short8*)&ldsBl[off];
        }
        #pragma unroll
        for (int m = 0; m < 4; ++m)
            #pragma unroll
            for (int n = 0; n < 4; ++n) {
                acc[m][n] = __builtin_amdgcn_mfma_f32_16x16x32_bf16(a_h[m], b_h[n], acc[m][n], 0, 0, 0);
                acc[m][n] = __builtin_amdgcn_mfma_f32_16x16x32_bf16(a_h[m], b_l[n], acc[m][n], 0, 0, 0);
                acc[m][n] = __builtin_amdgcn_mfma_f32_16x16x32_bf16(a_l[m], b_h[n], acc[m][n], 0, 0, 0);
            }
        __syncthreads();
    }

    #pragma unroll
    for (int m = 0; m < 4; ++m)
        #pragma unroll
        for (int n = 0; n < 4; ++n) {
            int col = bj + wc*64 + n*16 + fr;
            float bv = bias ? bias[col] : 0.0f;
            #pragma unroll
            for (int r = 0; r < 4; ++r) {
                int row = bi + wr*64 + m*16 + kg*4 + r;
                C[(size_t)row * N + col] = acc[m][n][r] + bv;
            }
        }
}

// ---------------------------------------------------------------------------
// Kernel 7: sparse graph attention, coalesced-gather version.
// Phase 1: thread=(j=tid>>3 neighbor, l=tid&7 dim-seg); per h, each thread
//          loads 32B of K row j -> wave covers 8 rows x 256B fully-used lines.
// Phase 2: thread=(h=tid>>5, dim-pair=tid&31), float2 V loads (256B/instr).
// Output pre-split hi/lo bf16.
// ---------------------------------------------------------------------------
__global__ __launch_bounds__(256) void attn_kernel(const float* __restrict__ qkv,
                                                   const int* __restrict__ idx,
                                                   ushort* __restrict__ ahi,
                                                   ushort* __restrict__ alo) {
    int n = blockIdx.x, b = blockIdx.y;
    size_t rowoff = ((size_t)b * NPTS + n);
    const float* qrow  = qkv + rowoff * TRIPLE;                      // 512 floats
    const float* kbase = qkv + (size_t)b * NPTS * TRIPLE + INNER;
    const float* vbase = qkv + (size_t)b * NPTS * TRIPLE + 2*INNER;

    __shared__ int   nb[KNN];
    __shared__ float dots[NHEAD][KNN];
    __shared__ float p[NHEAD][KNN];

    if (threadIdx.x < KNN)
        nb[threadIdx.x] = idx[rowoff * KNN + threadIdx.x];
    __syncthreads();

    // --- phase 1: dots, lanes along dim axis ---
    {
        int j = threadIdx.x >> 3;      // neighbor 0..31
        int l = threadIdx.x & 7;       // 8-float segment 0..7
        const float* krow = kbase + (size_t)nb[j] * TRIPLE;
        #pragma unroll
        for (int h = 0; h < NHEAD; ++h) {
            int off = h * DHEAD + l * 8;
            float4 k0 = *(const float4*)(krow + off);
            float4 k1 = *(const float4*)(krow + off + 4);
            float4 q0 = *(const float4*)(qrow + off);
            float4 q1 = *(const float4*)(qrow + off + 4);
            float d = k0.x*q0.x + k0.y*q0.y + k0.z*q0.z + k0.w*q0.w
                    + k1.x*q1.x + k1.y*q1.y + k1.z*q1.z + k1.w*q1.w;
            d += __shfl_xor(d, 1);
            d += __shfl_xor(d, 2);
            d += __shfl_xor(d, 4);
            if (l == 0) dots[h][j] = d * SCALE;
        }
    }
    __syncthreads();

    // --- phase 1b: softmax per head ---
    {
        int h = threadIdx.x >> 5, jj = threadIdx.x & 31;
        float dv = dots[h][jj];
        float mx = dv;
        for (int o = 16; o; o >>= 1) mx = fmaxf(mx, __shfl_xor(mx, o));
        float e = expf(dv - mx);
        float s = e;
        for (int o = 16; o; o >>= 1) s += __shfl_xor(s, o);
        p[h][jj] = e / s;
    }
    __syncthreads();

    // --- phase 2: weighted V sum, float2 per thread ---
    {
        int hd = threadIdx.x >> 5;
        int jd = threadIdx.x & 31;     // dim-pair index (dims 2jd, 2jd+1)
        float o0 = 0.f, o1 = 0.f;
        #pragma unroll 8
        for (int jj = 0; jj < KNN; ++jj) {
            int mm = nb[jj];
            float2 vv = *(const float2*)(vbase + (size_t)mm * TRIPLE + hd * DHEAD + jd * 2);
            float pw = p[hd][jj];
            o0 += pw * vv.x;
            o1 += pw * vv.y;
        }
        size_t base = rowoff * INNER + hd * DHEAD + jd * 2;
        unsigned q0 = bfsplit(o0);
        unsigned q1 = bfsplit(o1);
        *(unsigned*)(ahi + base) = (q0 & 0xffffu) | (q1 << 16);
        *(unsigned*)(alo + base) = (q0 >> 16) | (q1 & 0xffff0000u);
    }
}

// ---------------------------------------------------------------------------
extern "C" void kernel_launch(void* const* d_in, const int* in_sizes, int n_in,
                              void* d_out, int out_size, void* d_ws, size_t ws_size,
                              hipStream_t stream) {
    const float* x    = (const float*)d_in[0];   // [2,2048,256]
    const float* Wqkv = (const float*)d_in[1];   // [256,1536]
    const float* Wout = (const float*)d_in[2];   // [512,256]
    const float* bout = (const float*)d_in[3];   // [256]
    float* out = (float*)d_out;                  // [2,2048,256]

    // workspace layout
    float* S    = (float*)d_ws;                           // 8,388,608 f32
    float* x2   = S + (size_t)BATCH * NPTS * NPTS;        // 4096 f32
    int*   idx  = (int*)(x2 + (size_t)BATCH * NPTS);      // 131072 int
    float* qkv  = (float*)(idx + (size_t)BATCH * NPTS * KNN);   // 6,291,456 f32
    ushort* xhi = (ushort*)(qkv + (size_t)BATCH * NPTS * TRIPLE);
    ushort* xlo   = xhi   + (size_t)BATCH * NPTS * CDIM;  // 1,048,576 each
    ushort* xqd   = xlo   + (size_t)BATCH * NPTS * CDIM;
    ushort* ahi   = xqd   + (size_t)BATCH * NPTS * CDIM;  // 2,097,152 each
    ushort* alo   = ahi   + (size_t)BATCH * NPTS * INNER;
    ushort* wqhiT = alo   + (size_t)BATCH * NPTS * INNER; // [1536][256]
    ushort* wqloT = wqhiT + (size_t)TRIPLE * CDIM;
    ushort* wohiT = wqloT + (size_t)TRIPLE * CDIM;        // [256][512]
    ushort* woloT = wohiT + (size_t)CDIM * INNER;

    // 1. row squared norms
    rowsq_kernel<<<BATCH * NPTS, 64, 0, stream>>>(x, x2);

    // 2. split x -> bf16 h/l/q
    {
        int n = BATCH * NPTS * CDIM;
        split3_kernel<<<n / 1024, 256, 0, stream>>>(x, xhi, xlo, xqd, n);
    }

    // 3. transpose+split weights
    {
        dim3 g1(TRIPLE / 64, CDIM / 64);
        wtrans_split_kernel<<<g1, 256, 0, stream>>>(Wqkv, wqhiT, wqloT, CDIM, TRIPLE);
        dim3 g2(CDIM / 64, INNER / 64);
        wtrans_split_kernel<<<g2, 256, 0, stream>>>(Wout, wohiT, woloT, INNER, CDIM);
    }

    // 4. Gram/scores via 3-split MFMA (fp32-precision, selection-safe)
    {
        dim3 grid(NPTS / 128, NPTS / 128, BATCH);
        gram_mfma_kernel<<<grid, 256, 0, stream>>>(xhi, xlo, xqd, x2, S);
    }

    // 5. top-32 neighbor selection
    {
        dim3 grid(NPTS, BATCH);
        knn_radix_kernel<<<grid, 256, 0, stream>>>(S, idx);
    }

    // 6. qkv projection: [4096,256] @ [256,1536] via split-bf16 MFMA
    {
        dim3 grid(TRIPLE / 128, (BATCH * NPTS) / 128);
        mfma_split_gemm<<<grid, 256, 0, stream>>>(xhi, xlo, wqhiT, wqloT,
                                                  nullptr, qkv,
                                                  BATCH * NPTS, TRIPLE, CDIM);
    }

    // 7. sparse attention -> pre-split hi/lo
    {
        dim3 grid(NPTS, BATCH);
        attn_kernel<<<grid, 256, 0, stream>>>(qkv, idx, ahi, alo);
    }

    // 8. output projection: [4096,512] @ [512,256] + bias
    {
        dim3 grid(CDIM / 128, (BATCH * NPTS) / 128);
        mfma_split_gemm<<<grid, 256, 0, stream>>>(ahi, alo, wohiT, woloT,
                                                  bout, out,
                                                  BATCH * NPTS, CDIM, INNER);
    }
}

// Round 7
// 144.178 us; speedup vs baseline: 3.0394x; 1.2061x over previous
//
#include <hip/hip_runtime.h>
#include <hip/hip_bf16.h>

// Problem constants
#define BATCH 2
#define NPTS  2048
#define CDIM  256
#define NHEAD 8
#define DHEAD 64
#define INNER 512            // NHEAD*DHEAD
#define TRIPLE 1536          // 3*INNER
#define KNN   32
#define SCALE 0.125f         // 64^-0.5

typedef __attribute__((ext_vector_type(8))) short short8;      // 8 bf16 (4 VGPR)
typedef __attribute__((ext_vector_type(4))) float floatx4;     // MFMA acc
typedef __attribute__((ext_vector_type(4))) unsigned short ushort4v;
typedef unsigned short ushort;

// bf16 split: x = hi + lo (both RNE bf16), residual ~2^-18 relative.
// Returns hi in bits [15:0], lo in bits [31:16].
__device__ __forceinline__ unsigned bfsplit(float x) {
    unsigned u = __float_as_uint(x);
    unsigned r = u + 0x7fffu + ((u >> 16) & 1u);
    unsigned hs = r >> 16;
    float hf = __uint_as_float(hs << 16);
    float lo = x - hf;
    unsigned u2 = __float_as_uint(lo);
    unsigned r2 = u2 + 0x7fffu + ((u2 >> 16) & 1u);
    return (hs & 0xffffu) | (r2 & 0xffff0000u);
}

// 3-component split: x = h + l + q, residual ~2^-27 relative.
__device__ __forceinline__ void bfsplit3(float x, ushort* hh, ushort* ll, ushort* qq) {
    unsigned u = __float_as_uint(x);
    unsigned r = u + 0x7fffu + ((u >> 16) & 1u);
    unsigned hs = r >> 16;
    float hf = __uint_as_float(hs << 16);
    float d1 = x - hf;
    unsigned u2 = __float_as_uint(d1);
    unsigned r2 = u2 + 0x7fffu + ((u2 >> 16) & 1u);
    unsigned ls = r2 >> 16;
    float lf = __uint_as_float(ls << 16);
    float d2 = d1 - lf;
    unsigned u3 = __float_as_uint(d2);
    unsigned r3 = u3 + 0x7fffu + ((u3 >> 16) & 1u);
    *hh = (ushort)hs;
    *ll = (ushort)ls;
    *qq = (ushort)(r3 >> 16);
}

// ---------------------------------------------------------------------------
// Kernel 1: row squared norms
// ---------------------------------------------------------------------------
__global__ __launch_bounds__(64) void rowsq_kernel(const float* __restrict__ x,
                                                   float* __restrict__ x2) {
    int row = blockIdx.x;
    const float4* p = (const float4*)(x + (size_t)row * CDIM);
    float4 v = p[threadIdx.x];
    float s = v.x*v.x + v.y*v.y + v.z*v.z + v.w*v.w;
    for (int o = 32; o; o >>= 1) s += __shfl_down(s, o);
    if (threadIdx.x == 0) x2[row] = s;
}

// ---------------------------------------------------------------------------
// Kernel 2: elementwise fp32 -> bf16 3-way split (h, l, q)
// ---------------------------------------------------------------------------
__global__ __launch_bounds__(256) void split3_kernel(const float* __restrict__ src,
                                                     ushort* __restrict__ hi,
                                                     ushort* __restrict__ lo,
                                                     ushort* __restrict__ qd,
                                                     int n) {
    int i = (blockIdx.x * 256 + threadIdx.x) * 4;
    if (i >= n) return;
    float4 v = *(const float4*)(src + i);
    ushort h[4], l[4], q[4];
    bfsplit3(v.x, &h[0], &l[0], &q[0]);
    bfsplit3(v.y, &h[1], &l[1], &q[1]);
    bfsplit3(v.z, &h[2], &l[2], &q[2]);
    bfsplit3(v.w, &h[3], &l[3], &q[3]);
    *(ushort4v*)(hi + i) = *(ushort4v*)h;
    *(ushort4v*)(lo + i) = *(ushort4v*)l;
    *(ushort4v*)(qd + i) = *(ushort4v*)q;
}

// ---------------------------------------------------------------------------
// Kernel 3: W [K][N] fp32 -> hi/lo bf16 transposed [N][K]
// ---------------------------------------------------------------------------
__global__ __launch_bounds__(256) void wtrans_split_kernel(const float* __restrict__ W,
                                                           ushort* __restrict__ hiT,
                                                           ushort* __restrict__ loT,
                                                           int K, int N) {
    __shared__ float tile[64][65];
    int k0 = blockIdx.y * 64, n0 = blockIdx.x * 64;
    #pragma unroll
    for (int i = 0; i < 4; ++i) {
        int f = threadIdx.x + i * 256;      // 0..1023
        int r = f >> 4, c4 = (f & 15) * 4;
        float4 v = *(const float4*)(W + (size_t)(k0 + r) * N + n0 + c4);
        tile[r][c4+0] = v.x; tile[r][c4+1] = v.y;
        tile[r][c4+2] = v.z; tile[r][c4+3] = v.w;
    }
    __syncthreads();
    #pragma unroll
    for (int i = 0; i < 4; ++i) {
        int f = threadIdx.x + i * 256;
        int rn = f >> 4, ck = (f & 15) * 4;
        unsigned p0 = bfsplit(tile[ck+0][rn]);
        unsigned p1 = bfsplit(tile[ck+1][rn]);
        unsigned p2 = bfsplit(tile[ck+2][rn]);
        unsigned p3 = bfsplit(tile[ck+3][rn]);
        ushort4v h, l;
        h.x = (ushort)p0; l.x = (ushort)(p0 >> 16);
        h.y = (ushort)p1; l.y = (ushort)(p1 >> 16);
        h.z = (ushort)p2; l.z = (ushort)(p2 >> 16);
        h.w = (ushort)p3; l.w = (ushort)(p3 >> 16);
        *(ushort4v*)(hiT + (size_t)(n0 + rn) * K + k0 + ck) = h;
        *(ushort4v*)(loT + (size_t)(n0 + rn) * K + k0 + ck) = l;
    }
}

// ---------------------------------------------------------------------------
// Kernel 4: Gram/scores via 3-split bf16 MFMA (6 products = fp32 precision).
// ---------------------------------------------------------------------------
#define LSTR 40   // LDS row stride in ushort (80 B)
__global__ __launch_bounds__(256) void gram_mfma_kernel(const ushort* __restrict__ xh,
                                                        const ushort* __restrict__ xl,
                                                        const ushort* __restrict__ xq,
                                                        const float* __restrict__ x2,
                                                        float* __restrict__ S) {
    int b = blockIdx.z;
    size_t xoff = (size_t)b * NPTS * CDIM;
    const ushort* Ah = xh + xoff;
    const ushort* Al = xl + xoff;
    const ushort* Aq = xq + xoff;
    float* Sb = S + (size_t)b * NPTS * NPTS;
    const float* x2b = x2 + (size_t)b * NPTS;

    __shared__ ushort A_[3][128*LSTR];
    __shared__ ushort B_[3][128*LSTR];

    int bi = blockIdx.y * 128, bj = blockIdx.x * 128;
    int lane = threadIdx.x & 63, wave = threadIdx.x >> 6;
    int wr = wave >> 1, wc = wave & 1;
    int fr = lane & 15, kg = lane >> 4;

    floatx4 acc[4][4] = {};

    int srow = threadIdx.x >> 1;          // 0..127
    int sseg = (threadIdx.x & 1) * 16;    // 0 / 16 (bf16 elems)

    const ushort* sAh = Ah + (size_t)(bi + srow) * CDIM + sseg;
    const ushort* sAl = Al + (size_t)(bi + srow) * CDIM + sseg;
    const ushort* sAq = Aq + (size_t)(bi + srow) * CDIM + sseg;
    const ushort* sBh = Ah + (size_t)(bj + srow) * CDIM + sseg;
    const ushort* sBl = Al + (size_t)(bj + srow) * CDIM + sseg;
    const ushort* sBq = Aq + (size_t)(bj + srow) * CDIM + sseg;
    int dof = srow * LSTR + sseg;

    for (int k0 = 0; k0 < CDIM; k0 += 32) {
        uint4 a0 = *(const uint4*)(sAh + k0); uint4 a1 = *(const uint4*)(sAh + k0 + 8);
        uint4 b0 = *(const uint4*)(sAl + k0); uint4 b1 = *(const uint4*)(sAl + k0 + 8);
        uint4 c0 = *(const uint4*)(sAq + k0); uint4 c1 = *(const uint4*)(sAq + k0 + 8);
        uint4 d0 = *(const uint4*)(sBh + k0); uint4 d1 = *(const uint4*)(sBh + k0 + 8);
        uint4 e0 = *(const uint4*)(sBl + k0); uint4 e1 = *(const uint4*)(sBl + k0 + 8);
        uint4 f0 = *(const uint4*)(sBq + k0); uint4 f1 = *(const uint4*)(sBq + k0 + 8);
        *(uint4*)&A_[0][dof] = a0; *(uint4*)&A_[0][dof+8] = a1;
        *(uint4*)&A_[1][dof] = b0; *(uint4*)&A_[1][dof+8] = b1;
        *(uint4*)&A_[2][dof] = c0; *(uint4*)&A_[2][dof+8] = c1;
        *(uint4*)&B_[0][dof] = d0; *(uint4*)&B_[0][dof+8] = d1;
        *(uint4*)&B_[1][dof] = e0; *(uint4*)&B_[1][dof+8] = e1;
        *(uint4*)&B_[2][dof] = f0; *(uint4*)&B_[2][dof+8] = f1;
        __syncthreads();

        short8 a_h[4], a_l[4], a_q[4], b_h[4], b_l[4], b_q[4];
        #pragma unroll
        for (int m = 0; m < 4; ++m) {
            int off = (wr*64 + m*16 + fr) * LSTR + kg*8;
            a_h[m] = *(const short8*)&A_[0][off];
            a_l[m] = *(const short8*)&A_[1][off];
            a_q[m] = *(const short8*)&A_[2][off];
        }
        #pragma unroll
        for (int n = 0; n < 4; ++n) {
            int off = (wc*64 + n*16 + fr) * LSTR + kg*8;
            b_h[n] = *(const short8*)&B_[0][off];
            b_l[n] = *(const short8*)&B_[1][off];
            b_q[n] = *(const short8*)&B_[2][off];
        }
        #pragma unroll
        for (int m = 0; m < 4; ++m)
            #pragma unroll
            for (int n = 0; n < 4; ++n) {
                acc[m][n] = __builtin_amdgcn_mfma_f32_16x16x32_bf16(a_h[m], b_h[n], acc[m][n], 0, 0, 0);
                acc[m][n] = __builtin_amdgcn_mfma_f32_16x16x32_bf16(a_h[m], b_l[n], acc[m][n], 0, 0, 0);
                acc[m][n] = __builtin_amdgcn_mfma_f32_16x16x32_bf16(a_l[m], b_h[n], acc[m][n], 0, 0, 0);
                acc[m][n] = __builtin_amdgcn_mfma_f32_16x16x32_bf16(a_l[m], b_l[n], acc[m][n], 0, 0, 0);
                acc[m][n] = __builtin_amdgcn_mfma_f32_16x16x32_bf16(a_h[m], b_q[n], acc[m][n], 0, 0, 0);
                acc[m][n] = __builtin_amdgcn_mfma_f32_16x16x32_bf16(a_q[m], b_h[n], acc[m][n], 0, 0, 0);
            }
        __syncthreads();
    }

    #pragma unroll
    for (int m = 0; m < 4; ++m)
        #pragma unroll
        for (int n = 0; n < 4; ++n) {
            int col = bj + wc*64 + n*16 + fr;
            float xc = x2b[col];
            #pragma unroll
            for (int r = 0; r < 4; ++r) {
                int row = bi + wr*64 + m*16 + kg*4 + r;
                float val = xc - 2.0f * acc[m][n][r];
                if (row == col) val = __builtin_inff();
                Sb[(size_t)row * NPTS + col] = val;
            }
        }
}

// ---------------------------------------------------------------------------
// Kernel 5: per-row exact top-KNN via range-normalized histogram select.
// Keys are order-preserving uint maps of fp32 distances. Buckets are
// (key - lo) >> shift with shift fit to the ACTUAL row spread (256 buckets
// of real information, unlike fixed fp32 radix digits whose top bits are
// degenerate). <=4 refinements; then exact rank-by-count among <=64
// candidates (ties -> lowest index). Deterministic output positions.
// ---------------------------------------------------------------------------
__device__ __forceinline__ unsigned block_excl_scan_256(unsigned c,
                                                        unsigned* wsum,
                                                        unsigned* total_out) {
    unsigned v = c;
    #pragma unroll
    for (int o = 1; o < 64; o <<= 1) {
        unsigned t = __shfl_up(v, o);
        if ((threadIdx.x & 63) >= o) v += t;
    }
    if ((threadIdx.x & 63) == 63) wsum[threadIdx.x >> 6] = v;
    __syncthreads();
    unsigned woff = 0;
    int mywave = threadIdx.x >> 6;
    #pragma unroll
    for (int w = 0; w < 4; ++w) {
        unsigned s = wsum[w];
        if (w < mywave) woff += s;
    }
    if (total_out) *total_out = wsum[0] + wsum[1] + wsum[2] + wsum[3];
    __syncthreads();
    return v + woff - c;
}

__global__ __launch_bounds__(256) void knn_select2_kernel(const float* __restrict__ S,
                                                          int* __restrict__ idx) {
    int n = blockIdx.x, b = blockIdx.y;
    const float* row = S + ((size_t)b * NPTS + n) * NPTS;
    int* out = idx + ((size_t)b * NPTS + n) * KNN;

    __shared__ unsigned keys[NPTS];      // 8 KB
    __shared__ unsigned hist[256];       // 1 KB
    __shared__ unsigned wsum[4];
    __shared__ unsigned s_red[8];
    __shared__ unsigned sh_lo, sh_hi, sh_rank, sh_cnt, sh_break;
    __shared__ unsigned ckey[64];
    __shared__ int     cidx[64];
    __shared__ unsigned s_ccount;

    int tid = threadIdx.x;

    // load + order-preserving map; diag forced to max key and excluded from range
    unsigned mn = 0xffffffffu, mx = 0u;
    for (int i = tid; i < NPTS; i += 256) {
        unsigned u;
        if (i == n) {
            u = 0xffffffffu;
        } else {
            unsigned v = __float_as_uint(row[i]);
            u = (v & 0x80000000u) ? ~v : (v | 0x80000000u);
            mn = min(mn, u); mx = max(mx, u);
        }
        keys[i] = u;
    }
    #pragma unroll
    for (int o = 32; o; o >>= 1) {
        mn = min(mn, (unsigned)__shfl_xor((int)mn, o));
        mx = max(mx, (unsigned)__shfl_xor((int)mx, o));
    }
    if ((tid & 63) == 0) { s_red[tid >> 6] = mn; s_red[4 + (tid >> 6)] = mx; }
    __syncthreads();
    if (tid == 0) {
        unsigned a = min(min(s_red[0], s_red[1]), min(s_red[2], s_red[3]));
        unsigned z = max(max(s_red[4], s_red[5]), max(s_red[6], s_red[7]));
        sh_lo = a; sh_hi = z; sh_rank = KNN; sh_break = 0; s_ccount = 0;
    }
    __syncthreads();

    // refinement loop (<=4 real iterations)
    for (int it = 0; it < 5; ++it) {
        unsigned lo = sh_lo, hi = sh_hi;
        unsigned range1 = hi - lo;              // hi >= lo
        int shift = 0;
        if (range1 > 255u) shift = 24 - __clz(range1);   // (range1>>shift) <= 255
        hist[tid] = 0;
        __syncthreads();
        for (int i = tid; i < NPTS; i += 256) {
            unsigned u = keys[i];
            if (u >= lo && u <= hi)
                atomicAdd(&hist[(u - lo) >> shift], 1u);
        }
        __syncthreads();
        unsigned c = hist[tid];
        unsigned rank = sh_rank;                // read BEFORE scan's barriers
        unsigned excl = block_excl_scan_256(c, wsum, nullptr);
        if (excl < rank && excl + c >= rank) {  // unique crossing bucket
            sh_rank = rank - excl;
            unsigned nlo = lo + ((unsigned)tid << shift);
            unsigned span = (shift == 0) ? 0u : (((1u << shift)) - 1u);
            unsigned nhi = nlo + span;
            if (nhi > hi || nhi < nlo) nhi = hi;
            sh_lo = nlo; sh_hi = nhi;
            sh_cnt = c;
            sh_break = (shift == 0 || c <= 64u) ? 1u : 0u;
        }
        __syncthreads();
        if (sh_break) break;
    }

    unsigned lo = sh_lo, hi = sh_hi, rank = sh_rank, cnt = sh_cnt;

    // deterministic emit of keys < lo (prefix-scan positions, stride order)
    unsigned lt = 0;
    for (int i = tid; i < NPTS; i += 256) lt += (keys[i] < lo) ? 1u : 0u;
    unsigned pos = block_excl_scan_256(lt, wsum, nullptr);
    for (int i = tid; i < NPTS; i += 256) {
        unsigned u = keys[i];
        if (u < lo) out[pos++] = i;
        else if (u >= lo && u <= hi && cnt <= 64u) {
            unsigned p = atomicAdd(&s_ccount, 1u);
            ckey[p] = u; cidx[p] = i;
        }
    }
    __syncthreads();

    unsigned base = KNN - rank;                 // == count of keys < lo
    if (cnt <= 64u) {
        // exact rank-by-count among candidates; position = base + rank order
        if (tid < (int)cnt) {
            unsigned myk = ckey[tid]; int myi = cidx[tid];
            unsigned r = 0;
            for (unsigned s = 0; s < cnt; ++s) {
                unsigned sk = ckey[s]; int si = cidx[s];
                r += (sk < myk || (sk == myk && si < myi)) ? 1u : 0u;
            }
            if (r < rank) out[base + r] = myi;
        }
    } else {
        // pathological mass-duplicate fallback (shift==0, >64 equal keys):
        // lowest-index selection, serial but deterministic
        if (tid == 0) {
            unsigned need = rank, p = base;
            for (int i = 0; i < NPTS && need; ++i) {
                if (keys[i] >= lo && keys[i] <= hi) { out[p++] = i; --need; }
            }
        }
    }
}

// ---------------------------------------------------------------------------
// Kernel 6: split-bf16 MFMA GEMM (hi/lo, 3 products).
// ---------------------------------------------------------------------------
__global__ __launch_bounds__(256) void mfma_split_gemm(const ushort* __restrict__ Ahi,
                                                       const ushort* __restrict__ Alo,
                                                       const ushort* __restrict__ BhiT,
                                                       const ushort* __restrict__ BloT,
                                                       const float* __restrict__ bias,
                                                       float* __restrict__ C,
                                                       int M, int N, int K) {
    __shared__ ushort ldsAh[128*LSTR];
    __shared__ ushort ldsAl[128*LSTR];
    __shared__ ushort ldsBh[128*LSTR];
    __shared__ ushort ldsBl[128*LSTR];

    int bi = blockIdx.y * 128, bj = blockIdx.x * 128;
    int lane = threadIdx.x & 63, wave = threadIdx.x >> 6;
    int wr = wave >> 1, wc = wave & 1;
    int fr = lane & 15, kg = lane >> 4;

    floatx4 acc[4][4] = {};

    int srow = threadIdx.x >> 1;
    int sseg = (threadIdx.x & 1) * 16;

    const ushort* s0 = Ahi  + (size_t)(bi + srow) * K + sseg;
    const ushort* s1 = Alo  + (size_t)(bi + srow) * K + sseg;
    const ushort* s2 = BhiT + (size_t)(bj + srow) * K + sseg;
    const ushort* s3 = BloT + (size_t)(bj + srow) * K + sseg;
    ushort* d0 = &ldsAh[srow*LSTR + sseg];
    ushort* d1 = &ldsAl[srow*LSTR + sseg];
    ushort* d2 = &ldsBh[srow*LSTR + sseg];
    ushort* d3 = &ldsBl[srow*LSTR + sseg];

    for (int k0 = 0; k0 < K; k0 += 32) {
        uint4 va0 = *(const uint4*)(s0 + k0);
        uint4 va1 = *(const uint4*)(s0 + k0 + 8);
        uint4 vb0 = *(const uint4*)(s1 + k0);
        uint4 vb1 = *(const uint4*)(s1 + k0 + 8);
        uint4 vc0 = *(const uint4*)(s2 + k0);
        uint4 vc1 = *(const uint4*)(s2 + k0 + 8);
        uint4 vd0 = *(const uint4*)(s3 + k0);
        uint4 vd1 = *(const uint4*)(s3 + k0 + 8);
        *(uint4*)(d0)     = va0;  *(uint4*)(d0 + 8) = va1;
        *(uint4*)(d1)     = vb0;  *(uint4*)(d1 + 8) = vb1;
        *(uint4*)(d2)     = vc0;  *(uint4*)(d2 + 8) = vc1;
        *(uint4*)(d3)     = vd0;  *(uint4*)(d3 + 8) = vd1;
        __syncthreads();

        short8 a_h[4], a_l[4], b_h[4], b_l[4];
        #pragma unroll
        for (int m = 0; m < 4; ++m) {
            int off = (wr*64 + m*16 + fr) * LSTR + kg*8;
            a_h[m] = *(const short8*)&ldsAh[off];
            a_l[m] = *(const short8*)&ldsAl[off];
        }
        #pragma unroll
        for (int n = 0; n < 4; ++n) {
            int off = (wc*64 + n*16 + fr) * LSTR + kg*8;
            b_h[n] = *(const short8*)&ldsBh[off];
            b_l[n] = *(const short8*)&ldsBl[off];
        }
        #pragma unroll
        for (int m = 0; m < 4; ++m)
            #pragma unroll
            for (int n = 0; n < 4; ++n) {
                acc[m][n] = __builtin_amdgcn_mfma_f32_16x16x32_bf16(a_h[m], b_h[n], acc[m][n], 0, 0, 0);
                acc[m][n] = __builtin_amdgcn_mfma_f32_16x16x32_bf16(a_h[m], b_l[n], acc[m][n], 0, 0, 0);
                acc[m][n] = __builtin_amdgcn_mfma_f32_16x16x32_bf16(a_l[m], b_h[n], acc[m][n], 0, 0, 0);
            }
        __syncthreads();
    }

    #pragma unroll
    for (int m = 0; m < 4; ++m)
        #pragma unroll
        for (int n = 0; n < 4; ++n) {
            int col = bj + wc*64 + n*16 + fr;
            float bv = bias ? bias[col] : 0.0f;
            #pragma unroll
            for (int r = 0; r < 4; ++r) {
                int row = bi + wr*64 + m*16 + kg*4 + r;
                C[(size_t)row * N + col] = acc[m][n][r] + bv;
            }
        }
}

// ---------------------------------------------------------------------------
// Kernel 7: sparse graph attention, coalesced-gather version.
// ---------------------------------------------------------------------------
__global__ __launch_bounds__(256) void attn_kernel(const float* __restrict__ qkv,
                                                   const int* __restrict__ idx,
                                                   ushort* __restrict__ ahi,
                                                   ushort* __restrict__ alo) {
    int n = blockIdx.x, b = blockIdx.y;
    size_t rowoff = ((size_t)b * NPTS + n);
    const float* qrow  = qkv + rowoff * TRIPLE;                      // 512 floats
    const float* kbase = qkv + (size_t)b * NPTS * TRIPLE + INNER;
    const float* vbase = qkv + (size_t)b * NPTS * TRIPLE + 2*INNER;

    __shared__ int   nb[KNN];
    __shared__ float dots[NHEAD][KNN];
    __shared__ float p[NHEAD][KNN];

    if (threadIdx.x < KNN)
        nb[threadIdx.x] = idx[rowoff * KNN + threadIdx.x];
    __syncthreads();

    // --- phase 1: dots, lanes along dim axis ---
    {
        int j = threadIdx.x >> 3;      // neighbor 0..31
        int l = threadIdx.x & 7;       // 8-float segment 0..7
        const float* krow = kbase + (size_t)nb[j] * TRIPLE;
        #pragma unroll
        for (int h = 0; h < NHEAD; ++h) {
            int off = h * DHEAD + l * 8;
            float4 k0 = *(const float4*)(krow + off);
            float4 k1 = *(const float4*)(krow + off + 4);
            float4 q0 = *(const float4*)(qrow + off);
            float4 q1 = *(const float4*)(qrow + off + 4);
            float d = k0.x*q0.x + k0.y*q0.y + k0.z*q0.z + k0.w*q0.w
                    + k1.x*q1.x + k1.y*q1.y + k1.z*q1.z + k1.w*q1.w;
            d += __shfl_xor(d, 1);
            d += __shfl_xor(d, 2);
            d += __shfl_xor(d, 4);
            if (l == 0) dots[h][j] = d * SCALE;
        }
    }
    __syncthreads();

    // --- phase 1b: softmax per head ---
    {
        int h = threadIdx.x >> 5, jj = threadIdx.x & 31;
        float dv = dots[h][jj];
        float mx = dv;
        for (int o = 16; o; o >>= 1) mx = fmaxf(mx, __shfl_xor(mx, o));
        float e = expf(dv - mx);
        float s = e;
        for (int o = 16; o; o >>= 1) s += __shfl_xor(s, o);
        p[h][jj] = e / s;
    }
    __syncthreads();

    // --- phase 2: weighted V sum, float2 per thread ---
    {
        int hd = threadIdx.x >> 5;
        int jd = threadIdx.x & 31;     // dim-pair index (dims 2jd, 2jd+1)
        float o0 = 0.f, o1 = 0.f;
        #pragma unroll 8
        for (int jj = 0; jj < KNN; ++jj) {
            int mm = nb[jj];
            float2 vv = *(const float2*)(vbase + (size_t)mm * TRIPLE + hd * DHEAD + jd * 2);
            float pw = p[hd][jj];
            o0 += pw * vv.x;
            o1 += pw * vv.y;
        }
        size_t base = rowoff * INNER + hd * DHEAD + jd * 2;
        unsigned q0 = bfsplit(o0);
        unsigned q1 = bfsplit(o1);
        *(unsigned*)(ahi + base) = (q0 & 0xffffu) | (q1 << 16);
        *(unsigned*)(alo + base) = (q0 >> 16) | (q1 & 0xffff0000u);
    }
}

// ---------------------------------------------------------------------------
extern "C" void kernel_launch(void* const* d_in, const int* in_sizes, int n_in,
                              void* d_out, int out_size, void* d_ws, size_t ws_size,
                              hipStream_t stream) {
    const float* x    = (const float*)d_in[0];   // [2,2048,256]
    const float* Wqkv = (const float*)d_in[1];   // [256,1536]
    const float* Wout = (const float*)d_in[2];   // [512,256]
    const float* bout = (const float*)d_in[3];   // [256]
    float* out = (float*)d_out;                  // [2,2048,256]

    // workspace layout
    float* S    = (float*)d_ws;                           // 8,388,608 f32
    float* x2   = S + (size_t)BATCH * NPTS * NPTS;        // 4096 f32
    int*   idx  = (int*)(x2 + (size_t)BATCH * NPTS);      // 131072 int
    float* qkv  = (float*)(idx + (size_t)BATCH * NPTS * KNN);   // 6,291,456 f32
    ushort* xhi = (ushort*)(qkv + (size_t)BATCH * NPTS * TRIPLE);
    ushort* xlo   = xhi   + (size_t)BATCH * NPTS * CDIM;  // 1,048,576 each
    ushort* xqd   = xlo   + (size_t)BATCH * NPTS * CDIM;
    ushort* ahi   = xqd   + (size_t)BATCH * NPTS * CDIM;  // 2,097,152 each
    ushort* alo   = ahi   + (size_t)BATCH * NPTS * INNER;
    ushort* wqhiT = alo   + (size_t)BATCH * NPTS * INNER; // [1536][256]
    ushort* wqloT = wqhiT + (size_t)TRIPLE * CDIM;
    ushort* wohiT = wqloT + (size_t)TRIPLE * CDIM;        // [256][512]
    ushort* woloT = wohiT + (size_t)CDIM * INNER;

    // 1. row squared norms
    rowsq_kernel<<<BATCH * NPTS, 64, 0, stream>>>(x, x2);

    // 2. split x -> bf16 h/l/q
    {
        int n = BATCH * NPTS * CDIM;
        split3_kernel<<<n / 1024, 256, 0, stream>>>(x, xhi, xlo, xqd, n);
    }

    // 3. transpose+split weights
    {
        dim3 g1(TRIPLE / 64, CDIM / 64);
        wtrans_split_kernel<<<g1, 256, 0, stream>>>(Wqkv, wqhiT, wqloT, CDIM, TRIPLE);
        dim3 g2(CDIM / 64, INNER / 64);
        wtrans_split_kernel<<<g2, 256, 0, stream>>>(Wout, wohiT, woloT, INNER, CDIM);
    }

    // 4. Gram/scores via 3-split MFMA (fp32-precision, selection-safe)
    {
        dim3 grid(NPTS / 128, NPTS / 128, BATCH);
        gram_mfma_kernel<<<grid, 256, 0, stream>>>(xhi, xlo, xqd, x2, S);
    }

    // 5. top-32 neighbor selection (range-normalized histogram select)
    {
        dim3 grid(NPTS, BATCH);
        knn_select2_kernel<<<grid, 256, 0, stream>>>(S, idx);
    }

    // 6. qkv projection: [4096,256] @ [256,1536] via split-bf16 MFMA
    {
        dim3 grid(TRIPLE / 128, (BATCH * NPTS) / 128);
        mfma_split_gemm<<<grid, 256, 0, stream>>>(xhi, xlo, wqhiT, wqloT,
                                                  nullptr, qkv,
                                                  BATCH * NPTS, TRIPLE, CDIM);
    }

    // 7. sparse attention -> pre-split hi/lo
    {
        dim3 grid(NPTS, BATCH);
        attn_kernel<<<grid, 256, 0, stream>>>(qkv, idx, ahi, alo);
    }

    // 8. output projection: [4096,512] @ [512,256] + bias
    {
        dim3 grid(CDIM / 128, (BATCH * NPTS) / 128);
        mfma_split_gemm<<<grid, 256, 0, stream>>>(ahi, alo, wohiT, woloT,
                                                  bout, out,
                                                  BATCH * NPTS, CDIM, INNER);
    }
}

// Round 8
// 139.421 us; speedup vs baseline: 3.1430x; 1.0341x over previous
//
#include <hip/hip_runtime.h>
#include <hip/hip_bf16.h>

// Problem constants
#define BATCH 2
#define NPTS  2048
#define CDIM  256
#define NHEAD 8
#define DHEAD 64
#define INNER 512            // NHEAD*DHEAD
#define TRIPLE 1536          // 3*INNER
#define KNN   32
#define SCALE 0.125f         // 64^-0.5

typedef __attribute__((ext_vector_type(8))) short short8;      // 8 bf16 (4 VGPR)
typedef __attribute__((ext_vector_type(4))) float floatx4;     // MFMA acc
typedef __attribute__((ext_vector_type(4))) unsigned short ushort4v;
typedef unsigned short ushort;

#define LSTR 40              // LDS tile row stride in ushort (80 B)
#define TILE (128*LSTR)      // one 128-row tile (5120 ushort = 10240 B)

// bf16 split: x = hi + lo (both RNE bf16). hi in [15:0], lo in [31:16].
__device__ __forceinline__ unsigned bfsplit(float x) {
    unsigned u = __float_as_uint(x);
    unsigned r = u + 0x7fffu + ((u >> 16) & 1u);
    unsigned hs = r >> 16;
    float hf = __uint_as_float(hs << 16);
    float lo = x - hf;
    unsigned u2 = __float_as_uint(lo);
    unsigned r2 = u2 + 0x7fffu + ((u2 >> 16) & 1u);
    return (hs & 0xffffu) | (r2 & 0xffff0000u);
}

// 3-component split: x = h + l + q, residual ~2^-27 relative.
__device__ __forceinline__ void bfsplit3(float x, ushort* hh, ushort* ll, ushort* qq) {
    unsigned u = __float_as_uint(x);
    unsigned r = u + 0x7fffu + ((u >> 16) & 1u);
    unsigned hs = r >> 16;
    float hf = __uint_as_float(hs << 16);
    float d1 = x - hf;
    unsigned u2 = __float_as_uint(d1);
    unsigned r2 = u2 + 0x7fffu + ((u2 >> 16) & 1u);
    unsigned ls = r2 >> 16;
    float lf = __uint_as_float(ls << 16);
    float d2 = d1 - lf;
    unsigned u3 = __float_as_uint(d2);
    unsigned r3 = u3 + 0x7fffu + ((u3 >> 16) & 1u);
    *hh = (ushort)hs;
    *ll = (ushort)ls;
    *qq = (ushort)(r3 >> 16);
}

// ---------------------------------------------------------------------------
// Kernel 1 (fused): row squared norms + fp32 -> bf16 h/l/q split of x.
// One wave per row (grid = B*N/4 blocks of 256).
// ---------------------------------------------------------------------------
__global__ __launch_bounds__(256) void input_prep_kernel(const float* __restrict__ x,
                                                         float* __restrict__ x2,
                                                         ushort* __restrict__ xhi,
                                                         ushort* __restrict__ xlo,
                                                         ushort* __restrict__ xqd) {
    int wave = threadIdx.x >> 6, lane = threadIdx.x & 63;
    int row = blockIdx.x * 4 + wave;
    const float* xr = x + (size_t)row * CDIM;
    float4 v = *(const float4*)(xr + lane * 4);
    float s = v.x*v.x + v.y*v.y + v.z*v.z + v.w*v.w;
    #pragma unroll
    for (int o = 32; o; o >>= 1) s += __shfl_down(s, o);
    if (lane == 0) x2[row] = s;

    ushort h[4], l[4], q[4];
    bfsplit3(v.x, &h[0], &l[0], &q[0]);
    bfsplit3(v.y, &h[1], &l[1], &q[1]);
    bfsplit3(v.z, &h[2], &l[2], &q[2]);
    bfsplit3(v.w, &h[3], &l[3], &q[3]);
    size_t off = (size_t)row * CDIM + lane * 4;
    *(ushort4v*)(xhi + off) = *(ushort4v*)h;
    *(ushort4v*)(xlo + off) = *(ushort4v*)l;
    *(ushort4v*)(xqd + off) = *(ushort4v*)q;
}

// ---------------------------------------------------------------------------
// Kernel 2 (merged): both weight transposes+splits in one launch.
// blocks 0..95: Wqkv [256][1536] -> [1536][256]; 96..127: Wout [512][256]->[256][512]
// ---------------------------------------------------------------------------
__global__ __launch_bounds__(256) void wtrans2_kernel(const float* __restrict__ Wqkv,
                                                      const float* __restrict__ Wout,
                                                      ushort* __restrict__ wqhiT,
                                                      ushort* __restrict__ wqloT,
                                                      ushort* __restrict__ wohiT,
                                                      ushort* __restrict__ woloT) {
    __shared__ float tile[64][65];
    const float* W; ushort* hiT; ushort* loT; int K, N, bx, by;
    int bid = blockIdx.x;
    if (bid < 96) { W = Wqkv; hiT = wqhiT; loT = wqloT; K = CDIM;  N = TRIPLE; bx = bid % 24; by = bid / 24; }
    else { int t = bid - 96; W = Wout; hiT = wohiT; loT = woloT; K = INNER; N = CDIM;  bx = t % 4;  by = t / 4; }
    int k0 = by * 64, n0 = bx * 64;
    #pragma unroll
    for (int i = 0; i < 4; ++i) {
        int f = threadIdx.x + i * 256;
        int r = f >> 4, c4 = (f & 15) * 4;
        float4 v = *(const float4*)(W + (size_t)(k0 + r) * N + n0 + c4);
        tile[r][c4+0] = v.x; tile[r][c4+1] = v.y;
        tile[r][c4+2] = v.z; tile[r][c4+3] = v.w;
    }
    __syncthreads();
    #pragma unroll
    for (int i = 0; i < 4; ++i) {
        int f = threadIdx.x + i * 256;
        int rn = f >> 4, ck = (f & 15) * 4;
        unsigned p0 = bfsplit(tile[ck+0][rn]);
        unsigned p1 = bfsplit(tile[ck+1][rn]);
        unsigned p2 = bfsplit(tile[ck+2][rn]);
        unsigned p3 = bfsplit(tile[ck+3][rn]);
        ushort4v h, l;
        h.x = (ushort)p0; l.x = (ushort)(p0 >> 16);
        h.y = (ushort)p1; l.y = (ushort)(p1 >> 16);
        h.z = (ushort)p2; l.z = (ushort)(p2 >> 16);
        h.w = (ushort)p3; l.w = (ushort)(p3 >> 16);
        *(ushort4v*)(hiT + (size_t)(n0 + rn) * K + k0 + ck) = h;
        *(ushort4v*)(loT + (size_t)(n0 + rn) * K + k0 + ck) = l;
    }
}

// ---------------------------------------------------------------------------
// Shared MFMA bodies
// ---------------------------------------------------------------------------
// split-bf16 GEMM body (hi/lo, 3 products): C[bi..][bj..] tile of A@B (+bias)
__device__ __forceinline__ void gemm_split_body(const ushort* __restrict__ Ahi,
                                                const ushort* __restrict__ Alo,
                                                const ushort* __restrict__ BhiT,
                                                const ushort* __restrict__ BloT,
                                                const float* __restrict__ bias,
                                                float* __restrict__ C,
                                                int N, int K, int bi, int bj,
                                                ushort* lds) {
    ushort* ldsAh = lds;
    ushort* ldsAl = lds + TILE;
    ushort* ldsBh = lds + 2*TILE;
    ushort* ldsBl = lds + 3*TILE;

    int lane = threadIdx.x & 63, wave = threadIdx.x >> 6;
    int wr = wave >> 1, wc = wave & 1;
    int fr = lane & 15, kg = lane >> 4;

    floatx4 acc[4][4] = {};

    int srow = threadIdx.x >> 1;
    int sseg = (threadIdx.x & 1) * 16;

    const ushort* s0 = Ahi  + (size_t)(bi + srow) * K + sseg;
    const ushort* s1 = Alo  + (size_t)(bi + srow) * K + sseg;
    const ushort* s2 = BhiT + (size_t)(bj + srow) * K + sseg;
    const ushort* s3 = BloT + (size_t)(bj + srow) * K + sseg;
    int dof = srow * LSTR + sseg;

    for (int k0 = 0; k0 < K; k0 += 32) {
        uint4 va0 = *(const uint4*)(s0 + k0);
        uint4 va1 = *(const uint4*)(s0 + k0 + 8);
        uint4 vb0 = *(const uint4*)(s1 + k0);
        uint4 vb1 = *(const uint4*)(s1 + k0 + 8);
        uint4 vc0 = *(const uint4*)(s2 + k0);
        uint4 vc1 = *(const uint4*)(s2 + k0 + 8);
        uint4 vd0 = *(const uint4*)(s3 + k0);
        uint4 vd1 = *(const uint4*)(s3 + k0 + 8);
        *(uint4*)&ldsAh[dof] = va0;  *(uint4*)&ldsAh[dof + 8] = va1;
        *(uint4*)&ldsAl[dof] = vb0;  *(uint4*)&ldsAl[dof + 8] = vb1;
        *(uint4*)&ldsBh[dof] = vc0;  *(uint4*)&ldsBh[dof + 8] = vc1;
        *(uint4*)&ldsBl[dof] = vd0;  *(uint4*)&ldsBl[dof + 8] = vd1;
        __syncthreads();

        short8 a_h[4], a_l[4], b_h[4], b_l[4];
        #pragma unroll
        for (int m = 0; m < 4; ++m) {
            int off = (wr*64 + m*16 + fr) * LSTR + kg*8;
            a_h[m] = *(const short8*)&ldsAh[off];
            a_l[m] = *(const short8*)&ldsAl[off];
        }
        #pragma unroll
        for (int n = 0; n < 4; ++n) {
            int off = (wc*64 + n*16 + fr) * LSTR + kg*8;
            b_h[n] = *(const short8*)&ldsBh[off];
            b_l[n] = *(const short8*)&ldsBl[off];
        }
        #pragma unroll
        for (int m = 0; m < 4; ++m)
            #pragma unroll
            for (int n = 0; n < 4; ++n) {
                acc[m][n] = __builtin_amdgcn_mfma_f32_16x16x32_bf16(a_h[m], b_h[n], acc[m][n], 0, 0, 0);
                acc[m][n] = __builtin_amdgcn_mfma_f32_16x16x32_bf16(a_h[m], b_l[n], acc[m][n], 0, 0, 0);
                acc[m][n] = __builtin_amdgcn_mfma_f32_16x16x32_bf16(a_l[m], b_h[n], acc[m][n], 0, 0, 0);
            }
        __syncthreads();
    }

    #pragma unroll
    for (int m = 0; m < 4; ++m)
        #pragma unroll
        for (int n = 0; n < 4; ++n) {
            int col = bj + wc*64 + n*16 + fr;
            float bv = bias ? bias[col] : 0.0f;
            #pragma unroll
            for (int r = 0; r < 4; ++r) {
                int row = bi + wr*64 + m*16 + kg*4 + r;
                C[(size_t)row * N + col] = acc[m][n][r] + bv;
            }
        }
}

// Gram body: 3-split, 6 products (fp32-precision, selection-safe).
__device__ __forceinline__ void gram_body(const ushort* __restrict__ Ah,
                                          const ushort* __restrict__ Al,
                                          const ushort* __restrict__ Aq,
                                          const float* __restrict__ x2b,
                                          float* __restrict__ Sb,
                                          int bi, int bj, ushort* lds) {
    ushort* A0 = lds;
    ushort* A1 = lds + TILE;
    ushort* A2 = lds + 2*TILE;
    ushort* B0 = lds + 3*TILE;
    ushort* B1 = lds + 4*TILE;
    ushort* B2 = lds + 5*TILE;

    int lane = threadIdx.x & 63, wave = threadIdx.x >> 6;
    int wr = wave >> 1, wc = wave & 1;
    int fr = lane & 15, kg = lane >> 4;

    floatx4 acc[4][4] = {};

    int srow = threadIdx.x >> 1;
    int sseg = (threadIdx.x & 1) * 16;

    const ushort* sAh = Ah + (size_t)(bi + srow) * CDIM + sseg;
    const ushort* sAl = Al + (size_t)(bi + srow) * CDIM + sseg;
    const ushort* sAq = Aq + (size_t)(bi + srow) * CDIM + sseg;
    const ushort* sBh = Ah + (size_t)(bj + srow) * CDIM + sseg;
    const ushort* sBl = Al + (size_t)(bj + srow) * CDIM + sseg;
    const ushort* sBq = Aq + (size_t)(bj + srow) * CDIM + sseg;
    int dof = srow * LSTR + sseg;

    for (int k0 = 0; k0 < CDIM; k0 += 32) {
        uint4 a0 = *(const uint4*)(sAh + k0); uint4 a1 = *(const uint4*)(sAh + k0 + 8);
        uint4 b0 = *(const uint4*)(sAl + k0); uint4 b1 = *(const uint4*)(sAl + k0 + 8);
        uint4 c0 = *(const uint4*)(sAq + k0); uint4 c1 = *(const uint4*)(sAq + k0 + 8);
        uint4 d0 = *(const uint4*)(sBh + k0); uint4 d1 = *(const uint4*)(sBh + k0 + 8);
        uint4 e0 = *(const uint4*)(sBl + k0); uint4 e1 = *(const uint4*)(sBl + k0 + 8);
        uint4 f0 = *(const uint4*)(sBq + k0); uint4 f1 = *(const uint4*)(sBq + k0 + 8);
        *(uint4*)&A0[dof] = a0; *(uint4*)&A0[dof+8] = a1;
        *(uint4*)&A1[dof] = b0; *(uint4*)&A1[dof+8] = b1;
        *(uint4*)&A2[dof] = c0; *(uint4*)&A2[dof+8] = c1;
        *(uint4*)&B0[dof] = d0; *(uint4*)&B0[dof+8] = d1;
        *(uint4*)&B1[dof] = e0; *(uint4*)&B1[dof+8] = e1;
        *(uint4*)&B2[dof] = f0; *(uint4*)&B2[dof+8] = f1;
        __syncthreads();

        short8 a_h[4], a_l[4], a_q[4], b_h[4], b_l[4], b_q[4];
        #pragma unroll
        for (int m = 0; m < 4; ++m) {
            int off = (wr*64 + m*16 + fr) * LSTR + kg*8;
            a_h[m] = *(const short8*)&A0[off];
            a_l[m] = *(const short8*)&A1[off];
            a_q[m] = *(const short8*)&A2[off];
        }
        #pragma unroll
        for (int n = 0; n < 4; ++n) {
            int off = (wc*64 + n*16 + fr) * LSTR + kg*8;
            b_h[n] = *(const short8*)&B0[off];
            b_l[n] = *(const short8*)&B1[off];
            b_q[n] = *(const short8*)&B2[off];
        }
        #pragma unroll
        for (int m = 0; m < 4; ++m)
            #pragma unroll
            for (int n = 0; n < 4; ++n) {
                acc[m][n] = __builtin_amdgcn_mfma_f32_16x16x32_bf16(a_h[m], b_h[n], acc[m][n], 0, 0, 0);
                acc[m][n] = __builtin_amdgcn_mfma_f32_16x16x32_bf16(a_h[m], b_l[n], acc[m][n], 0, 0, 0);
                acc[m][n] = __builtin_amdgcn_mfma_f32_16x16x32_bf16(a_l[m], b_h[n], acc[m][n], 0, 0, 0);
                acc[m][n] = __builtin_amdgcn_mfma_f32_16x16x32_bf16(a_l[m], b_l[n], acc[m][n], 0, 0, 0);
                acc[m][n] = __builtin_amdgcn_mfma_f32_16x16x32_bf16(a_h[m], b_q[n], acc[m][n], 0, 0, 0);
                acc[m][n] = __builtin_amdgcn_mfma_f32_16x16x32_bf16(a_q[m], b_h[n], acc[m][n], 0, 0, 0);
            }
        __syncthreads();
    }

    #pragma unroll
    for (int m = 0; m < 4; ++m)
        #pragma unroll
        for (int n = 0; n < 4; ++n) {
            int col = bj + wc*64 + n*16 + fr;
            float xc = x2b[col];
            #pragma unroll
            for (int r = 0; r < 4; ++r) {
                int row = bi + wr*64 + m*16 + kg*4 + r;
                float val = xc - 2.0f * acc[m][n][r];
                if (row == col) val = __builtin_inff();
                Sb[(size_t)row * NPTS + col] = val;
            }
        }
}

// ---------------------------------------------------------------------------
// Kernel 3 (merged): gram tiles (blocks 0..511) + qkv GEMM tiles (512..895).
// Both depend only on the splits/weights -> one launch, concurrent fill.
// ---------------------------------------------------------------------------
__global__ __launch_bounds__(256) void fused_mfma_kernel(const ushort* __restrict__ xh,
                                                         const ushort* __restrict__ xl,
                                                         const ushort* __restrict__ xq,
                                                         const float* __restrict__ x2,
                                                         float* __restrict__ S,
                                                         const ushort* __restrict__ wqhiT,
                                                         const ushort* __restrict__ wqloT,
                                                         float* __restrict__ qkv) {
    __shared__ ushort lds[6*TILE];
    int bid = blockIdx.x;
    if (bid < 512) {
        int b = bid >> 8, rem = bid & 255;
        int by = rem >> 4, bx = rem & 15;
        size_t xoff = (size_t)b * NPTS * CDIM;
        gram_body(xh + xoff, xl + xoff, xq + xoff,
                  x2 + (size_t)b * NPTS, S + (size_t)b * NPTS * NPTS,
                  by * 128, bx * 128, lds);
    } else {
        int t = bid - 512;               // 0..383
        int bx = t % 12, by = t / 12;    // 12 col-tiles, 32 row-tiles
        gemm_split_body(xh, xl, wqhiT, wqloT, nullptr, qkv,
                        TRIPLE, CDIM, by * 128, bx * 128, lds);
    }
}

// ---------------------------------------------------------------------------
// Kernel 4: out projection (standalone split GEMM + bias).
// ---------------------------------------------------------------------------
__global__ __launch_bounds__(256) void outproj_kernel(const ushort* __restrict__ Ahi,
                                                      const ushort* __restrict__ Alo,
                                                      const ushort* __restrict__ BhiT,
                                                      const ushort* __restrict__ BloT,
                                                      const float* __restrict__ bias,
                                                      float* __restrict__ C) {
    __shared__ ushort lds[4*TILE];
    gemm_split_body(Ahi, Alo, BhiT, BloT, bias, C,
                    CDIM, INNER, blockIdx.y * 128, blockIdx.x * 128, lds);
}

// ---------------------------------------------------------------------------
// Kernel 5: per-row exact top-KNN via range-normalized histogram select.
// ---------------------------------------------------------------------------
__device__ __forceinline__ unsigned block_excl_scan_256(unsigned c,
                                                        unsigned* wsum,
                                                        unsigned* total_out) {
    unsigned v = c;
    #pragma unroll
    for (int o = 1; o < 64; o <<= 1) {
        unsigned t = __shfl_up(v, o);
        if ((threadIdx.x & 63) >= o) v += t;
    }
    if ((threadIdx.x & 63) == 63) wsum[threadIdx.x >> 6] = v;
    __syncthreads();
    unsigned woff = 0;
    int mywave = threadIdx.x >> 6;
    #pragma unroll
    for (int w = 0; w < 4; ++w) {
        unsigned s = wsum[w];
        if (w < mywave) woff += s;
    }
    if (total_out) *total_out = wsum[0] + wsum[1] + wsum[2] + wsum[3];
    __syncthreads();
    return v + woff - c;
}

__global__ __launch_bounds__(256) void knn_select2_kernel(const float* __restrict__ S,
                                                          int* __restrict__ idx) {
    int n = blockIdx.x, b = blockIdx.y;
    const float* row = S + ((size_t)b * NPTS + n) * NPTS;
    int* out = idx + ((size_t)b * NPTS + n) * KNN;

    __shared__ unsigned keys[NPTS];      // 8 KB
    __shared__ unsigned hist[256];       // 1 KB
    __shared__ unsigned wsum[4];
    __shared__ unsigned s_red[8];
    __shared__ unsigned sh_lo, sh_hi, sh_rank, sh_cnt, sh_break;
    __shared__ unsigned ckey[64];
    __shared__ int     cidx[64];
    __shared__ unsigned s_ccount;

    int tid = threadIdx.x;

    // vectorized load + order-preserving map; diag -> max key, excluded from range
    unsigned mn = 0xffffffffu, mx = 0u;
    {
        int i0 = tid * 8;
        float4 f0 = *(const float4*)(row + i0);
        float4 f1 = *(const float4*)(row + i0 + 4);
        float fv[8] = { f0.x, f0.y, f0.z, f0.w, f1.x, f1.y, f1.z, f1.w };
        #pragma unroll
        for (int t = 0; t < 8; ++t) {
            int i = i0 + t;
            unsigned u;
            if (i == n) {
                u = 0xffffffffu;
            } else {
                unsigned v = __float_as_uint(fv[t]);
                u = (v & 0x80000000u) ? ~v : (v | 0x80000000u);
                mn = min(mn, u); mx = max(mx, u);
            }
            keys[i] = u;
        }
    }
    #pragma unroll
    for (int o = 32; o; o >>= 1) {
        mn = min(mn, (unsigned)__shfl_xor((int)mn, o));
        mx = max(mx, (unsigned)__shfl_xor((int)mx, o));
    }
    if ((tid & 63) == 0) { s_red[tid >> 6] = mn; s_red[4 + (tid >> 6)] = mx; }
    __syncthreads();
    if (tid == 0) {
        unsigned a = min(min(s_red[0], s_red[1]), min(s_red[2], s_red[3]));
        unsigned z = max(max(s_red[4], s_red[5]), max(s_red[6], s_red[7]));
        sh_lo = a; sh_hi = z; sh_rank = KNN; sh_break = 0; s_ccount = 0;
    }
    __syncthreads();

    for (int it = 0; it < 5; ++it) {
        unsigned lo = sh_lo, hi = sh_hi;
        unsigned range1 = hi - lo;
        int shift = 0;
        if (range1 > 255u) shift = 24 - __clz(range1);
        hist[tid] = 0;
        __syncthreads();
        for (int i = tid; i < NPTS; i += 256) {
            unsigned u = keys[i];
            if (u >= lo && u <= hi)
                atomicAdd(&hist[(u - lo) >> shift], 1u);
        }
        __syncthreads();
        unsigned c = hist[tid];
        unsigned rank = sh_rank;
        unsigned excl = block_excl_scan_256(c, wsum, nullptr);
        if (excl < rank && excl + c >= rank) {
            sh_rank = rank - excl;
            unsigned nlo = lo + ((unsigned)tid << shift);
            unsigned span = (shift == 0) ? 0u : (((1u << shift)) - 1u);
            unsigned nhi = nlo + span;
            if (nhi > hi || nhi < nlo) nhi = hi;
            sh_lo = nlo; sh_hi = nhi;
            sh_cnt = c;
            sh_break = (shift == 0 || c <= 64u) ? 1u : 0u;
        }
        __syncthreads();
        if (sh_break) break;
    }

    unsigned lo = sh_lo, hi = sh_hi, rank = sh_rank, cnt = sh_cnt;

    unsigned lt = 0;
    for (int i = tid; i < NPTS; i += 256) lt += (keys[i] < lo) ? 1u : 0u;
    unsigned pos = block_excl_scan_256(lt, wsum, nullptr);
    for (int i = tid; i < NPTS; i += 256) {
        unsigned u = keys[i];
        if (u < lo) out[pos++] = i;
        else if (u >= lo && u <= hi && cnt <= 64u) {
            unsigned p = atomicAdd(&s_ccount, 1u);
            ckey[p] = u; cidx[p] = i;
        }
    }
    __syncthreads();

    unsigned base = KNN - rank;
    if (cnt <= 64u) {
        if (tid < (int)cnt) {
            unsigned myk = ckey[tid]; int myi = cidx[tid];
            unsigned r = 0;
            for (unsigned s = 0; s < cnt; ++s) {
                unsigned sk = ckey[s]; int si = cidx[s];
                r += (sk < myk || (sk == myk && si < myi)) ? 1u : 0u;
            }
            if (r < rank) out[base + r] = myi;
        }
    } else {
        if (tid == 0) {
            unsigned need = rank, p = base;
            for (int i = 0; i < NPTS && need; ++i) {
                if (keys[i] >= lo && keys[i] <= hi) { out[p++] = i; --need; }
            }
        }
    }
}

// ---------------------------------------------------------------------------
// Kernel 6: sparse graph attention, deep-ILP gather version.
// ---------------------------------------------------------------------------
__global__ __launch_bounds__(256) void attn_kernel(const float* __restrict__ qkv,
                                                   const int* __restrict__ idx,
                                                   ushort* __restrict__ ahi,
                                                   ushort* __restrict__ alo) {
    int n = blockIdx.x, b = blockIdx.y;
    size_t rowoff = ((size_t)b * NPTS + n);
    const float* qrow  = qkv + rowoff * TRIPLE;
    const float* kbase = qkv + (size_t)b * NPTS * TRIPLE + INNER;
    const float* vbase = qkv + (size_t)b * NPTS * TRIPLE + 2*INNER;

    __shared__ int   nb[KNN];
    __shared__ float dots[NHEAD][KNN];
    __shared__ float p[NHEAD][KNN];

    if (threadIdx.x < KNN)
        nb[threadIdx.x] = idx[rowoff * KNN + threadIdx.x];
    __syncthreads();

    // --- phase 1: dots; all 16 K loads issued before the reduce chain ---
    {
        int j = threadIdx.x >> 3;      // neighbor 0..31
        int l = threadIdx.x & 7;       // 8-float segment 0..7
        const float* krow = kbase + (size_t)nb[j] * TRIPLE + l * 8;
        float4 kr0[NHEAD], kr1[NHEAD];
        #pragma unroll
        for (int h = 0; h < NHEAD; ++h) {
            kr0[h] = *(const float4*)(krow + h * DHEAD);
            kr1[h] = *(const float4*)(krow + h * DHEAD + 4);
        }
        const float* qp = qrow + l * 8;
        #pragma unroll
        for (int h = 0; h < NHEAD; ++h) {
            float4 q0 = *(const float4*)(qp + h * DHEAD);
            float4 q1 = *(const float4*)(qp + h * DHEAD + 4);
            float d = kr0[h].x*q0.x + kr0[h].y*q0.y + kr0[h].z*q0.z + kr0[h].w*q0.w
                    + kr1[h].x*q1.x + kr1[h].y*q1.y + kr1[h].z*q1.z + kr1[h].w*q1.w;
            d += __shfl_xor(d, 1);
            d += __shfl_xor(d, 2);
            d += __shfl_xor(d, 4);
            if (l == 0) dots[h][j] = d * SCALE;
        }
    }
    __syncthreads();

    // --- phase 1b: softmax per head ---
    {
        int h = threadIdx.x >> 5, jj = threadIdx.x & 31;
        float dv = dots[h][jj];
        float mx = dv;
        for (int o = 16; o; o >>= 1) mx = fmaxf(mx, __shfl_xor(mx, o));
        float e = expf(dv - mx);
        float s = e;
        for (int o = 16; o; o >>= 1) s += __shfl_xor(s, o);
        p[h][jj] = e / s;
    }
    __syncthreads();

    // --- phase 2: weighted V sum, 8 loads in flight per group ---
    {
        int hd = threadIdx.x >> 5;
        int jd = threadIdx.x & 31;
        const float* vb = vbase + hd * DHEAD + jd * 2;
        float o0 = 0.f, o1 = 0.f;
        #pragma unroll
        for (int g = 0; g < 4; ++g) {
            float2 vv[8]; float pw[8];
            #pragma unroll
            for (int t = 0; t < 8; ++t) {
                int jj = g * 8 + t;
                vv[t] = *(const float2*)(vb + (size_t)nb[jj] * TRIPLE);
                pw[t] = p[hd][jj];
            }
            #pragma unroll
            for (int t = 0; t < 8; ++t) { o0 += pw[t] * vv[t].x; o1 += pw[t] * vv[t].y; }
        }
        size_t base = rowoff * INNER + hd * DHEAD + jd * 2;
        unsigned q0 = bfsplit(o0);
        unsigned q1 = bfsplit(o1);
        *(unsigned*)(ahi + base) = (q0 & 0xffffu) | (q1 << 16);
        *(unsigned*)(alo + base) = (q0 >> 16) | (q1 & 0xffff0000u);
    }
}

// ---------------------------------------------------------------------------
extern "C" void kernel_launch(void* const* d_in, const int* in_sizes, int n_in,
                              void* d_out, int out_size, void* d_ws, size_t ws_size,
                              hipStream_t stream) {
    const float* x    = (const float*)d_in[0];   // [2,2048,256]
    const float* Wqkv = (const float*)d_in[1];   // [256,1536]
    const float* Wout = (const float*)d_in[2];   // [512,256]
    const float* bout = (const float*)d_in[3];   // [256]
    float* out = (float*)d_out;                  // [2,2048,256]

    // workspace layout
    float* S    = (float*)d_ws;                           // 8,388,608 f32
    float* x2   = S + (size_t)BATCH * NPTS * NPTS;        // 4096 f32
    int*   idx  = (int*)(x2 + (size_t)BATCH * NPTS);      // 131072 int
    float* qkv  = (float*)(idx + (size_t)BATCH * NPTS * KNN);   // 6,291,456 f32
    ushort* xhi = (ushort*)(qkv + (size_t)BATCH * NPTS * TRIPLE);
    ushort* xlo   = xhi   + (size_t)BATCH * NPTS * CDIM;
    ushort* xqd   = xlo   + (size_t)BATCH * NPTS * CDIM;
    ushort* ahi   = xqd   + (size_t)BATCH * NPTS * CDIM;
    ushort* alo   = ahi   + (size_t)BATCH * NPTS * INNER;
    ushort* wqhiT = alo   + (size_t)BATCH * NPTS * INNER; // [1536][256]
    ushort* wqloT = wqhiT + (size_t)TRIPLE * CDIM;
    ushort* wohiT = wqloT + (size_t)TRIPLE * CDIM;        // [256][512]
    ushort* woloT = wohiT + (size_t)CDIM * INNER;

    // 1. fused rowsq + x split
    input_prep_kernel<<<(BATCH * NPTS) / 4, 256, 0, stream>>>(x, x2, xhi, xlo, xqd);

    // 2. merged weight transpose+split
    wtrans2_kernel<<<128, 256, 0, stream>>>(Wqkv, Wout, wqhiT, wqloT, wohiT, woloT);

    // 3. merged gram + qkv GEMM
    fused_mfma_kernel<<<896, 256, 0, stream>>>(xhi, xlo, xqd, x2, S,
                                               wqhiT, wqloT, qkv);

    // 4. top-32 neighbor selection
    {
        dim3 grid(NPTS, BATCH);
        knn_select2_kernel<<<grid, 256, 0, stream>>>(S, idx);
    }

    // 5. sparse attention -> pre-split hi/lo
    {
        dim3 grid(NPTS, BATCH);
        attn_kernel<<<grid, 256, 0, stream>>>(qkv, idx, ahi, alo);
    }

    // 6. output projection: [4096,512] @ [512,256] + bias
    {
        dim3 grid(CDIM / 128, (BATCH * NPTS) / 128);
        outproj_kernel<<<grid, 256, 0, stream>>>(ahi, alo, wohiT, woloT, bout, out);
    }
}

// Round 9
// 131.152 us; speedup vs baseline: 3.3412x; 1.0631x over previous
//
#include <hip/hip_runtime.h>
#include <hip/hip_bf16.h>

// Problem constants
#define BATCH 2
#define NPTS  2048
#define CDIM  256
#define NHEAD 8
#define DHEAD 64
#define INNER 512            // NHEAD*DHEAD
#define TRIPLE 1536          // 3*INNER
#define KNN   32
#define SCALE 0.125f         // 64^-0.5

typedef __attribute__((ext_vector_type(8))) short short8;      // 8 bf16 (4 VGPR)
typedef __attribute__((ext_vector_type(4))) float floatx4;     // MFMA acc
typedef __attribute__((ext_vector_type(4))) unsigned short ushort4v;
typedef unsigned short ushort;

#define TW  32               // LDS tile row width in ushort (64 B, linear)
#define TSZ (128*TW)         // ushorts per 128-row tile (8192 B)

// async global->LDS, 16 B per lane; dest = wave-uniform base + lane*16
__device__ __forceinline__ void glds16(const ushort* g, ushort* l) {
    __builtin_amdgcn_global_load_lds(
        (const __attribute__((address_space(1))) unsigned int*)g,
        (__attribute__((address_space(3))) unsigned int*)l, 16, 0, 0);
}

// bf16 split: x = hi + lo (both RNE bf16). hi in [15:0], lo in [31:16].
__device__ __forceinline__ unsigned bfsplit(float x) {
    unsigned u = __float_as_uint(x);
    unsigned r = u + 0x7fffu + ((u >> 16) & 1u);
    unsigned hs = r >> 16;
    float hf = __uint_as_float(hs << 16);
    float lo = x - hf;
    unsigned u2 = __float_as_uint(lo);
    unsigned r2 = u2 + 0x7fffu + ((u2 >> 16) & 1u);
    return (hs & 0xffffu) | (r2 & 0xffff0000u);
}

// 3-component split: x = h + l + q, residual ~2^-27 relative.
__device__ __forceinline__ void bfsplit3(float x, ushort* hh, ushort* ll, ushort* qq) {
    unsigned u = __float_as_uint(x);
    unsigned r = u + 0x7fffu + ((u >> 16) & 1u);
    unsigned hs = r >> 16;
    float hf = __uint_as_float(hs << 16);
    float d1 = x - hf;
    unsigned u2 = __float_as_uint(d1);
    unsigned r2 = u2 + 0x7fffu + ((u2 >> 16) & 1u);
    unsigned ls = r2 >> 16;
    float lf = __uint_as_float(ls << 16);
    float d2 = d1 - lf;
    unsigned u3 = __float_as_uint(d2);
    unsigned r3 = u3 + 0x7fffu + ((u3 >> 16) & 1u);
    *hh = (ushort)hs;
    *ll = (ushort)ls;
    *qq = (ushort)(r3 >> 16);
}

// ---------------------------------------------------------------------------
// Kernel 1 (fused): row squared norms + fp32 -> bf16 h/l/q split of x.
// ---------------------------------------------------------------------------
__global__ __launch_bounds__(256) void input_prep_kernel(const float* __restrict__ x,
                                                         float* __restrict__ x2,
                                                         ushort* __restrict__ xhi,
                                                         ushort* __restrict__ xlo,
                                                         ushort* __restrict__ xqd) {
    int wave = threadIdx.x >> 6, lane = threadIdx.x & 63;
    int row = blockIdx.x * 4 + wave;
    const float* xr = x + (size_t)row * CDIM;
    float4 v = *(const float4*)(xr + lane * 4);
    float s = v.x*v.x + v.y*v.y + v.z*v.z + v.w*v.w;
    #pragma unroll
    for (int o = 32; o; o >>= 1) s += __shfl_down(s, o);
    if (lane == 0) x2[row] = s;

    ushort h[4], l[4], q[4];
    bfsplit3(v.x, &h[0], &l[0], &q[0]);
    bfsplit3(v.y, &h[1], &l[1], &q[1]);
    bfsplit3(v.z, &h[2], &l[2], &q[2]);
    bfsplit3(v.w, &h[3], &l[3], &q[3]);
    size_t off = (size_t)row * CDIM + lane * 4;
    *(ushort4v*)(xhi + off) = *(ushort4v*)h;
    *(ushort4v*)(xlo + off) = *(ushort4v*)l;
    *(ushort4v*)(xqd + off) = *(ushort4v*)q;
}

// ---------------------------------------------------------------------------
// Kernel 2 (merged): both weight transposes+splits in one launch.
// ---------------------------------------------------------------------------
__global__ __launch_bounds__(256) void wtrans2_kernel(const float* __restrict__ Wqkv,
                                                      const float* __restrict__ Wout,
                                                      ushort* __restrict__ wqhiT,
                                                      ushort* __restrict__ wqloT,
                                                      ushort* __restrict__ wohiT,
                                                      ushort* __restrict__ woloT) {
    __shared__ float tile[64][65];
    const float* W; ushort* hiT; ushort* loT; int K, N, bx, by;
    int bid = blockIdx.x;
    if (bid < 96) { W = Wqkv; hiT = wqhiT; loT = wqloT; K = CDIM;  N = TRIPLE; bx = bid % 24; by = bid / 24; }
    else { int t = bid - 96; W = Wout; hiT = wohiT; loT = woloT; K = INNER; N = CDIM;  bx = t % 4;  by = t / 4; }
    int k0 = by * 64, n0 = bx * 64;
    #pragma unroll
    for (int i = 0; i < 4; ++i) {
        int f = threadIdx.x + i * 256;
        int r = f >> 4, c4 = (f & 15) * 4;
        float4 v = *(const float4*)(W + (size_t)(k0 + r) * N + n0 + c4);
        tile[r][c4+0] = v.x; tile[r][c4+1] = v.y;
        tile[r][c4+2] = v.z; tile[r][c4+3] = v.w;
    }
    __syncthreads();
    #pragma unroll
    for (int i = 0; i < 4; ++i) {
        int f = threadIdx.x + i * 256;
        int rn = f >> 4, ck = (f & 15) * 4;
        unsigned p0 = bfsplit(tile[ck+0][rn]);
        unsigned p1 = bfsplit(tile[ck+1][rn]);
        unsigned p2 = bfsplit(tile[ck+2][rn]);
        unsigned p3 = bfsplit(tile[ck+3][rn]);
        ushort4v h, l;
        h.x = (ushort)p0; l.x = (ushort)(p0 >> 16);
        h.y = (ushort)p1; l.y = (ushort)(p1 >> 16);
        h.z = (ushort)p2; l.z = (ushort)(p2 >> 16);
        h.w = (ushort)p3; l.w = (ushort)(p3 >> 16);
        *(ushort4v*)(hiT + (size_t)(n0 + rn) * K + k0 + ck) = h;
        *(ushort4v*)(loT + (size_t)(n0 + rn) * K + k0 + ck) = l;
    }
}

// ---------------------------------------------------------------------------
// MFMA bodies: linear LDS tiles + global_load_lds staging with
// chunk-XOR swizzle (LDS chunk c of row r holds K-chunk c ^ ((r>>1)&3)).
// ---------------------------------------------------------------------------

// GEMM body (hi/lo, 3 products hh+hl+lh): C tile = A @ B^T (+bias)
__device__ __forceinline__ void gemm_split_body(const ushort* __restrict__ Ahi,
                                                const ushort* __restrict__ Alo,
                                                const ushort* __restrict__ BhiT,
                                                const ushort* __restrict__ BloT,
                                                const float* __restrict__ bias,
                                                float* __restrict__ C,
                                                int N, int K, int bi, int bj,
                                                ushort* lds) {
    int lane = threadIdx.x & 63, wave = threadIdx.x >> 6;
    int wr = wave >> 1, wc = wave & 1;
    int fr = lane & 15, kg = lane >> 4;
    int swz8 = (kg ^ ((fr >> 1) & 3)) * 8;       // read-side chunk swizzle

    int lrow = lane >> 2;                        // staging row within 16-row seg
    int koff = ((lane & 3) ^ ((lane >> 3) & 3)) * 8;  // pre-swizzled source chunk

    const ushort* gb[4];
    gb[0] = Ahi  + (size_t)(bi + lrow) * K + koff;
    gb[1] = Alo  + (size_t)(bi + lrow) * K + koff;
    gb[2] = BhiT + (size_t)(bj + lrow) * K + koff;
    gb[3] = BloT + (size_t)(bj + lrow) * K + koff;

    floatx4 acc[4][4] = {};

    for (int k0 = 0; k0 < K; k0 += 32) {
        #pragma unroll
        for (int t = 0; t < 4; ++t) {
            glds16(gb[t] + (size_t)(wave * 16) * K + k0,       lds + t*TSZ + wave * 512);
            glds16(gb[t] + (size_t)((wave + 4) * 16) * K + k0, lds + t*TSZ + (wave + 4) * 512);
        }
        __syncthreads();

        short8 a_h[4], a_l[4], b_h[4], b_l[4];
        #pragma unroll
        for (int m = 0; m < 4; ++m) {
            int off = (wr*64 + m*16 + fr) * TW + swz8;
            a_h[m] = *(const short8*)&lds[0*TSZ + off];
            a_l[m] = *(const short8*)&lds[1*TSZ + off];
        }
        #pragma unroll
        for (int n = 0; n < 4; ++n) {
            int off = (wc*64 + n*16 + fr) * TW + swz8;
            b_h[n] = *(const short8*)&lds[2*TSZ + off];
            b_l[n] = *(const short8*)&lds[3*TSZ + off];
        }
        #pragma unroll
        for (int m = 0; m < 4; ++m)
            #pragma unroll
            for (int n = 0; n < 4; ++n) {
                acc[m][n] = __builtin_amdgcn_mfma_f32_16x16x32_bf16(a_h[m], b_h[n], acc[m][n], 0, 0, 0);
                acc[m][n] = __builtin_amdgcn_mfma_f32_16x16x32_bf16(a_h[m], b_l[n], acc[m][n], 0, 0, 0);
                acc[m][n] = __builtin_amdgcn_mfma_f32_16x16x32_bf16(a_l[m], b_h[n], acc[m][n], 0, 0, 0);
            }
        __syncthreads();
    }

    #pragma unroll
    for (int m = 0; m < 4; ++m)
        #pragma unroll
        for (int n = 0; n < 4; ++n) {
            int col = bj + wc*64 + n*16 + fr;
            float bv = bias ? bias[col] : 0.0f;
            #pragma unroll
            for (int r = 0; r < 4; ++r) {
                int row = bi + wr*64 + m*16 + kg*4 + r;
                C[(size_t)row * N + col] = acc[m][n][r] + bv;
            }
        }
}

// Gram body: 3-split, 6 products (fp32-precision, selection-safe).
__device__ __forceinline__ void gram_body(const ushort* __restrict__ Ah,
                                          const ushort* __restrict__ Al,
                                          const ushort* __restrict__ Aq,
                                          const float* __restrict__ x2b,
                                          float* __restrict__ Sb,
                                          int bi, int bj, ushort* lds) {
    int lane = threadIdx.x & 63, wave = threadIdx.x >> 6;
    int wr = wave >> 1, wc = wave & 1;
    int fr = lane & 15, kg = lane >> 4;
    int swz8 = (kg ^ ((fr >> 1) & 3)) * 8;

    int lrow = lane >> 2;
    int koff = ((lane & 3) ^ ((lane >> 3) & 3)) * 8;

    const ushort* gb[6];
    gb[0] = Ah + (size_t)(bi + lrow) * CDIM + koff;
    gb[1] = Al + (size_t)(bi + lrow) * CDIM + koff;
    gb[2] = Aq + (size_t)(bi + lrow) * CDIM + koff;
    gb[3] = Ah + (size_t)(bj + lrow) * CDIM + koff;
    gb[4] = Al + (size_t)(bj + lrow) * CDIM + koff;
    gb[5] = Aq + (size_t)(bj + lrow) * CDIM + koff;

    floatx4 acc[4][4] = {};

    for (int k0 = 0; k0 < CDIM; k0 += 32) {
        #pragma unroll
        for (int t = 0; t < 6; ++t) {
            glds16(gb[t] + (size_t)(wave * 16) * CDIM + k0,       lds + t*TSZ + wave * 512);
            glds16(gb[t] + (size_t)((wave + 4) * 16) * CDIM + k0, lds + t*TSZ + (wave + 4) * 512);
        }
        __syncthreads();

        short8 a_h[4], a_l[4], a_q[4], b_h[4], b_l[4], b_q[4];
        #pragma unroll
        for (int m = 0; m < 4; ++m) {
            int off = (wr*64 + m*16 + fr) * TW + swz8;
            a_h[m] = *(const short8*)&lds[0*TSZ + off];
            a_l[m] = *(const short8*)&lds[1*TSZ + off];
            a_q[m] = *(const short8*)&lds[2*TSZ + off];
        }
        #pragma unroll
        for (int n = 0; n < 4; ++n) {
            int off = (wc*64 + n*16 + fr) * TW + swz8;
            b_h[n] = *(const short8*)&lds[3*TSZ + off];
            b_l[n] = *(const short8*)&lds[4*TSZ + off];
            b_q[n] = *(const short8*)&lds[5*TSZ + off];
        }
        #pragma unroll
        for (int m = 0; m < 4; ++m)
            #pragma unroll
            for (int n = 0; n < 4; ++n) {
                acc[m][n] = __builtin_amdgcn_mfma_f32_16x16x32_bf16(a_h[m], b_h[n], acc[m][n], 0, 0, 0);
                acc[m][n] = __builtin_amdgcn_mfma_f32_16x16x32_bf16(a_h[m], b_l[n], acc[m][n], 0, 0, 0);
                acc[m][n] = __builtin_amdgcn_mfma_f32_16x16x32_bf16(a_l[m], b_h[n], acc[m][n], 0, 0, 0);
                acc[m][n] = __builtin_amdgcn_mfma_f32_16x16x32_bf16(a_l[m], b_l[n], acc[m][n], 0, 0, 0);
                acc[m][n] = __builtin_amdgcn_mfma_f32_16x16x32_bf16(a_h[m], b_q[n], acc[m][n], 0, 0, 0);
                acc[m][n] = __builtin_amdgcn_mfma_f32_16x16x32_bf16(a_q[m], b_h[n], acc[m][n], 0, 0, 0);
            }
        __syncthreads();
    }

    #pragma unroll
    for (int m = 0; m < 4; ++m)
        #pragma unroll
        for (int n = 0; n < 4; ++n) {
            int col = bj + wc*64 + n*16 + fr;
            float xc = x2b[col];
            #pragma unroll
            for (int r = 0; r < 4; ++r) {
                int row = bi + wr*64 + m*16 + kg*4 + r;
                float val = xc - 2.0f * acc[m][n][r];
                if (row == col) val = __builtin_inff();
                Sb[(size_t)row * NPTS + col] = val;
            }
        }
}

// ---------------------------------------------------------------------------
// Kernel 3 (merged): gram tiles (blocks 0..511) + qkv GEMM tiles (512..895).
// ---------------------------------------------------------------------------
__global__ __launch_bounds__(256) void fused_mfma_kernel(const ushort* __restrict__ xh,
                                                         const ushort* __restrict__ xl,
                                                         const ushort* __restrict__ xq,
                                                         const float* __restrict__ x2,
                                                         float* __restrict__ S,
                                                         const ushort* __restrict__ wqhiT,
                                                         const ushort* __restrict__ wqloT,
                                                         float* __restrict__ qkv) {
    __shared__ ushort lds[6*TSZ];    // 48 KB -> 3 blocks/CU
    int bid = blockIdx.x;
    if (bid < 512) {
        int b = bid >> 8, rem = bid & 255;
        int by = rem >> 4, bx = rem & 15;
        size_t xoff = (size_t)b * NPTS * CDIM;
        gram_body(xh + xoff, xl + xoff, xq + xoff,
                  x2 + (size_t)b * NPTS, S + (size_t)b * NPTS * NPTS,
                  by * 128, bx * 128, lds);
    } else {
        int t = bid - 512;               // 0..383
        int bx = t % 12, by = t / 12;    // 12 col-tiles, 32 row-tiles
        gemm_split_body(xh, xl, wqhiT, wqloT, nullptr, qkv,
                        TRIPLE, CDIM, by * 128, bx * 128, lds);
    }
}

// ---------------------------------------------------------------------------
// Kernel 4: out projection (standalone split GEMM + bias).
// ---------------------------------------------------------------------------
__global__ __launch_bounds__(256) void outproj_kernel(const ushort* __restrict__ Ahi,
                                                      const ushort* __restrict__ Alo,
                                                      const ushort* __restrict__ BhiT,
                                                      const ushort* __restrict__ BloT,
                                                      const float* __restrict__ bias,
                                                      float* __restrict__ C) {
    __shared__ ushort lds[4*TSZ];    // 32 KB
    gemm_split_body(Ahi, Alo, BhiT, BloT, bias, C,
                    CDIM, INNER, blockIdx.y * 128, blockIdx.x * 128, lds);
}

// ---------------------------------------------------------------------------
// Kernel 5: per-row exact top-KNN via range-normalized histogram select.
// ---------------------------------------------------------------------------
__device__ __forceinline__ unsigned block_excl_scan_256(unsigned c,
                                                        unsigned* wsum,
                                                        unsigned* total_out) {
    unsigned v = c;
    #pragma unroll
    for (int o = 1; o < 64; o <<= 1) {
        unsigned t = __shfl_up(v, o);
        if ((threadIdx.x & 63) >= o) v += t;
    }
    if ((threadIdx.x & 63) == 63) wsum[threadIdx.x >> 6] = v;
    __syncthreads();
    unsigned woff = 0;
    int mywave = threadIdx.x >> 6;
    #pragma unroll
    for (int w = 0; w < 4; ++w) {
        unsigned s = wsum[w];
        if (w < mywave) woff += s;
    }
    if (total_out) *total_out = wsum[0] + wsum[1] + wsum[2] + wsum[3];
    __syncthreads();
    return v + woff - c;
}

__global__ __launch_bounds__(256) void knn_select2_kernel(const float* __restrict__ S,
                                                          int* __restrict__ idx) {
    int n = blockIdx.x, b = blockIdx.y;
    const float* row = S + ((size_t)b * NPTS + n) * NPTS;
    int* out = idx + ((size_t)b * NPTS + n) * KNN;

    __shared__ unsigned keys[NPTS];
    __shared__ unsigned hist[256];
    __shared__ unsigned wsum[4];
    __shared__ unsigned s_red[8];
    __shared__ unsigned sh_lo, sh_hi, sh_rank, sh_cnt, sh_break;
    __shared__ unsigned ckey[64];
    __shared__ int     cidx[64];
    __shared__ unsigned s_ccount;

    int tid = threadIdx.x;

    unsigned mn = 0xffffffffu, mx = 0u;
    {
        int i0 = tid * 8;
        float4 f0 = *(const float4*)(row + i0);
        float4 f1 = *(const float4*)(row + i0 + 4);
        float fv[8] = { f0.x, f0.y, f0.z, f0.w, f1.x, f1.y, f1.z, f1.w };
        #pragma unroll
        for (int t = 0; t < 8; ++t) {
            int i = i0 + t;
            unsigned u;
            if (i == n) {
                u = 0xffffffffu;
            } else {
                unsigned v = __float_as_uint(fv[t]);
                u = (v & 0x80000000u) ? ~v : (v | 0x80000000u);
                mn = min(mn, u); mx = max(mx, u);
            }
            keys[i] = u;
        }
    }
    #pragma unroll
    for (int o = 32; o; o >>= 1) {
        mn = min(mn, (unsigned)__shfl_xor((int)mn, o));
        mx = max(mx, (unsigned)__shfl_xor((int)mx, o));
    }
    if ((tid & 63) == 0) { s_red[tid >> 6] = mn; s_red[4 + (tid >> 6)] = mx; }
    __syncthreads();
    if (tid == 0) {
        unsigned a = min(min(s_red[0], s_red[1]), min(s_red[2], s_red[3]));
        unsigned z = max(max(s_red[4], s_red[5]), max(s_red[6], s_red[7]));
        sh_lo = a; sh_hi = z; sh_rank = KNN; sh_break = 0; s_ccount = 0;
    }
    __syncthreads();

    for (int it = 0; it < 5; ++it) {
        unsigned lo = sh_lo, hi = sh_hi;
        unsigned range1 = hi - lo;
        int shift = 0;
        if (range1 > 255u) shift = 24 - __clz(range1);
        hist[tid] = 0;
        __syncthreads();
        for (int i = tid; i < NPTS; i += 256) {
            unsigned u = keys[i];
            if (u >= lo && u <= hi)
                atomicAdd(&hist[(u - lo) >> shift], 1u);
        }
        __syncthreads();
        unsigned c = hist[tid];
        unsigned rank = sh_rank;
        unsigned excl = block_excl_scan_256(c, wsum, nullptr);
        if (excl < rank && excl + c >= rank) {
            sh_rank = rank - excl;
            unsigned nlo = lo + ((unsigned)tid << shift);
            unsigned span = (shift == 0) ? 0u : (((1u << shift)) - 1u);
            unsigned nhi = nlo + span;
            if (nhi > hi || nhi < nlo) nhi = hi;
            sh_lo = nlo; sh_hi = nhi;
            sh_cnt = c;
            sh_break = (shift == 0 || c <= 64u) ? 1u : 0u;
        }
        __syncthreads();
        if (sh_break) break;
    }

    unsigned lo = sh_lo, hi = sh_hi, rank = sh_rank, cnt = sh_cnt;

    unsigned lt = 0;
    for (int i = tid; i < NPTS; i += 256) lt += (keys[i] < lo) ? 1u : 0u;
    unsigned pos = block_excl_scan_256(lt, wsum, nullptr);
    for (int i = tid; i < NPTS; i += 256) {
        unsigned u = keys[i];
        if (u < lo) out[pos++] = i;
        else if (u >= lo && u <= hi && cnt <= 64u) {
            unsigned p = atomicAdd(&s_ccount, 1u);
            ckey[p] = u; cidx[p] = i;
        }
    }
    __syncthreads();

    unsigned base = KNN - rank;
    if (cnt <= 64u) {
        if (tid < (int)cnt) {
            unsigned myk = ckey[tid]; int myi = cidx[tid];
            unsigned r = 0;
            for (unsigned s = 0; s < cnt; ++s) {
                unsigned sk = ckey[s]; int si = cidx[s];
                r += (sk < myk || (sk == myk && si < myi)) ? 1u : 0u;
            }
            if (r < rank) out[base + r] = myi;
        }
    } else {
        if (tid == 0) {
            unsigned need = rank, p = base;
            for (int i = 0; i < NPTS && need; ++i) {
                if (keys[i] >= lo && keys[i] <= hi) { out[p++] = i; --need; }
            }
        }
    }
}

// ---------------------------------------------------------------------------
// Kernel 6: sparse graph attention, deep-ILP gather version.
// ---------------------------------------------------------------------------
__global__ __launch_bounds__(256) void attn_kernel(const float* __restrict__ qkv,
                                                   const int* __restrict__ idx,
                                                   ushort* __restrict__ ahi,
                                                   ushort* __restrict__ alo) {
    int n = blockIdx.x, b = blockIdx.y;
    size_t rowoff = ((size_t)b * NPTS + n);
    const float* qrow  = qkv + rowoff * TRIPLE;
    const float* kbase = qkv + (size_t)b * NPTS * TRIPLE + INNER;
    const float* vbase = qkv + (size_t)b * NPTS * TRIPLE + 2*INNER;

    __shared__ int   nb[KNN];
    __shared__ float dots[NHEAD][KNN];
    __shared__ float p[NHEAD][KNN];

    if (threadIdx.x < KNN)
        nb[threadIdx.x] = idx[rowoff * KNN + threadIdx.x];
    __syncthreads();

    {
        int j = threadIdx.x >> 3;
        int l = threadIdx.x & 7;
        const float* krow = kbase + (size_t)nb[j] * TRIPLE + l * 8;
        float4 kr0[NHEAD], kr1[NHEAD];
        #pragma unroll
        for (int h = 0; h < NHEAD; ++h) {
            kr0[h] = *(const float4*)(krow + h * DHEAD);
            kr1[h] = *(const float4*)(krow + h * DHEAD + 4);
        }
        const float* qp = qrow + l * 8;
        #pragma unroll
        for (int h = 0; h < NHEAD; ++h) {
            float4 q0 = *(const float4*)(qp + h * DHEAD);
            float4 q1 = *(const float4*)(qp + h * DHEAD + 4);
            float d = kr0[h].x*q0.x + kr0[h].y*q0.y + kr0[h].z*q0.z + kr0[h].w*q0.w
                    + kr1[h].x*q1.x + kr1[h].y*q1.y + kr1[h].z*q1.z + kr1[h].w*q1.w;
            d += __shfl_xor(d, 1);
            d += __shfl_xor(d, 2);
            d += __shfl_xor(d, 4);
            if (l == 0) dots[h][j] = d * SCALE;
        }
    }
    __syncthreads();

    {
        int h = threadIdx.x >> 5, jj = threadIdx.x & 31;
        float dv = dots[h][jj];
        float mx = dv;
        for (int o = 16; o; o >>= 1) mx = fmaxf(mx, __shfl_xor(mx, o));
        float e = expf(dv - mx);
        float s = e;
        for (int o = 16; o; o >>= 1) s += __shfl_xor(s, o);
        p[h][jj] = e / s;
    }
    __syncthreads();

    {
        int hd = threadIdx.x >> 5;
        int jd = threadIdx.x & 31;
        const float* vb = vbase + hd * DHEAD + jd * 2;
        float o0 = 0.f, o1 = 0.f;
        #pragma unroll
        for (int g = 0; g < 4; ++g) {
            float2 vv[8]; float pw[8];
            #pragma unroll
            for (int t = 0; t < 8; ++t) {
                int jj = g * 8 + t;
                vv[t] = *(const float2*)(vb + (size_t)nb[jj] * TRIPLE);
                pw[t] = p[hd][jj];
            }
            #pragma unroll
            for (int t = 0; t < 8; ++t) { o0 += pw[t] * vv[t].x; o1 += pw[t] * vv[t].y; }
        }
        size_t base = rowoff * INNER + hd * DHEAD + jd * 2;
        unsigned q0 = bfsplit(o0);
        unsigned q1 = bfsplit(o1);
        *(unsigned*)(ahi + base) = (q0 & 0xffffu) | (q1 << 16);
        *(unsigned*)(alo + base) = (q0 >> 16) | (q1 & 0xffff0000u);
    }
}

// ---------------------------------------------------------------------------
extern "C" void kernel_launch(void* const* d_in, const int* in_sizes, int n_in,
                              void* d_out, int out_size, void* d_ws, size_t ws_size,
                              hipStream_t stream) {
    const float* x    = (const float*)d_in[0];   // [2,2048,256]
    const float* Wqkv = (const float*)d_in[1];   // [256,1536]
    const float* Wout = (const float*)d_in[2];   // [512,256]
    const float* bout = (const float*)d_in[3];   // [256]
    float* out = (float*)d_out;                  // [2,2048,256]

    // workspace layout
    float* S    = (float*)d_ws;                           // 8,388,608 f32
    float* x2   = S + (size_t)BATCH * NPTS * NPTS;        // 4096 f32
    int*   idx  = (int*)(x2 + (size_t)BATCH * NPTS);      // 131072 int
    float* qkv  = (float*)(idx + (size_t)BATCH * NPTS * KNN);   // 6,291,456 f32
    ushort* xhi = (ushort*)(qkv + (size_t)BATCH * NPTS * TRIPLE);
    ushort* xlo   = xhi   + (size_t)BATCH * NPTS * CDIM;
    ushort* xqd   = xlo   + (size_t)BATCH * NPTS * CDIM;
    ushort* ahi   = xqd   + (size_t)BATCH * NPTS * CDIM;
    ushort* alo   = ahi   + (size_t)BATCH * NPTS * INNER;
    ushort* wqhiT = alo   + (size_t)BATCH * NPTS * INNER; // [1536][256]
    ushort* wqloT = wqhiT + (size_t)TRIPLE * CDIM;
    ushort* wohiT = wqloT + (size_t)TRIPLE * CDIM;        // [256][512]
    ushort* woloT = wohiT + (size_t)CDIM * INNER;

    // 1. fused rowsq + x split
    input_prep_kernel<<<(BATCH * NPTS) / 4, 256, 0, stream>>>(x, x2, xhi, xlo, xqd);

    // 2. merged weight transpose+split
    wtrans2_kernel<<<128, 256, 0, stream>>>(Wqkv, Wout, wqhiT, wqloT, wohiT, woloT);

    // 3. merged gram + qkv GEMM
    fused_mfma_kernel<<<896, 256, 0, stream>>>(xhi, xlo, xqd, x2, S,
                                               wqhiT, wqloT, qkv);

    // 4. top-32 neighbor selection
    {
        dim3 grid(NPTS, BATCH);
        knn_select2_kernel<<<grid, 256, 0, stream>>>(S, idx);
    }

    // 5. sparse attention -> pre-split hi/lo
    {
        dim3 grid(NPTS, BATCH);
        attn_kernel<<<grid, 256, 0, stream>>>(qkv, idx, ahi, alo);
    }

    // 6. output projection: [4096,512] @ [512,256] + bias
    {
        dim3 grid(CDIM / 128, (BATCH * NPTS) / 128);
        outproj_kernel<<<grid, 256, 0, stream>>>(ahi, alo, wohiT, woloT, bout, out);
    }
}

// Round 10
// 130.640 us; speedup vs baseline: 3.3543x; 1.0039x over previous
//
#include <hip/hip_runtime.h>
#include <hip/hip_bf16.h>

// Problem constants
#define BATCH 2
#define NPTS  2048
#define CDIM  256
#define NHEAD 8
#define DHEAD 64
#define INNER 512            // NHEAD*DHEAD
#define TRIPLE 1536          // 3*INNER
#define KNN   32
#define SCALE 0.125f         // 64^-0.5

typedef __attribute__((ext_vector_type(8))) short short8;      // 8 bf16 (4 VGPR)
typedef __attribute__((ext_vector_type(4))) float floatx4;     // MFMA acc
typedef __attribute__((ext_vector_type(4))) unsigned short ushort4v;
typedef unsigned short ushort;

#define TW  32               // LDS tile row width in ushort (64 B, linear)
#define TSZ (128*TW)         // ushorts per 128-row tile (8192 B)

// bf16 split: x = hi + lo (both RNE bf16). hi in [15:0], lo in [31:16].
__device__ __forceinline__ unsigned bfsplit(float x) {
    unsigned u = __float_as_uint(x);
    unsigned r = u + 0x7fffu + ((u >> 16) & 1u);
    unsigned hs = r >> 16;
    float hf = __uint_as_float(hs << 16);
    float lo = x - hf;
    unsigned u2 = __float_as_uint(lo);
    unsigned r2 = u2 + 0x7fffu + ((u2 >> 16) & 1u);
    return (hs & 0xffffu) | (r2 & 0xffff0000u);
}

// 3-component split: x = h + l + q, residual ~2^-27 relative.
__device__ __forceinline__ void bfsplit3(float x, ushort* hh, ushort* ll, ushort* qq) {
    unsigned u = __float_as_uint(x);
    unsigned r = u + 0x7fffu + ((u >> 16) & 1u);
    unsigned hs = r >> 16;
    float hf = __uint_as_float(hs << 16);
    float d1 = x - hf;
    unsigned u2 = __float_as_uint(d1);
    unsigned r2 = u2 + 0x7fffu + ((u2 >> 16) & 1u);
    unsigned ls = r2 >> 16;
    float lf = __uint_as_float(ls << 16);
    float d2 = d1 - lf;
    unsigned u3 = __float_as_uint(d2);
    unsigned r3 = u3 + 0x7fffu + ((u3 >> 16) & 1u);
    *hh = (ushort)hs;
    *ll = (ushort)ls;
    *qq = (ushort)(r3 >> 16);
}

// ---------------------------------------------------------------------------
// Kernel 1 (fused): row squared norms + fp32 -> bf16 h/l/q split of x.
// ---------------------------------------------------------------------------
__global__ __launch_bounds__(256) void input_prep_kernel(const float* __restrict__ x,
                                                         float* __restrict__ x2,
                                                         ushort* __restrict__ xhi,
                                                         ushort* __restrict__ xlo,
                                                         ushort* __restrict__ xqd) {
    int wave = threadIdx.x >> 6, lane = threadIdx.x & 63;
    int row = blockIdx.x * 4 + wave;
    const float* xr = x + (size_t)row * CDIM;
    float4 v = *(const float4*)(xr + lane * 4);
    float s = v.x*v.x + v.y*v.y + v.z*v.z + v.w*v.w;
    #pragma unroll
    for (int o = 32; o; o >>= 1) s += __shfl_down(s, o);
    if (lane == 0) x2[row] = s;

    ushort h[4], l[4], q[4];
    bfsplit3(v.x, &h[0], &l[0], &q[0]);
    bfsplit3(v.y, &h[1], &l[1], &q[1]);
    bfsplit3(v.z, &h[2], &l[2], &q[2]);
    bfsplit3(v.w, &h[3], &l[3], &q[3]);
    size_t off = (size_t)row * CDIM + lane * 4;
    *(ushort4v*)(xhi + off) = *(ushort4v*)h;
    *(ushort4v*)(xlo + off) = *(ushort4v*)l;
    *(ushort4v*)(xqd + off) = *(ushort4v*)q;
}

// ---------------------------------------------------------------------------
// Kernel 2 (merged): both weight transposes+splits in one launch.
// ---------------------------------------------------------------------------
__global__ __launch_bounds__(256) void wtrans2_kernel(const float* __restrict__ Wqkv,
                                                      const float* __restrict__ Wout,
                                                      ushort* __restrict__ wqhiT,
                                                      ushort* __restrict__ wqloT,
                                                      ushort* __restrict__ wohiT,
                                                      ushort* __restrict__ woloT) {
    __shared__ float tile[64][65];
    const float* W; ushort* hiT; ushort* loT; int K, N, bx, by;
    int bid = blockIdx.x;
    if (bid < 96) { W = Wqkv; hiT = wqhiT; loT = wqloT; K = CDIM;  N = TRIPLE; bx = bid % 24; by = bid / 24; }
    else { int t = bid - 96; W = Wout; hiT = wohiT; loT = woloT; K = INNER; N = CDIM;  bx = t % 4;  by = t / 4; }
    int k0 = by * 64, n0 = bx * 64;
    #pragma unroll
    for (int i = 0; i < 4; ++i) {
        int f = threadIdx.x + i * 256;
        int r = f >> 4, c4 = (f & 15) * 4;
        float4 v = *(const float4*)(W + (size_t)(k0 + r) * N + n0 + c4);
        tile[r][c4+0] = v.x; tile[r][c4+1] = v.y;
        tile[r][c4+2] = v.z; tile[r][c4+3] = v.w;
    }
    __syncthreads();
    #pragma unroll
    for (int i = 0; i < 4; ++i) {
        int f = threadIdx.x + i * 256;
        int rn = f >> 4, ck = (f & 15) * 4;
        unsigned p0 = bfsplit(tile[ck+0][rn]);
        unsigned p1 = bfsplit(tile[ck+1][rn]);
        unsigned p2 = bfsplit(tile[ck+2][rn]);
        unsigned p3 = bfsplit(tile[ck+3][rn]);
        ushort4v h, l;
        h.x = (ushort)p0; l.x = (ushort)(p0 >> 16);
        h.y = (ushort)p1; l.y = (ushort)(p1 >> 16);
        h.z = (ushort)p2; l.z = (ushort)(p2 >> 16);
        h.w = (ushort)p3; l.w = (ushort)(p3 >> 16);
        *(ushort4v*)(hiT + (size_t)(n0 + rn) * K + k0 + ck) = h;
        *(ushort4v*)(loT + (size_t)(n0 + rn) * K + k0 + ck) = l;
    }
}

// ---------------------------------------------------------------------------
// MFMA bodies: register-staged global->LDS (lets compiler hoist next-step
// loads over MFMA) + linear TW=32 tiles with chunk-XOR swizzle
// (LDS chunk c of row r holds K-chunk c ^ ((r>>1)&3)) -> conflict-free reads.
// ---------------------------------------------------------------------------

// GEMM body (hi/lo, 3 products hh+hl+lh): C tile = A @ B^T (+bias)
__device__ __forceinline__ void gemm_split_body(const ushort* __restrict__ Ahi,
                                                const ushort* __restrict__ Alo,
                                                const ushort* __restrict__ BhiT,
                                                const ushort* __restrict__ BloT,
                                                const float* __restrict__ bias,
                                                float* __restrict__ C,
                                                int N, int K, int bi, int bj,
                                                ushort* lds) {
    int lane = threadIdx.x & 63, wave = threadIdx.x >> 6;
    int wr = wave >> 1, wc = wave & 1;
    int fr = lane & 15, kg = lane >> 4;
    int swz8 = (kg ^ ((fr >> 1) & 3)) * 8;      // read-side chunk swizzle

    int srow = threadIdx.x >> 1;                // 0..127
    int hc = (threadIdx.x & 1) * 2;             // global chunk base: 0 or 2
    int sw = (srow >> 1) & 3;                   // row swizzle key
    int d0 = srow * TW + ((hc + 0) ^ sw) * 8;   // LDS dests (swizzled)
    int d1 = srow * TW + ((hc + 1) ^ sw) * 8;

    const ushort* g0 = Ahi  + (size_t)(bi + srow) * K + hc * 8;
    const ushort* g1 = Alo  + (size_t)(bi + srow) * K + hc * 8;
    const ushort* g2 = BhiT + (size_t)(bj + srow) * K + hc * 8;
    const ushort* g3 = BloT + (size_t)(bj + srow) * K + hc * 8;

    floatx4 acc[4][4] = {};

    for (int k0 = 0; k0 < K; k0 += 32) {
        uint4 va0 = *(const uint4*)(g0 + k0);
        uint4 va1 = *(const uint4*)(g0 + k0 + 8);
        uint4 vb0 = *(const uint4*)(g1 + k0);
        uint4 vb1 = *(const uint4*)(g1 + k0 + 8);
        uint4 vc0 = *(const uint4*)(g2 + k0);
        uint4 vc1 = *(const uint4*)(g2 + k0 + 8);
        uint4 vd0 = *(const uint4*)(g3 + k0);
        uint4 vd1 = *(const uint4*)(g3 + k0 + 8);
        *(uint4*)&lds[0*TSZ + d0] = va0;  *(uint4*)&lds[0*TSZ + d1] = va1;
        *(uint4*)&lds[1*TSZ + d0] = vb0;  *(uint4*)&lds[1*TSZ + d1] = vb1;
        *(uint4*)&lds[2*TSZ + d0] = vc0;  *(uint4*)&lds[2*TSZ + d1] = vc1;
        *(uint4*)&lds[3*TSZ + d0] = vd0;  *(uint4*)&lds[3*TSZ + d1] = vd1;
        __syncthreads();

        short8 a_h[4], a_l[4], b_h[4], b_l[4];
        #pragma unroll
        for (int m = 0; m < 4; ++m) {
            int off = (wr*64 + m*16 + fr) * TW + swz8;
            a_h[m] = *(const short8*)&lds[0*TSZ + off];
            a_l[m] = *(const short8*)&lds[1*TSZ + off];
        }
        #pragma unroll
        for (int n = 0; n < 4; ++n) {
            int off = (wc*64 + n*16 + fr) * TW + swz8;
            b_h[n] = *(const short8*)&lds[2*TSZ + off];
            b_l[n] = *(const short8*)&lds[3*TSZ + off];
        }
        #pragma unroll
        for (int m = 0; m < 4; ++m)
            #pragma unroll
            for (int n = 0; n < 4; ++n) {
                acc[m][n] = __builtin_amdgcn_mfma_f32_16x16x32_bf16(a_h[m], b_h[n], acc[m][n], 0, 0, 0);
                acc[m][n] = __builtin_amdgcn_mfma_f32_16x16x32_bf16(a_h[m], b_l[n], acc[m][n], 0, 0, 0);
                acc[m][n] = __builtin_amdgcn_mfma_f32_16x16x32_bf16(a_l[m], b_h[n], acc[m][n], 0, 0, 0);
            }
        __syncthreads();
    }

    #pragma unroll
    for (int m = 0; m < 4; ++m)
        #pragma unroll
        for (int n = 0; n < 4; ++n) {
            int col = bj + wc*64 + n*16 + fr;
            float bv = bias ? bias[col] : 0.0f;
            #pragma unroll
            for (int r = 0; r < 4; ++r) {
                int row = bi + wr*64 + m*16 + kg*4 + r;
                C[(size_t)row * N + col] = acc[m][n][r] + bv;
            }
        }
}

// Gram body: 3-split, 6 products (fp32-precision, selection-safe).
// Computes tile (bi,bj); if bi!=bj also mirror-writes the (bj,bi) tile via
// LDS transpose (dot is symmetric; MFMA sum order identical -> bit-identical).
__device__ __forceinline__ void gram_body(const ushort* __restrict__ Ah,
                                          const ushort* __restrict__ Al,
                                          const ushort* __restrict__ Aq,
                                          const float* __restrict__ x2b,
                                          float* __restrict__ Sb,
                                          int bi, int bj, ushort* lds) {
    int lane = threadIdx.x & 63, wave = threadIdx.x >> 6;
    int wr = wave >> 1, wc = wave & 1;
    int fr = lane & 15, kg = lane >> 4;
    int swz8 = (kg ^ ((fr >> 1) & 3)) * 8;

    int srow = threadIdx.x >> 1;
    int hc = (threadIdx.x & 1) * 2;
    int sw = (srow >> 1) & 3;
    int d0 = srow * TW + ((hc + 0) ^ sw) * 8;
    int d1 = srow * TW + ((hc + 1) ^ sw) * 8;

    const ushort* g0 = Ah + (size_t)(bi + srow) * CDIM + hc * 8;
    const ushort* g1 = Al + (size_t)(bi + srow) * CDIM + hc * 8;
    const ushort* g2 = Aq + (size_t)(bi + srow) * CDIM + hc * 8;
    const ushort* g3 = Ah + (size_t)(bj + srow) * CDIM + hc * 8;
    const ushort* g4 = Al + (size_t)(bj + srow) * CDIM + hc * 8;
    const ushort* g5 = Aq + (size_t)(bj + srow) * CDIM + hc * 8;

    floatx4 acc[4][4] = {};

    for (int k0 = 0; k0 < CDIM; k0 += 32) {
        uint4 a0 = *(const uint4*)(g0 + k0); uint4 a1 = *(const uint4*)(g0 + k0 + 8);
        uint4 b0 = *(const uint4*)(g1 + k0); uint4 b1 = *(const uint4*)(g1 + k0 + 8);
        uint4 c0 = *(const uint4*)(g2 + k0); uint4 c1 = *(const uint4*)(g2 + k0 + 8);
        uint4 e0 = *(const uint4*)(g3 + k0); uint4 e1 = *(const uint4*)(g3 + k0 + 8);
        uint4 f0 = *(const uint4*)(g4 + k0); uint4 f1 = *(const uint4*)(g4 + k0 + 8);
        uint4 h0 = *(const uint4*)(g5 + k0); uint4 h1 = *(const uint4*)(g5 + k0 + 8);
        *(uint4*)&lds[0*TSZ + d0] = a0; *(uint4*)&lds[0*TSZ + d1] = a1;
        *(uint4*)&lds[1*TSZ + d0] = b0; *(uint4*)&lds[1*TSZ + d1] = b1;
        *(uint4*)&lds[2*TSZ + d0] = c0; *(uint4*)&lds[2*TSZ + d1] = c1;
        *(uint4*)&lds[3*TSZ + d0] = e0; *(uint4*)&lds[3*TSZ + d1] = e1;
        *(uint4*)&lds[4*TSZ + d0] = f0; *(uint4*)&lds[4*TSZ + d1] = f1;
        *(uint4*)&lds[5*TSZ + d0] = h0; *(uint4*)&lds[5*TSZ + d1] = h1;
        __syncthreads();

        short8 a_h[4], a_l[4], a_q[4], b_h[4], b_l[4], b_q[4];
        #pragma unroll
        for (int m = 0; m < 4; ++m) {
            int off = (wr*64 + m*16 + fr) * TW + swz8;
            a_h[m] = *(const short8*)&lds[0*TSZ + off];
            a_l[m] = *(const short8*)&lds[1*TSZ + off];
            a_q[m] = *(const short8*)&lds[2*TSZ + off];
        }
        #pragma unroll
        for (int n = 0; n < 4; ++n) {
            int off = (wc*64 + n*16 + fr) * TW + swz8;
            b_h[n] = *(const short8*)&lds[3*TSZ + off];
            b_l[n] = *(const short8*)&lds[4*TSZ + off];
            b_q[n] = *(const short8*)&lds[5*TSZ + off];
        }
        #pragma unroll
        for (int m = 0; m < 4; ++m)
            #pragma unroll
            for (int n = 0; n < 4; ++n) {
                acc[m][n] = __builtin_amdgcn_mfma_f32_16x16x32_bf16(a_h[m], b_h[n], acc[m][n], 0, 0, 0);
                acc[m][n] = __builtin_amdgcn_mfma_f32_16x16x32_bf16(a_h[m], b_l[n], acc[m][n], 0, 0, 0);
                acc[m][n] = __builtin_amdgcn_mfma_f32_16x16x32_bf16(a_l[m], b_h[n], acc[m][n], 0, 0, 0);
                acc[m][n] = __builtin_amdgcn_mfma_f32_16x16x32_bf16(a_l[m], b_l[n], acc[m][n], 0, 0, 0);
                acc[m][n] = __builtin_amdgcn_mfma_f32_16x16x32_bf16(a_h[m], b_q[n], acc[m][n], 0, 0, 0);
                acc[m][n] = __builtin_amdgcn_mfma_f32_16x16x32_bf16(a_q[m], b_h[n], acc[m][n], 0, 0, 0);
            }
        __syncthreads();
    }

    // normal write: S[bi+row][bj+col] = x2[col] - 2 acc (diag -> inf)
    #pragma unroll
    for (int m = 0; m < 4; ++m)
        #pragma unroll
        for (int n = 0; n < 4; ++n) {
            int col = bj + wc*64 + n*16 + fr;
            float xc = x2b[col];
            #pragma unroll
            for (int r = 0; r < 4; ++r) {
                int row = bi + wr*64 + m*16 + kg*4 + r;
                float val = xc - 2.0f * acc[m][n][r];
                if (row == col) val = __builtin_inff();
                Sb[(size_t)row * NPTS + col] = val;
            }
        }

    // mirror write: S[bj+col][bi+row] = x2[row] - 2 acc, via LDS transpose
    if (bi != bj) {
        float* T = (float*)lds;                 // 64 x 128, stride 132 floats
        #pragma unroll
        for (int p = 0; p < 2; ++p) {
            __syncthreads();
            if (wc == p) {
                #pragma unroll
                for (int m = 0; m < 4; ++m) {
                    int row0 = wr*64 + m*16 + kg*4;
                    float x0 = x2b[bi + row0 + 0];
                    float x1 = x2b[bi + row0 + 1];
                    float x2v = x2b[bi + row0 + 2];
                    float x3 = x2b[bi + row0 + 3];
                    #pragma unroll
                    for (int n = 0; n < 4; ++n) {
                        int colp = n*16 + fr;   // 0..63 within pass
                        float4 v;
                        v.x = x0 - 2.0f * acc[m][n][0];
                        v.y = x1 - 2.0f * acc[m][n][1];
                        v.z = x2v - 2.0f * acc[m][n][2];
                        v.w = x3 - 2.0f * acc[m][n][3];
                        *(float4*)&T[colp * 132 + row0] = v;
                    }
                }
            }
            __syncthreads();
            #pragma unroll
            for (int i = 0; i < 8; ++i) {
                int f = threadIdx.x + i * 256;  // 0..2047
                int cr = f >> 5, c4 = (f & 31) * 4;
                float4 v = *(const float4*)&T[cr * 132 + c4];
                *(float4*)(Sb + (size_t)(bj + p*64 + cr) * NPTS + bi + c4) = v;
            }
        }
    }
}

// ---------------------------------------------------------------------------
// Kernel 3 (merged): gram upper-tri tiles (blocks 0..271) + qkv GEMM (272..655).
// ---------------------------------------------------------------------------
__global__ __launch_bounds__(256) void fused_mfma_kernel(const ushort* __restrict__ xh,
                                                         const ushort* __restrict__ xl,
                                                         const ushort* __restrict__ xq,
                                                         const float* __restrict__ x2,
                                                         float* __restrict__ S,
                                                         const ushort* __restrict__ wqhiT,
                                                         const ushort* __restrict__ wqloT,
                                                         float* __restrict__ qkv) {
    __shared__ ushort lds[6*TSZ];    // 48 KB
    int bid = blockIdx.x;
    if (bid < 272) {
        int b = bid / 136, t = bid % 136;
        int by = 0;
        while (t >= 16 - by) { t -= 16 - by; ++by; }
        int bx = by + t;                 // by <= bx (upper triangle)
        size_t xoff = (size_t)b * NPTS * CDIM;
        gram_body(xh + xoff, xl + xoff, xq + xoff,
                  x2 + (size_t)b * NPTS, S + (size_t)b * NPTS * NPTS,
                  by * 128, bx * 128, lds);
    } else {
        int t = bid - 272;               // 0..383
        int bx = t % 12, by = t / 12;    // 12 col-tiles, 32 row-tiles
        gemm_split_body(xh, xl, wqhiT, wqloT, nullptr, qkv,
                        TRIPLE, CDIM, by * 128, bx * 128, lds);
    }
}

// ---------------------------------------------------------------------------
// Kernel 4: out projection (standalone split GEMM + bias).
// ---------------------------------------------------------------------------
__global__ __launch_bounds__(256) void outproj_kernel(const ushort* __restrict__ Ahi,
                                                      const ushort* __restrict__ Alo,
                                                      const ushort* __restrict__ BhiT,
                                                      const ushort* __restrict__ BloT,
                                                      const float* __restrict__ bias,
                                                      float* __restrict__ C) {
    __shared__ ushort lds[4*TSZ];    // 32 KB
    gemm_split_body(Ahi, Alo, BhiT, BloT, bias, C,
                    CDIM, INNER, blockIdx.y * 128, blockIdx.x * 128, lds);
}

// ---------------------------------------------------------------------------
// Kernel 5: per-row exact top-KNN via range-normalized histogram select.
// ---------------------------------------------------------------------------
__device__ __forceinline__ unsigned block_excl_scan_256(unsigned c,
                                                        unsigned* wsum,
                                                        unsigned* total_out) {
    unsigned v = c;
    #pragma unroll
    for (int o = 1; o < 64; o <<= 1) {
        unsigned t = __shfl_up(v, o);
        if ((threadIdx.x & 63) >= o) v += t;
    }
    if ((threadIdx.x & 63) == 63) wsum[threadIdx.x >> 6] = v;
    __syncthreads();
    unsigned woff = 0;
    int mywave = threadIdx.x >> 6;
    #pragma unroll
    for (int w = 0; w < 4; ++w) {
        unsigned s = wsum[w];
        if (w < mywave) woff += s;
    }
    if (total_out) *total_out = wsum[0] + wsum[1] + wsum[2] + wsum[3];
    __syncthreads();
    return v + woff - c;
}

__global__ __launch_bounds__(256) void knn_select2_kernel(const float* __restrict__ S,
                                                          int* __restrict__ idx) {
    int n = blockIdx.x, b = blockIdx.y;
    const float* row = S + ((size_t)b * NPTS + n) * NPTS;
    int* out = idx + ((size_t)b * NPTS + n) * KNN;

    __shared__ unsigned keys[NPTS];
    __shared__ unsigned hist[256];
    __shared__ unsigned wsum[4];
    __shared__ unsigned s_red[8];
    __shared__ unsigned sh_lo, sh_hi, sh_rank, sh_cnt, sh_break;
    __shared__ unsigned ckey[64];
    __shared__ int     cidx[64];
    __shared__ unsigned s_ccount;

    int tid = threadIdx.x;

    unsigned mn = 0xffffffffu, mx = 0u;
    {
        int i0 = tid * 8;
        float4 f0 = *(const float4*)(row + i0);
        float4 f1 = *(const float4*)(row + i0 + 4);
        float fv[8] = { f0.x, f0.y, f0.z, f0.w, f1.x, f1.y, f1.z, f1.w };
        #pragma unroll
        for (int t = 0; t < 8; ++t) {
            int i = i0 + t;
            unsigned u;
            if (i == n) {
                u = 0xffffffffu;
            } else {
                unsigned v = __float_as_uint(fv[t]);
                u = (v & 0x80000000u) ? ~v : (v | 0x80000000u);
                mn = min(mn, u); mx = max(mx, u);
            }
            keys[i] = u;
        }
    }
    #pragma unroll
    for (int o = 32; o; o >>= 1) {
        mn = min(mn, (unsigned)__shfl_xor((int)mn, o));
        mx = max(mx, (unsigned)__shfl_xor((int)mx, o));
    }
    if ((tid & 63) == 0) { s_red[tid >> 6] = mn; s_red[4 + (tid >> 6)] = mx; }
    __syncthreads();
    if (tid == 0) {
        unsigned a = min(min(s_red[0], s_red[1]), min(s_red[2], s_red[3]));
        unsigned z = max(max(s_red[4], s_red[5]), max(s_red[6], s_red[7]));
        sh_lo = a; sh_hi = z; sh_rank = KNN; sh_break = 0; s_ccount = 0;
    }
    __syncthreads();

    for (int it = 0; it < 5; ++it) {
        unsigned lo = sh_lo, hi = sh_hi;
        unsigned range1 = hi - lo;
        int shift = 0;
        if (range1 > 255u) shift = 24 - __clz(range1);
        hist[tid] = 0;
        __syncthreads();
        for (int i = tid; i < NPTS; i += 256) {
            unsigned u = keys[i];
            if (u >= lo && u <= hi)
                atomicAdd(&hist[(u - lo) >> shift], 1u);
        }
        __syncthreads();
        unsigned c = hist[tid];
        unsigned rank = sh_rank;
        unsigned excl = block_excl_scan_256(c, wsum, nullptr);
        if (excl < rank && excl + c >= rank) {
            sh_rank = rank - excl;
            unsigned nlo = lo + ((unsigned)tid << shift);
            unsigned span = (shift == 0) ? 0u : (((1u << shift)) - 1u);
            unsigned nhi = nlo + span;
            if (nhi > hi || nhi < nlo) nhi = hi;
            sh_lo = nlo; sh_hi = nhi;
            sh_cnt = c;
            sh_break = (shift == 0 || c <= 64u) ? 1u : 0u;
        }
        __syncthreads();
        if (sh_break) break;
    }

    unsigned lo = sh_lo, hi = sh_hi, rank = sh_rank, cnt = sh_cnt;

    unsigned lt = 0;
    for (int i = tid; i < NPTS; i += 256) lt += (keys[i] < lo) ? 1u : 0u;
    unsigned pos = block_excl_scan_256(lt, wsum, nullptr);
    for (int i = tid; i < NPTS; i += 256) {
        unsigned u = keys[i];
        if (u < lo) out[pos++] = i;
        else if (u >= lo && u <= hi && cnt <= 64u) {
            unsigned p = atomicAdd(&s_ccount, 1u);
            ckey[p] = u; cidx[p] = i;
        }
    }
    __syncthreads();

    unsigned base = KNN - rank;
    if (cnt <= 64u) {
        if (tid < (int)cnt) {
            unsigned myk = ckey[tid]; int myi = cidx[tid];
            unsigned r = 0;
            for (unsigned s = 0; s < cnt; ++s) {
                unsigned sk = ckey[s]; int si = cidx[s];
                r += (sk < myk || (sk == myk && si < myi)) ? 1u : 0u;
            }
            if (r < rank) out[base + r] = myi;
        }
    } else {
        if (tid == 0) {
            unsigned need = rank, p = base;
            for (int i = 0; i < NPTS && need; ++i) {
                if (keys[i] >= lo && keys[i] <= hi) { out[p++] = i; --need; }
            }
        }
    }
}

// ---------------------------------------------------------------------------
// Kernel 6: sparse graph attention, deep-ILP gather version.
// ---------------------------------------------------------------------------
__global__ __launch_bounds__(256) void attn_kernel(const float* __restrict__ qkv,
                                                   const int* __restrict__ idx,
                                                   ushort* __restrict__ ahi,
                                                   ushort* __restrict__ alo) {
    int n = blockIdx.x, b = blockIdx.y;
    size_t rowoff = ((size_t)b * NPTS + n);
    const float* qrow  = qkv + rowoff * TRIPLE;
    const float* kbase = qkv + (size_t)b * NPTS * TRIPLE + INNER;
    const float* vbase = qkv + (size_t)b * NPTS * TRIPLE + 2*INNER;

    __shared__ int   nb[KNN];
    __shared__ float dots[NHEAD][KNN];
    __shared__ float p[NHEAD][KNN];

    if (threadIdx.x < KNN)
        nb[threadIdx.x] = idx[rowoff * KNN + threadIdx.x];
    __syncthreads();

    {
        int j = threadIdx.x >> 3;
        int l = threadIdx.x & 7;
        const float* krow = kbase + (size_t)nb[j] * TRIPLE + l * 8;
        float4 kr0[NHEAD], kr1[NHEAD];
        #pragma unroll
        for (int h = 0; h < NHEAD; ++h) {
            kr0[h] = *(const float4*)(krow + h * DHEAD);
            kr1[h] = *(const float4*)(krow + h * DHEAD + 4);
        }
        const float* qp = qrow + l * 8;
        #pragma unroll
        for (int h = 0; h < NHEAD; ++h) {
            float4 q0 = *(const float4*)(qp + h * DHEAD);
            float4 q1 = *(const float4*)(qp + h * DHEAD + 4);
            float d = kr0[h].x*q0.x + kr0[h].y*q0.y + kr0[h].z*q0.z + kr0[h].w*q0.w
                    + kr1[h].x*q1.x + kr1[h].y*q1.y + kr1[h].z*q1.z + kr1[h].w*q1.w;
            d += __shfl_xor(d, 1);
            d += __shfl_xor(d, 2);
            d += __shfl_xor(d, 4);
            if (l == 0) dots[h][j] = d * SCALE;
        }
    }
    __syncthreads();

    {
        int h = threadIdx.x >> 5, jj = threadIdx.x & 31;
        float dv = dots[h][jj];
        float mx = dv;
        for (int o = 16; o; o >>= 1) mx = fmaxf(mx, __shfl_xor(mx, o));
        float e = expf(dv - mx);
        float s = e;
        for (int o = 16; o; o >>= 1) s += __shfl_xor(s, o);
        p[h][jj] = e / s;
    }
    __syncthreads();

    {
        int hd = threadIdx.x >> 5;
        int jd = threadIdx.x & 31;
        const float* vb = vbase + hd * DHEAD + jd * 2;
        float o0 = 0.f, o1 = 0.f;
        #pragma unroll
        for (int g = 0; g < 4; ++g) {
            float2 vv[8]; float pw[8];
            #pragma unroll
            for (int t = 0; t < 8; ++t) {
                int jj = g * 8 + t;
                vv[t] = *(const float2*)(vb + (size_t)nb[jj] * TRIPLE);
                pw[t] = p[hd][jj];
            }
            #pragma unroll
            for (int t = 0; t < 8; ++t) { o0 += pw[t] * vv[t].x; o1 += pw[t] * vv[t].y; }
        }
        size_t base = rowoff * INNER + hd * DHEAD + jd * 2;
        unsigned q0 = bfsplit(o0);
        unsigned q1 = bfsplit(o1);
        *(unsigned*)(ahi + base) = (q0 & 0xffffu) | (q1 << 16);
        *(unsigned*)(alo + base) = (q0 >> 16) | (q1 & 0xffff0000u);
    }
}

// ---------------------------------------------------------------------------
extern "C" void kernel_launch(void* const* d_in, const int* in_sizes, int n_in,
                              void* d_out, int out_size, void* d_ws, size_t ws_size,
                              hipStream_t stream) {
    const float* x    = (const float*)d_in[0];   // [2,2048,256]
    const float* Wqkv = (const float*)d_in[1];   // [256,1536]
    const float* Wout = (const float*)d_in[2];   // [512,256]
    const float* bout = (const float*)d_in[3];   // [256]
    float* out = (float*)d_out;                  // [2,2048,256]

    // workspace layout
    float* S    = (float*)d_ws;                           // 8,388,608 f32
    float* x2   = S + (size_t)BATCH * NPTS * NPTS;        // 4096 f32
    int*   idx  = (int*)(x2 + (size_t)BATCH * NPTS);      // 131072 int
    float* qkv  = (float*)(idx + (size_t)BATCH * NPTS * KNN);   // 6,291,456 f32
    ushort* xhi = (ushort*)(qkv + (size_t)BATCH * NPTS * TRIPLE);
    ushort* xlo   = xhi   + (size_t)BATCH * NPTS * CDIM;
    ushort* xqd   = xlo   + (size_t)BATCH * NPTS * CDIM;
    ushort* ahi   = xqd   + (size_t)BATCH * NPTS * CDIM;
    ushort* alo   = ahi   + (size_t)BATCH * NPTS * INNER;
    ushort* wqhiT = alo   + (size_t)BATCH * NPTS * INNER; // [1536][256]
    ushort* wqloT = wqhiT + (size_t)TRIPLE * CDIM;
    ushort* wohiT = wqloT + (size_t)TRIPLE * CDIM;        // [256][512]
    ushort* woloT = wohiT + (size_t)CDIM * INNER;

    // 1. fused rowsq + x split
    input_prep_kernel<<<(BATCH * NPTS) / 4, 256, 0, stream>>>(x, x2, xhi, xlo, xqd);

    // 2. merged weight transpose+split
    wtrans2_kernel<<<128, 256, 0, stream>>>(Wqkv, Wout, wqhiT, wqloT, wohiT, woloT);

    // 3. merged gram (upper-tri + mirror) + qkv GEMM
    fused_mfma_kernel<<<656, 256, 0, stream>>>(xhi, xlo, xqd, x2, S,
                                               wqhiT, wqloT, qkv);

    // 4. top-32 neighbor selection
    {
        dim3 grid(NPTS, BATCH);
        knn_select2_kernel<<<grid, 256, 0, stream>>>(S, idx);
    }

    // 5. sparse attention -> pre-split hi/lo
    {
        dim3 grid(NPTS, BATCH);
        attn_kernel<<<grid, 256, 0, stream>>>(qkv, idx, ahi, alo);
    }

    // 6. output projection: [4096,512] @ [512,256] + bias
    {
        dim3 grid(CDIM / 128, (BATCH * NPTS) / 128);
        outproj_kernel<<<grid, 256, 0, stream>>>(ahi, alo, wohiT, woloT, bout, out);
    }
}

// Round 11
// 109.023 us; speedup vs baseline: 4.0194x; 1.1983x over previous
//
#include <hip/hip_runtime.h>
#include <hip/hip_bf16.h>
#include <hip/hip_fp16.h>

// Problem constants
#define BATCH 2
#define NPTS  2048
#define CDIM  256
#define NHEAD 8
#define DHEAD 64
#define INNER 512            // NHEAD*DHEAD
#define TRIPLE 1536          // 3*INNER
#define KNN   32
#define SCALE 0.125f         // 64^-0.5

typedef __attribute__((ext_vector_type(8))) short short8;      // 8 bf16 (4 VGPR)
typedef __attribute__((ext_vector_type(4))) float floatx4;     // MFMA acc
typedef __attribute__((ext_vector_type(4))) unsigned short ushort4v;
typedef unsigned short ushort;

#define TW  32               // LDS tile row width in ushort (64 B, linear)
#define TSZ (128*TW)         // ushorts per 128-row tile (8192 B)

// bf16 split: x = hi + lo (both RNE bf16). hi in [15:0], lo in [31:16].
__device__ __forceinline__ unsigned bfsplit(float x) {
    unsigned u = __float_as_uint(x);
    unsigned r = u + 0x7fffu + ((u >> 16) & 1u);
    unsigned hs = r >> 16;
    float hf = __uint_as_float(hs << 16);
    float lo = x - hf;
    unsigned u2 = __float_as_uint(lo);
    unsigned r2 = u2 + 0x7fffu + ((u2 >> 16) & 1u);
    return (hs & 0xffffu) | (r2 & 0xffff0000u);
}

// 3-component split: x = h + l + q, residual ~2^-27 relative.
__device__ __forceinline__ void bfsplit3(float x, ushort* hh, ushort* ll, ushort* qq) {
    unsigned u = __float_as_uint(x);
    unsigned r = u + 0x7fffu + ((u >> 16) & 1u);
    unsigned hs = r >> 16;
    float hf = __uint_as_float(hs << 16);
    float d1 = x - hf;
    unsigned u2 = __float_as_uint(d1);
    unsigned r2 = u2 + 0x7fffu + ((u2 >> 16) & 1u);
    unsigned ls = r2 >> 16;
    float lf = __uint_as_float(ls << 16);
    float d2 = d1 - lf;
    unsigned u3 = __float_as_uint(d2);
    unsigned r3 = u3 + 0x7fffu + ((u3 >> 16) & 1u);
    *hh = (ushort)hs;
    *ll = (ushort)ls;
    *qq = (ushort)(r3 >> 16);
}

// fp16 bit helpers
__device__ __forceinline__ ushort f2h(float f) {
    __half h = __float2half(f);               // RNE
    return *reinterpret_cast<ushort*>(&h);
}
__device__ __forceinline__ float h2f(ushort u) {
    __half h;
    *reinterpret_cast<ushort*>(&h) = u;
    return __half2float(h);
}

// ---------------------------------------------------------------------------
// Kernel 1 (fused): row squared norms + fp32 -> bf16 h/l/q split of x.
// ---------------------------------------------------------------------------
__global__ __launch_bounds__(256) void input_prep_kernel(const float* __restrict__ x,
                                                         float* __restrict__ x2,
                                                         ushort* __restrict__ xhi,
                                                         ushort* __restrict__ xlo,
                                                         ushort* __restrict__ xqd) {
    int wave = threadIdx.x >> 6, lane = threadIdx.x & 63;
    int row = blockIdx.x * 4 + wave;
    const float* xr = x + (size_t)row * CDIM;
    float4 v = *(const float4*)(xr + lane * 4);
    float s = v.x*v.x + v.y*v.y + v.z*v.z + v.w*v.w;
    #pragma unroll
    for (int o = 32; o; o >>= 1) s += __shfl_down(s, o);
    if (lane == 0) x2[row] = s;

    ushort h[4], l[4], q[4];
    bfsplit3(v.x, &h[0], &l[0], &q[0]);
    bfsplit3(v.y, &h[1], &l[1], &q[1]);
    bfsplit3(v.z, &h[2], &l[2], &q[2]);
    bfsplit3(v.w, &h[3], &l[3], &q[3]);
    size_t off = (size_t)row * CDIM + lane * 4;
    *(ushort4v*)(xhi + off) = *(ushort4v*)h;
    *(ushort4v*)(xlo + off) = *(ushort4v*)l;
    *(ushort4v*)(xqd + off) = *(ushort4v*)q;
}

// ---------------------------------------------------------------------------
// Kernel 2 (merged): both weight transposes+splits in one launch.
// ---------------------------------------------------------------------------
__global__ __launch_bounds__(256) void wtrans2_kernel(const float* __restrict__ Wqkv,
                                                      const float* __restrict__ Wout,
                                                      ushort* __restrict__ wqhiT,
                                                      ushort* __restrict__ wqloT,
                                                      ushort* __restrict__ wohiT,
                                                      ushort* __restrict__ woloT) {
    __shared__ float tile[64][65];
    const float* W; ushort* hiT; ushort* loT; int K, N, bx, by;
    int bid = blockIdx.x;
    if (bid < 96) { W = Wqkv; hiT = wqhiT; loT = wqloT; K = CDIM;  N = TRIPLE; bx = bid % 24; by = bid / 24; }
    else { int t = bid - 96; W = Wout; hiT = wohiT; loT = woloT; K = INNER; N = CDIM;  bx = t % 4;  by = t / 4; }
    int k0 = by * 64, n0 = bx * 64;
    #pragma unroll
    for (int i = 0; i < 4; ++i) {
        int f = threadIdx.x + i * 256;
        int r = f >> 4, c4 = (f & 15) * 4;
        float4 v = *(const float4*)(W + (size_t)(k0 + r) * N + n0 + c4);
        tile[r][c4+0] = v.x; tile[r][c4+1] = v.y;
        tile[r][c4+2] = v.z; tile[r][c4+3] = v.w;
    }
    __syncthreads();
    #pragma unroll
    for (int i = 0; i < 4; ++i) {
        int f = threadIdx.x + i * 256;
        int rn = f >> 4, ck = (f & 15) * 4;
        unsigned p0 = bfsplit(tile[ck+0][rn]);
        unsigned p1 = bfsplit(tile[ck+1][rn]);
        unsigned p2 = bfsplit(tile[ck+2][rn]);
        unsigned p3 = bfsplit(tile[ck+3][rn]);
        ushort4v h, l;
        h.x = (ushort)p0; l.x = (ushort)(p0 >> 16);
        h.y = (ushort)p1; l.y = (ushort)(p1 >> 16);
        h.z = (ushort)p2; l.z = (ushort)(p2 >> 16);
        h.w = (ushort)p3; l.w = (ushort)(p3 >> 16);
        *(ushort4v*)(hiT + (size_t)(n0 + rn) * K + k0 + ck) = h;
        *(ushort4v*)(loT + (size_t)(n0 + rn) * K + k0 + ck) = l;
    }
}

// ---------------------------------------------------------------------------
// MFMA bodies: register-staged global->LDS + linear TW=32 tiles with
// chunk-XOR swizzle -> conflict-free reads, compiler hoists prefetch.
// ---------------------------------------------------------------------------

// GEMM body (hi/lo, 3 products hh+hl+lh): C tile = A @ B^T (+bias).
// If kv16 != nullptr, also emits fp16 copy of cols >= 512 (K,V compact).
__device__ __forceinline__ void gemm_split_body(const ushort* __restrict__ Ahi,
                                                const ushort* __restrict__ Alo,
                                                const ushort* __restrict__ BhiT,
                                                const ushort* __restrict__ BloT,
                                                const float* __restrict__ bias,
                                                float* __restrict__ C,
                                                int N, int K, int bi, int bj,
                                                ushort* lds,
                                                ushort* __restrict__ kv16) {
    int lane = threadIdx.x & 63, wave = threadIdx.x >> 6;
    int wr = wave >> 1, wc = wave & 1;
    int fr = lane & 15, kg = lane >> 4;
    int swz8 = (kg ^ ((fr >> 1) & 3)) * 8;      // read-side chunk swizzle

    int srow = threadIdx.x >> 1;                // 0..127
    int hc = (threadIdx.x & 1) * 2;             // global chunk base: 0 or 2
    int sw = (srow >> 1) & 3;                   // row swizzle key
    int d0 = srow * TW + ((hc + 0) ^ sw) * 8;   // LDS dests (swizzled)
    int d1 = srow * TW + ((hc + 1) ^ sw) * 8;

    const ushort* g0 = Ahi  + (size_t)(bi + srow) * K + hc * 8;
    const ushort* g1 = Alo  + (size_t)(bi + srow) * K + hc * 8;
    const ushort* g2 = BhiT + (size_t)(bj + srow) * K + hc * 8;
    const ushort* g3 = BloT + (size_t)(bj + srow) * K + hc * 8;

    floatx4 acc[4][4] = {};

    for (int k0 = 0; k0 < K; k0 += 32) {
        uint4 va0 = *(const uint4*)(g0 + k0);
        uint4 va1 = *(const uint4*)(g0 + k0 + 8);
        uint4 vb0 = *(const uint4*)(g1 + k0);
        uint4 vb1 = *(const uint4*)(g1 + k0 + 8);
        uint4 vc0 = *(const uint4*)(g2 + k0);
        uint4 vc1 = *(const uint4*)(g2 + k0 + 8);
        uint4 vd0 = *(const uint4*)(g3 + k0);
        uint4 vd1 = *(const uint4*)(g3 + k0 + 8);
        *(uint4*)&lds[0*TSZ + d0] = va0;  *(uint4*)&lds[0*TSZ + d1] = va1;
        *(uint4*)&lds[1*TSZ + d0] = vb0;  *(uint4*)&lds[1*TSZ + d1] = vb1;
        *(uint4*)&lds[2*TSZ + d0] = vc0;  *(uint4*)&lds[2*TSZ + d1] = vc1;
        *(uint4*)&lds[3*TSZ + d0] = vd0;  *(uint4*)&lds[3*TSZ + d1] = vd1;
        __syncthreads();

        short8 a_h[4], a_l[4], b_h[4], b_l[4];
        #pragma unroll
        for (int m = 0; m < 4; ++m) {
            int off = (wr*64 + m*16 + fr) * TW + swz8;
            a_h[m] = *(const short8*)&lds[0*TSZ + off];
            a_l[m] = *(const short8*)&lds[1*TSZ + off];
        }
        #pragma unroll
        for (int n = 0; n < 4; ++n) {
            int off = (wc*64 + n*16 + fr) * TW + swz8;
            b_h[n] = *(const short8*)&lds[2*TSZ + off];
            b_l[n] = *(const short8*)&lds[3*TSZ + off];
        }
        #pragma unroll
        for (int m = 0; m < 4; ++m)
            #pragma unroll
            for (int n = 0; n < 4; ++n) {
                acc[m][n] = __builtin_amdgcn_mfma_f32_16x16x32_bf16(a_h[m], b_h[n], acc[m][n], 0, 0, 0);
                acc[m][n] = __builtin_amdgcn_mfma_f32_16x16x32_bf16(a_h[m], b_l[n], acc[m][n], 0, 0, 0);
                acc[m][n] = __builtin_amdgcn_mfma_f32_16x16x32_bf16(a_l[m], b_h[n], acc[m][n], 0, 0, 0);
            }
        __syncthreads();
    }

    #pragma unroll
    for (int m = 0; m < 4; ++m)
        #pragma unroll
        for (int n = 0; n < 4; ++n) {
            int col = bj + wc*64 + n*16 + fr;
            float bv = bias ? bias[col] : 0.0f;
            #pragma unroll
            for (int r = 0; r < 4; ++r) {
                int row = bi + wr*64 + m*16 + kg*4 + r;
                float val = acc[m][n][r] + bv;
                C[(size_t)row * N + col] = val;
                if (kv16 && col >= INNER)
                    kv16[(size_t)row * 1024 + (col - INNER)] = f2h(val);
            }
        }
}

// Gram body: 3-split, 6 products (fp32-precision, selection-safe).
// Computes tile (bi,bj); if bi!=bj also mirror-writes (bj,bi) via LDS
// transpose (dot symmetric; MFMA sum order identical -> bit-identical).
__device__ __forceinline__ void gram_body(const ushort* __restrict__ Ah,
                                          const ushort* __restrict__ Al,
                                          const ushort* __restrict__ Aq,
                                          const float* __restrict__ x2b,
                                          float* __restrict__ Sb,
                                          int bi, int bj, ushort* lds) {
    int lane = threadIdx.x & 63, wave = threadIdx.x >> 6;
    int wr = wave >> 1, wc = wave & 1;
    int fr = lane & 15, kg = lane >> 4;
    int swz8 = (kg ^ ((fr >> 1) & 3)) * 8;

    int srow = threadIdx.x >> 1;
    int hc = (threadIdx.x & 1) * 2;
    int sw = (srow >> 1) & 3;
    int d0 = srow * TW + ((hc + 0) ^ sw) * 8;
    int d1 = srow * TW + ((hc + 1) ^ sw) * 8;

    const ushort* g0 = Ah + (size_t)(bi + srow) * CDIM + hc * 8;
    const ushort* g1 = Al + (size_t)(bi + srow) * CDIM + hc * 8;
    const ushort* g2 = Aq + (size_t)(bi + srow) * CDIM + hc * 8;
    const ushort* g3 = Ah + (size_t)(bj + srow) * CDIM + hc * 8;
    const ushort* g4 = Al + (size_t)(bj + srow) * CDIM + hc * 8;
    const ushort* g5 = Aq + (size_t)(bj + srow) * CDIM + hc * 8;

    floatx4 acc[4][4] = {};

    for (int k0 = 0; k0 < CDIM; k0 += 32) {
        uint4 a0 = *(const uint4*)(g0 + k0); uint4 a1 = *(const uint4*)(g0 + k0 + 8);
        uint4 b0 = *(const uint4*)(g1 + k0); uint4 b1 = *(const uint4*)(g1 + k0 + 8);
        uint4 c0 = *(const uint4*)(g2 + k0); uint4 c1 = *(const uint4*)(g2 + k0 + 8);
        uint4 e0 = *(const uint4*)(g3 + k0); uint4 e1 = *(const uint4*)(g3 + k0 + 8);
        uint4 f0 = *(const uint4*)(g4 + k0); uint4 f1 = *(const uint4*)(g4 + k0 + 8);
        uint4 h0 = *(const uint4*)(g5 + k0); uint4 h1 = *(const uint4*)(g5 + k0 + 8);
        *(uint4*)&lds[0*TSZ + d0] = a0; *(uint4*)&lds[0*TSZ + d1] = a1;
        *(uint4*)&lds[1*TSZ + d0] = b0; *(uint4*)&lds[1*TSZ + d1] = b1;
        *(uint4*)&lds[2*TSZ + d0] = c0; *(uint4*)&lds[2*TSZ + d1] = c1;
        *(uint4*)&lds[3*TSZ + d0] = e0; *(uint4*)&lds[3*TSZ + d1] = e1;
        *(uint4*)&lds[4*TSZ + d0] = f0; *(uint4*)&lds[4*TSZ + d1] = f1;
        *(uint4*)&lds[5*TSZ + d0] = h0; *(uint4*)&lds[5*TSZ + d1] = h1;
        __syncthreads();

        short8 a_h[4], a_l[4], a_q[4], b_h[4], b_l[4], b_q[4];
        #pragma unroll
        for (int m = 0; m < 4; ++m) {
            int off = (wr*64 + m*16 + fr) * TW + swz8;
            a_h[m] = *(const short8*)&lds[0*TSZ + off];
            a_l[m] = *(const short8*)&lds[1*TSZ + off];
            a_q[m] = *(const short8*)&lds[2*TSZ + off];
        }
        #pragma unroll
        for (int n = 0; n < 4; ++n) {
            int off = (wc*64 + n*16 + fr) * TW + swz8;
            b_h[n] = *(const short8*)&lds[3*TSZ + off];
            b_l[n] = *(const short8*)&lds[4*TSZ + off];
            b_q[n] = *(const short8*)&lds[5*TSZ + off];
        }
        #pragma unroll
        for (int m = 0; m < 4; ++m)
            #pragma unroll
            for (int n = 0; n < 4; ++n) {
                acc[m][n] = __builtin_amdgcn_mfma_f32_16x16x32_bf16(a_h[m], b_h[n], acc[m][n], 0, 0, 0);
                acc[m][n] = __builtin_amdgcn_mfma_f32_16x16x32_bf16(a_h[m], b_l[n], acc[m][n], 0, 0, 0);
                acc[m][n] = __builtin_amdgcn_mfma_f32_16x16x32_bf16(a_l[m], b_h[n], acc[m][n], 0, 0, 0);
                acc[m][n] = __builtin_amdgcn_mfma_f32_16x16x32_bf16(a_l[m], b_l[n], acc[m][n], 0, 0, 0);
                acc[m][n] = __builtin_amdgcn_mfma_f32_16x16x32_bf16(a_h[m], b_q[n], acc[m][n], 0, 0, 0);
                acc[m][n] = __builtin_amdgcn_mfma_f32_16x16x32_bf16(a_q[m], b_h[n], acc[m][n], 0, 0, 0);
            }
        __syncthreads();
    }

    // normal write: S[bi+row][bj+col] = x2[col] - 2 acc (diag -> inf)
    #pragma unroll
    for (int m = 0; m < 4; ++m)
        #pragma unroll
        for (int n = 0; n < 4; ++n) {
            int col = bj + wc*64 + n*16 + fr;
            float xc = x2b[col];
            #pragma unroll
            for (int r = 0; r < 4; ++r) {
                int row = bi + wr*64 + m*16 + kg*4 + r;
                float val = xc - 2.0f * acc[m][n][r];
                if (row == col) val = __builtin_inff();
                Sb[(size_t)row * NPTS + col] = val;
            }
        }

    // mirror write: S[bj+col][bi+row] = x2[row] - 2 acc, via LDS transpose
    if (bi != bj) {
        float* T = (float*)lds;                 // 64 x 128, stride 132 floats
        #pragma unroll
        for (int p = 0; p < 2; ++p) {
            __syncthreads();
            if (wc == p) {
                #pragma unroll
                for (int m = 0; m < 4; ++m) {
                    int row0 = wr*64 + m*16 + kg*4;
                    float x0 = x2b[bi + row0 + 0];
                    float x1 = x2b[bi + row0 + 1];
                    float x2v = x2b[bi + row0 + 2];
                    float x3 = x2b[bi + row0 + 3];
                    #pragma unroll
                    for (int n = 0; n < 4; ++n) {
                        int colp = n*16 + fr;   // 0..63 within pass
                        float4 v;
                        v.x = x0 - 2.0f * acc[m][n][0];
                        v.y = x1 - 2.0f * acc[m][n][1];
                        v.z = x2v - 2.0f * acc[m][n][2];
                        v.w = x3 - 2.0f * acc[m][n][3];
                        *(float4*)&T[colp * 132 + row0] = v;
                    }
                }
            }
            __syncthreads();
            #pragma unroll
            for (int i = 0; i < 8; ++i) {
                int f = threadIdx.x + i * 256;  // 0..2047
                int cr = f >> 5, c4 = (f & 31) * 4;
                float4 v = *(const float4*)&T[cr * 132 + c4];
                *(float4*)(Sb + (size_t)(bj + p*64 + cr) * NPTS + bi + c4) = v;
            }
        }
    }
}

// ---------------------------------------------------------------------------
// Kernel 3 (merged): gram upper-tri tiles (blocks 0..271) + qkv GEMM (272..655).
// qkv part also emits fp16 K/V compact array.
// ---------------------------------------------------------------------------
__global__ __launch_bounds__(256) void fused_mfma_kernel(const ushort* __restrict__ xh,
                                                         const ushort* __restrict__ xl,
                                                         const ushort* __restrict__ xq,
                                                         const float* __restrict__ x2,
                                                         float* __restrict__ S,
                                                         const ushort* __restrict__ wqhiT,
                                                         const ushort* __restrict__ wqloT,
                                                         float* __restrict__ qkv,
                                                         ushort* __restrict__ kv16) {
    __shared__ ushort lds[6*TSZ];    // 48 KB
    int bid = blockIdx.x;
    if (bid < 272) {
        int b = bid / 136, t = bid % 136;
        int by = 0;
        while (t >= 16 - by) { t -= 16 - by; ++by; }
        int bx = by + t;                 // by <= bx (upper triangle)
        size_t xoff = (size_t)b * NPTS * CDIM;
        gram_body(xh + xoff, xl + xoff, xq + xoff,
                  x2 + (size_t)b * NPTS, S + (size_t)b * NPTS * NPTS,
                  by * 128, bx * 128, lds);
    } else {
        int t = bid - 272;               // 0..383
        int bx = t % 12, by = t / 12;    // 12 col-tiles, 32 row-tiles
        gemm_split_body(xh, xl, wqhiT, wqloT, nullptr, qkv,
                        TRIPLE, CDIM, by * 128, bx * 128, lds, kv16);
    }
}

// ---------------------------------------------------------------------------
// Kernel 4: out projection (standalone split GEMM + bias).
// ---------------------------------------------------------------------------
__global__ __launch_bounds__(256) void outproj_kernel(const ushort* __restrict__ Ahi,
                                                      const ushort* __restrict__ Alo,
                                                      const ushort* __restrict__ BhiT,
                                                      const ushort* __restrict__ BloT,
                                                      const float* __restrict__ bias,
                                                      float* __restrict__ C) {
    __shared__ ushort lds[4*TSZ];    // 32 KB
    gemm_split_body(Ahi, Alo, BhiT, BloT, bias, C,
                    CDIM, INNER, blockIdx.y * 128, blockIdx.x * 128, lds, nullptr);
}

// ---------------------------------------------------------------------------
// Kernel 5 (fused): top-KNN selection (range-normalized histogram) + sparse
// attention over the selected neighbors, all in one block per (b,n).
// Neighbor list never leaves LDS. K/V gathered in fp16 (q stays fp32).
// XCD batch pinning: bid -> b = (bid&7)>>2, n = (bid>>3)*4 + (bid&3).
// ---------------------------------------------------------------------------
__device__ __forceinline__ unsigned block_excl_scan_256(unsigned c,
                                                        unsigned* wsum,
                                                        unsigned* total_out) {
    unsigned v = c;
    #pragma unroll
    for (int o = 1; o < 64; o <<= 1) {
        unsigned t = __shfl_up(v, o);
        if ((threadIdx.x & 63) >= o) v += t;
    }
    if ((threadIdx.x & 63) == 63) wsum[threadIdx.x >> 6] = v;
    __syncthreads();
    unsigned woff = 0;
    int mywave = threadIdx.x >> 6;
    #pragma unroll
    for (int w = 0; w < 4; ++w) {
        unsigned s = wsum[w];
        if (w < mywave) woff += s;
    }
    if (total_out) *total_out = wsum[0] + wsum[1] + wsum[2] + wsum[3];
    __syncthreads();
    return v + woff - c;
}

__global__ __launch_bounds__(256) void knn_attn_kernel(const float* __restrict__ S,
                                                       const float* __restrict__ qkv,
                                                       const ushort* __restrict__ kv16,
                                                       ushort* __restrict__ ahi,
                                                       ushort* __restrict__ alo) {
    int bid = blockIdx.x;
    int b = (bid & 7) >> 2;
    int n = ((bid >> 3) << 2) | (bid & 3);
    size_t rowoff = (size_t)b * NPTS + n;
    const float* row = S + rowoff * NPTS;

    __shared__ unsigned keys[NPTS];
    __shared__ unsigned hist[256];
    __shared__ unsigned wsum[4];
    __shared__ unsigned s_red[8];
    __shared__ unsigned sh_lo, sh_hi, sh_rank, sh_cnt, sh_break;
    __shared__ unsigned ckey[64];
    __shared__ int     cidx[64];
    __shared__ unsigned s_ccount;
    __shared__ int   nb[KNN];
    __shared__ float dots[NHEAD][KNN];
    __shared__ float p[NHEAD][KNN];

    int tid = threadIdx.x;

    // ---- selection phase (unchanged logic; output -> LDS nb[]) ----
    unsigned mn = 0xffffffffu, mx = 0u;
    {
        int i0 = tid * 8;
        float4 f0 = *(const float4*)(row + i0);
        float4 f1 = *(const float4*)(row + i0 + 4);
        float fv[8] = { f0.x, f0.y, f0.z, f0.w, f1.x, f1.y, f1.z, f1.w };
        #pragma unroll
        for (int t = 0; t < 8; ++t) {
            int i = i0 + t;
            unsigned u;
            if (i == n) {
                u = 0xffffffffu;
            } else {
                unsigned v = __float_as_uint(fv[t]);
                u = (v & 0x80000000u) ? ~v : (v | 0x80000000u);
                mn = min(mn, u); mx = max(mx, u);
            }
            keys[i] = u;
        }
    }
    #pragma unroll
    for (int o = 32; o; o >>= 1) {
        mn = min(mn, (unsigned)__shfl_xor((int)mn, o));
        mx = max(mx, (unsigned)__shfl_xor((int)mx, o));
    }
    if ((tid & 63) == 0) { s_red[tid >> 6] = mn; s_red[4 + (tid >> 6)] = mx; }
    __syncthreads();
    if (tid == 0) {
        unsigned a = min(min(s_red[0], s_red[1]), min(s_red[2], s_red[3]));
        unsigned z = max(max(s_red[4], s_red[5]), max(s_red[6], s_red[7]));
        sh_lo = a; sh_hi = z; sh_rank = KNN; sh_break = 0; s_ccount = 0;
    }
    __syncthreads();

    for (int it = 0; it < 5; ++it) {
        unsigned lo = sh_lo, hi = sh_hi;
        unsigned range1 = hi - lo;
        int shift = 0;
        if (range1 > 255u) shift = 24 - __clz(range1);
        hist[tid] = 0;
        __syncthreads();
        for (int i = tid; i < NPTS; i += 256) {
            unsigned u = keys[i];
            if (u >= lo && u <= hi)
                atomicAdd(&hist[(u - lo) >> shift], 1u);
        }
        __syncthreads();
        unsigned c = hist[tid];
        unsigned rank = sh_rank;
        unsigned excl = block_excl_scan_256(c, wsum, nullptr);
        if (excl < rank && excl + c >= rank) {
            sh_rank = rank - excl;
            unsigned nlo = lo + ((unsigned)tid << shift);
            unsigned span = (shift == 0) ? 0u : (((1u << shift)) - 1u);
            unsigned nhi = nlo + span;
            if (nhi > hi || nhi < nlo) nhi = hi;
            sh_lo = nlo; sh_hi = nhi;
            sh_cnt = c;
            sh_break = (shift == 0 || c <= 64u) ? 1u : 0u;
        }
        __syncthreads();
        if (sh_break) break;
    }

    unsigned lo = sh_lo, hi = sh_hi, rank = sh_rank, cnt = sh_cnt;

    unsigned lt = 0;
    for (int i = tid; i < NPTS; i += 256) lt += (keys[i] < lo) ? 1u : 0u;
    unsigned pos = block_excl_scan_256(lt, wsum, nullptr);
    for (int i = tid; i < NPTS; i += 256) {
        unsigned u = keys[i];
        if (u < lo) nb[pos++] = i;
        else if (u >= lo && u <= hi && cnt <= 64u) {
            unsigned pp = atomicAdd(&s_ccount, 1u);
            ckey[pp] = u; cidx[pp] = i;
        }
    }
    __syncthreads();

    unsigned base = KNN - rank;
    if (cnt <= 64u) {
        if (tid < (int)cnt) {
            unsigned myk = ckey[tid]; int myi = cidx[tid];
            unsigned r = 0;
            for (unsigned s = 0; s < cnt; ++s) {
                unsigned sk = ckey[s]; int si = cidx[s];
                r += (sk < myk || (sk == myk && si < myi)) ? 1u : 0u;
            }
            if (r < rank) nb[base + r] = myi;
        }
    } else {
        if (tid == 0) {
            unsigned need = rank, pp = base;
            for (int i = 0; i < NPTS && need; ++i) {
                if (keys[i] >= lo && keys[i] <= hi) { nb[pp++] = i; --need; }
            }
        }
    }
    __syncthreads();

    // ---- attention phase (fp16 K/V gather, fp32 math) ----
    const float* qrow = qkv + rowoff * TRIPLE;                 // q cols 0..511
    const ushort* kvb = kv16 + (size_t)b * NPTS * 1024;

    // phase 1: dots; all 8 head-chunks of K row loaded upfront
    {
        int j = tid >> 3;              // neighbor 0..31
        int l = tid & 7;               // 8-elem segment 0..7
        const ushort* krow = kvb + (size_t)nb[j] * 1024 + l * 8;   // k at 0..511
        short8 kr[NHEAD];
        #pragma unroll
        for (int h = 0; h < NHEAD; ++h)
            kr[h] = *(const short8*)(krow + h * DHEAD);
        const float* qp = qrow + l * 8;
        #pragma unroll
        for (int h = 0; h < NHEAD; ++h) {
            float4 q0 = *(const float4*)(qp + h * DHEAD);
            float4 q1 = *(const float4*)(qp + h * DHEAD + 4);
            float d = h2f((ushort)kr[h][0]) * q0.x + h2f((ushort)kr[h][1]) * q0.y
                    + h2f((ushort)kr[h][2]) * q0.z + h2f((ushort)kr[h][3]) * q0.w
                    + h2f((ushort)kr[h][4]) * q1.x + h2f((ushort)kr[h][5]) * q1.y
                    + h2f((ushort)kr[h][6]) * q1.z + h2f((ushort)kr[h][7]) * q1.w;
            d += __shfl_xor(d, 1);
            d += __shfl_xor(d, 2);
            d += __shfl_xor(d, 4);
            if (l == 0) dots[h][j] = d * SCALE;
        }
    }
    __syncthreads();

    // phase 1b: softmax per head
    {
        int h = tid >> 5, jj = tid & 31;
        float dv = dots[h][jj];
        float mxv = dv;
        for (int o = 16; o; o >>= 1) mxv = fmaxf(mxv, __shfl_xor(mxv, o));
        float e = expf(dv - mxv);
        float s = e;
        for (int o = 16; o; o >>= 1) s += __shfl_xor(s, o);
        p[h][jj] = e / s;
    }
    __syncthreads();

    // phase 2: weighted V sum (fp16 V), 8 loads in flight per group
    {
        int hd = tid >> 5;
        int jd = tid & 31;
        const ushort* vb = kvb + INNER + hd * DHEAD + jd * 2;      // v at 512..1023
        float o0 = 0.f, o1 = 0.f;
        #pragma unroll
        for (int g = 0; g < 4; ++g) {
            unsigned vv[8]; float pw[8];
            #pragma unroll
            for (int t = 0; t < 8; ++t) {
                int jj = g * 8 + t;
                vv[t] = *(const unsigned*)(vb + (size_t)nb[jj] * 1024);
                pw[t] = p[hd][jj];
            }
            #pragma unroll
            for (int t = 0; t < 8; ++t) {
                o0 += pw[t] * h2f((ushort)(vv[t] & 0xffffu));
                o1 += pw[t] * h2f((ushort)(vv[t] >> 16));
            }
        }
        size_t baseo = rowoff * INNER + hd * DHEAD + jd * 2;
        unsigned q0 = bfsplit(o0);
        unsigned q1 = bfsplit(o1);
        *(unsigned*)(ahi + baseo) = (q0 & 0xffffu) | (q1 << 16);
        *(unsigned*)(alo + baseo) = (q0 >> 16) | (q1 & 0xffff0000u);
    }
}

// ---------------------------------------------------------------------------
extern "C" void kernel_launch(void* const* d_in, const int* in_sizes, int n_in,
                              void* d_out, int out_size, void* d_ws, size_t ws_size,
                              hipStream_t stream) {
    const float* x    = (const float*)d_in[0];   // [2,2048,256]
    const float* Wqkv = (const float*)d_in[1];   // [256,1536]
    const float* Wout = (const float*)d_in[2];   // [512,256]
    const float* bout = (const float*)d_in[3];   // [256]
    float* out = (float*)d_out;                  // [2,2048,256]

    // workspace layout
    float* S    = (float*)d_ws;                           // 8,388,608 f32
    float* x2   = S + (size_t)BATCH * NPTS * NPTS;        // 4096 f32
    float* qkv  = x2 + (size_t)BATCH * NPTS;              // B*N*1536 f32
    ushort* kv16 = (ushort*)(qkv + (size_t)BATCH * NPTS * TRIPLE); // B*N*1024 fp16
    ushort* xhi = kv16 + (size_t)BATCH * NPTS * 1024;
    ushort* xlo   = xhi   + (size_t)BATCH * NPTS * CDIM;
    ushort* xqd   = xlo   + (size_t)BATCH * NPTS * CDIM;
    ushort* ahi   = xqd   + (size_t)BATCH * NPTS * CDIM;
    ushort* alo   = ahi   + (size_t)BATCH * NPTS * INNER;
    ushort* wqhiT = alo   + (size_t)BATCH * NPTS * INNER; // [1536][256]
    ushort* wqloT = wqhiT + (size_t)TRIPLE * CDIM;
    ushort* wohiT = wqloT + (size_t)TRIPLE * CDIM;        // [256][512]
    ushort* woloT = wohiT + (size_t)CDIM * INNER;

    // 1. fused rowsq + x split
    input_prep_kernel<<<(BATCH * NPTS) / 4, 256, 0, stream>>>(x, x2, xhi, xlo, xqd);

    // 2. merged weight transpose+split
    wtrans2_kernel<<<128, 256, 0, stream>>>(Wqkv, Wout, wqhiT, wqloT, wohiT, woloT);

    // 3. merged gram (upper-tri + mirror) + qkv GEMM (+ fp16 K/V emit)
    fused_mfma_kernel<<<656, 256, 0, stream>>>(xhi, xlo, xqd, x2, S,
                                               wqhiT, wqloT, qkv, kv16);

    // 4. fused top-32 selection + sparse attention (XCD batch pinning)
    knn_attn_kernel<<<BATCH * NPTS, 256, 0, stream>>>(S, qkv, kv16, ahi, alo);

    // 5. output projection: [4096,512] @ [512,256] + bias
    {
        dim3 grid(CDIM / 128, (BATCH * NPTS) / 128);
        outproj_kernel<<<grid, 256, 0, stream>>>(ahi, alo, wohiT, woloT, bout, out);
    }
}